// Round 4
// baseline (992.688 us; speedup 1.0000x reference)
//
#include <hip/hip_runtime.h>
#include <hip/hip_bf16.h>

typedef __bf16 bf16;
typedef bf16 bf16x8 __attribute__((ext_vector_type(8)));
typedef bf16 bf16x4 __attribute__((ext_vector_type(4)));
typedef float f32x4 __attribute__((ext_vector_type(4)));

#define MFMA16(a, b, c) __builtin_amdgcn_mfma_f32_16x16x32_bf16((a), (b), (c), 0, 0, 0)

// ---------------------------------------------------------------------------
// dtype detection: sample 4096 u32 words of tgt; count words whose bits[14:7]
// look like a bf16 exponent near 127. bf16 data -> ~4096 hits; f32 data ->
// bits[14:7] are mantissa noise -> ~800 hits. flag=1 means "inputs are bf16".
__global__ __launch_bounds__(256) void k_detect(const void* __restrict__ src, int* __restrict__ flag) {
    __shared__ int cnt;
    if (threadIdx.x == 0) cnt = 0;
    __syncthreads();
    const unsigned int* w = (const unsigned int*)src;
    int local = 0;
    for (int i = threadIdx.x; i < 4096; i += 256) {
        unsigned int e = (w[i] >> 7) & 0xFF;
        local += (e > 100 && e < 150) ? 1 : 0;
    }
    atomicAdd(&cnt, local);
    __syncthreads();
    if (threadIdx.x == 0) *flag = (cnt > 2048) ? 1 : 0;
}

// normalize any input (f32 or bf16 per flag) into a bf16 copy. n8 = n/8.
__global__ __launch_bounds__(256) void k_norm(const int* __restrict__ flag, const void* __restrict__ src,
                                              bf16* __restrict__ dst, int n8) {
    int i = blockIdx.x * 256 + threadIdx.x;
    if (i >= n8) return;
    if (*flag) {
        ((bf16x8*)dst)[i] = ((const bf16x8*)src)[i];
    } else {
        const float* s = (const float*)src + (size_t)i * 8;
        bf16x8 o;
#pragma unroll
        for (int j = 0; j < 8; j++) o[j] = (bf16)s[j];
        ((bf16x8*)dst)[i] = o;
    }
}

// tgt -> f32 residual base (dual dtype)
__global__ __launch_bounds__(256) void k_cvt(const int* __restrict__ flag, const void* __restrict__ in,
                                             float* __restrict__ out) {
    size_t i = (size_t)blockIdx.x * 256 + threadIdx.x;  // one per 8 elems
    f32x4 a, b;
    if (*flag) {
        bf16x8 v = ((const bf16x8*)in)[i];
#pragma unroll
        for (int j = 0; j < 4; j++) { a[j] = (float)v[j]; b[j] = (float)v[4 + j]; }
    } else {
        a = ((const f32x4*)in)[i * 2];
        b = ((const f32x4*)in)[i * 2 + 1];
    }
    ((f32x4*)out)[i * 2] = a;
    ((f32x4*)out)[i * 2 + 1] = b;
}

// ---------------------------------------------------------------------------
// transpose (dual dtype in): in[R][C] -> out[C][R] bf16   (sru_w -> wT)
__global__ __launch_bounds__(256) void k_transpose(const int* __restrict__ flag, const void* __restrict__ in,
                                                   bf16* __restrict__ out, int R, int C) {
    __shared__ __align__(16) bf16 t[64][72];
    int tid = threadIdx.x;
    int c0 = blockIdx.x * 64, r0 = blockIdx.y * 64;
#pragma unroll
    for (int i = 0; i < 2; i++) {
        int idx = tid + i * 256;            // 0..511
        int r = idx >> 3, ch = idx & 7;
        size_t base = (size_t)(r0 + r) * C + c0 + ch * 8;
        bf16x8 v;
        if (*flag) {
            v = *(const bf16x8*)((const bf16*)in + base);
        } else {
            const float* f = (const float*)in + base;
            f32x4 x = *(const f32x4*)f, y = *(const f32x4*)(f + 4);
#pragma unroll
            for (int j = 0; j < 4; j++) { v[j] = (bf16)x[j]; v[4 + j] = (bf16)y[j]; }
        }
        *(bf16x8*)&t[r][ch * 8] = v;
    }
    __syncthreads();
#pragma unroll
    for (int i = 0; i < 2; i++) {
        int idx = tid + i * 256;
        int cr = idx >> 3, ch = idx & 7;
        bf16x8 v;
#pragma unroll
        for (int j = 0; j < 8; j++) v[j] = t[ch * 8 + j][cr];
        *(bf16x8*)(out + (size_t)(c0 + cr) * R + r0 + ch * 8) = v;
    }
}

// ---------------------------------------------------------------------------
// GEMM: C[M,N] = A[M,K] @ W[N,K]^T (+bias) (*scale for col<scale_end)
// 128x128 tile, BK=32, 4 waves (2x2), 4x4 16x16 MFMA tiles per wave.
__device__ __forceinline__ int swz(int r, int byteInRow) {
    return r * 64 + (byteInRow ^ ((r & 3) << 4));
}

template <typename AT>
__global__ __launch_bounds__(256) void k_gemm(
    const AT* __restrict__ A, int lda,
    const bf16* __restrict__ W, int ldw,
    const bf16* __restrict__ bias,
    float* __restrict__ Cf, bf16* __restrict__ Cb, int ldc,
    int K, int scale_end, float scale) {
    __shared__ __align__(16) char Asm[128 * 64];
    __shared__ __align__(16) char Bsm[128 * 64];
    int tid = threadIdx.x, w = tid >> 6, l = tid & 63, lg = l >> 4, lm = l & 15;
    int wm = w >> 1, wn = w & 1;
    int m0 = blockIdx.y * 128, n0 = blockIdx.x * 128;

    f32x4 acc[4][4] = {};

    for (int k0 = 0; k0 < K; k0 += 32) {
        if constexpr (sizeof(AT) == 4) {  // f32 A -> bf16 LDS
#pragma unroll
            for (int i = 0; i < 4; i++) {
                int c = tid + i * 256;          // 0..1023
                int r = c >> 3, ch = c & 7;
                f32x4 v = *(const f32x4*)(A + (size_t)(m0 + r) * lda + k0 + ch * 4);
                bf16x4 o;
#pragma unroll
                for (int j = 0; j < 4; j++) o[j] = (bf16)v[j];
                *(bf16x4*)(Asm + swz(r, ch * 8)) = o;
            }
        } else {  // bf16 A
#pragma unroll
            for (int i = 0; i < 2; i++) {
                int c = tid + i * 256;          // 0..511
                int r = c >> 2, ch = c & 3;
                bf16x8 v = *(const bf16x8*)(A + (size_t)(m0 + r) * lda + k0 + ch * 8);
                *(bf16x8*)(Asm + swz(r, ch * 16)) = v;
            }
        }
#pragma unroll
        for (int i = 0; i < 2; i++) {
            int c = tid + i * 256;
            int r = c >> 2, ch = c & 3;
            bf16x8 v = *(const bf16x8*)(W + (size_t)(n0 + r) * ldw + k0 + ch * 8);
            *(bf16x8*)(Bsm + swz(r, ch * 16)) = v;
        }
        __syncthreads();
        bf16x8 af[4], bfr[4];
#pragma unroll
        for (int i = 0; i < 4; i++)
            af[i] = *(const bf16x8*)(Asm + swz(wm * 64 + i * 16 + lm, lg * 16));
#pragma unroll
        for (int j = 0; j < 4; j++)
            bfr[j] = *(const bf16x8*)(Bsm + swz(wn * 64 + j * 16 + lm, lg * 16));
#pragma unroll
        for (int i = 0; i < 4; i++)
#pragma unroll
            for (int j = 0; j < 4; j++)
                acc[i][j] = MFMA16(af[i], bfr[j], acc[i][j]);
        __syncthreads();
    }
#pragma unroll
    for (int j = 0; j < 4; j++) {
        int col = n0 + wn * 64 + j * 16 + lm;
        float bv = bias ? (float)bias[col] : 0.f;
        float sc = (col < scale_end) ? scale : 1.f;
#pragma unroll
        for (int i = 0; i < 4; i++) {
            int row = m0 + wm * 64 + i * 16 + lg * 4;
#pragma unroll
            for (int r = 0; r < 4; r++) {
                float v = (acc[i][j][r] + bv) * sc;
                size_t idx = (size_t)(row + r) * ldc + col;
                if (Cf) Cf[idx] = v;
                if (Cb) Cb[idx] = (bf16)v;
            }
        }
    }
}

// ---------------------------------------------------------------------------
// Flash attention (non-causal). Row layout: row = s*B + b; head h = cols
// [h*64, h*64+64). Block = (qblk 64 rows, h, b). 4 waves, 16 q-rows each.
__device__ __forceinline__ int swz2(int row, int byteInRow) {
    return row * 128 + (byteInRow ^ ((row & 7) << 4));
}

__global__ __launch_bounds__(256) void k_attn(
    const bf16* __restrict__ Qp, const bf16* __restrict__ Kp, const bf16* __restrict__ Vp,
    int ldq, int ldk, float* __restrict__ Op) {
    int qblk = blockIdx.x, h = blockIdx.y, b = blockIdx.z;
    int tid = threadIdx.x, w = tid >> 6, l = tid & 63, lg = l >> 4, lm = l & 15;

    __shared__ __align__(16) char Ksm[64 * 128];
    __shared__ __align__(16) char Vsm[64 * 128];     // transposed: [dim][krow]
    __shared__ __align__(16) char Psm[4][16 * 128];  // per-wave P

    bf16x8 qf[2];
    int qrow = qblk * 64 + w * 16 + lm;
#pragma unroll
    for (int kk = 0; kk < 2; kk++)
        qf[kk] = *(const bf16x8*)(Qp + (size_t)(qrow * 4 + b) * ldq + h * 64 + kk * 32 + lg * 8);

    f32x4 oa[4] = {};
    float mrun[4], lrun[4];
#pragma unroll
    for (int r = 0; r < 4; r++) { mrun[r] = -1e30f; lrun[r] = 0.f; }

    for (int kt = 0; kt < 16; kt++) {
#pragma unroll
        for (int p = 0; p < 2; p++) {
            int idx = tid + p * 256;
            int r = idx >> 3, ch = idx & 7;
            bf16x8 kv = *(const bf16x8*)(Kp + (size_t)((kt * 64 + r) * 4 + b) * ldk + h * 64 + ch * 8);
            *(bf16x8*)(Ksm + swz2(r, ch * 16)) = kv;
            bf16x8 vv = *(const bf16x8*)(Vp + (size_t)((kt * 64 + r) * 4 + b) * ldk + h * 64 + ch * 8);
#pragma unroll
            for (int j = 0; j < 8; j++) {
                int d = ch * 8 + j;
                *(bf16*)(Vsm + swz2(d, r * 2)) = vv[j];  // Vt[d][r]
            }
        }
        __syncthreads();

        f32x4 sc[4] = {};
#pragma unroll
        for (int kk = 0; kk < 2; kk++)
#pragma unroll
            for (int jt = 0; jt < 4; jt++) {
                bf16x8 bk = *(const bf16x8*)(Ksm + swz2(jt * 16 + lm, kk * 64 + lg * 16));
                sc[jt] = MFMA16(qf[kk], bk, sc[jt]);
            }

        // online softmax; sc[jt][r]: row lg*4+r, col jt*16+lm
        float al[4], rs[4];
#pragma unroll
        for (int r = 0; r < 4; r++) {
            float m = fmaxf(fmaxf(sc[0][r], sc[1][r]), fmaxf(sc[2][r], sc[3][r]));
#pragma unroll
            for (int d = 1; d < 16; d <<= 1) m = fmaxf(m, __shfl_xor(m, d));
            float mn = fmaxf(mrun[r], m);
            al[r] = __expf(mrun[r] - mn);
            mrun[r] = mn;
            rs[r] = 0.f;
        }
#pragma unroll
        for (int jt = 0; jt < 4; jt++)
#pragma unroll
            for (int r = 0; r < 4; r++) {
                float p = __expf(sc[jt][r] - mrun[r]);
                sc[jt][r] = p;
                rs[r] += p;
            }
#pragma unroll
        for (int r = 0; r < 4; r++) {
#pragma unroll
            for (int d = 1; d < 16; d <<= 1) rs[r] += __shfl_xor(rs[r], d);
            lrun[r] = lrun[r] * al[r] + rs[r];
        }
#pragma unroll
        for (int ot = 0; ot < 4; ot++)
#pragma unroll
            for (int r = 0; r < 4; r++) oa[ot][r] *= al[r];
#pragma unroll
        for (int jt = 0; jt < 4; jt++)
#pragma unroll
            for (int r = 0; r < 4; r++)
                *(bf16*)(Psm[w] + swz2(lg * 4 + r, (jt * 16 + lm) * 2)) = (bf16)sc[jt][r];
        __syncthreads();  // fence P stores vs vector re-reads
#pragma unroll
        for (int kk = 0; kk < 2; kk++) {
            bf16x8 pa = *(const bf16x8*)(Psm[w] + swz2(lm, kk * 64 + lg * 16));
#pragma unroll
            for (int ot = 0; ot < 4; ot++) {
                bf16x8 bv = *(const bf16x8*)(Vsm + swz2(ot * 16 + lm, kk * 64 + lg * 16));
                oa[ot] = MFMA16(pa, bv, oa[ot]);
            }
        }
        __syncthreads();
    }
#pragma unroll
    for (int r = 0; r < 4; r++) {
        float inv = 1.f / lrun[r];
        int srow = qblk * 64 + w * 16 + lg * 4 + r;
#pragma unroll
        for (int ot = 0; ot < 4; ot++) {
            int col = h * 64 + ot * 16 + lm;
            Op[(size_t)(srow * 4 + b) * 1024 + col] = oa[ot][r] * inv;
        }
    }
}

// ---------------------------------------------------------------------------
// residual-add + LayerNorm over D=1024. 4 rows/block (wave per row). X dtype templated.
template <typename XT>
__global__ __launch_bounds__(256) void k_addln(
    const XT* __restrict__ X, const float* __restrict__ Yd,
    const bf16* __restrict__ g, const bf16* __restrict__ bb,
    float* __restrict__ outF, bf16* __restrict__ outB) {
    int row = blockIdx.x * 4 + (threadIdx.x >> 6);
    int l = threadIdx.x & 63;
    const XT* xr = X + (size_t)row * 1024;
    const float* yr = Yd + (size_t)row * 1024;
    float v[16];
    float s = 0.f, s2 = 0.f;
#pragma unroll
    for (int q = 0; q < 4; q++) {
        float xa[4];
        if constexpr (sizeof(XT) == 4) {
            f32x4 a = *(const f32x4*)(xr + l * 4 + q * 256);
#pragma unroll
            for (int j = 0; j < 4; j++) xa[j] = a[j];
        } else {
            bf16x4 a = *(const bf16x4*)(xr + l * 4 + q * 256);
#pragma unroll
            for (int j = 0; j < 4; j++) xa[j] = (float)a[j];
        }
        f32x4 c = *(const f32x4*)(yr + l * 4 + q * 256);
#pragma unroll
        for (int j = 0; j < 4; j++) {
            float t = xa[j] + c[j];
            v[q * 4 + j] = t;
            s += t;
            s2 += t * t;
        }
    }
#pragma unroll
    for (int d = 1; d < 64; d <<= 1) { s += __shfl_xor(s, d); s2 += __shfl_xor(s2, d); }
    float mu = s * (1.f / 1024.f);
    float var = s2 * (1.f / 1024.f) - mu * mu;
    float rstd = rsqrtf(var + 1e-5f);
#pragma unroll
    for (int q = 0; q < 4; q++)
#pragma unroll
        for (int j = 0; j < 4; j++) {
            int col = l * 4 + q * 256 + j;
            float y = (v[q * 4 + j] - mu) * rstd * (float)g[col] + (float)bb[col];
            if (outF) outF[(size_t)row * 1024 + col] = y;
            if (outB) outB[(size_t)row * 1024 + col] = (bf16)y;
        }
}

// ---------------------------------------------------------------------------
// SRU scan chunk: 256 steps, carried state cst[8192]. One thread per (b,h).
__global__ __launch_bounds__(256) void k_sru(
    const float* __restrict__ U, const bf16* __restrict__ v2, const bf16* __restrict__ b2,
    bf16* __restrict__ Hb, float* __restrict__ cst, int s0, int init) {
    int ch = blockIdx.x * 256 + threadIdx.x;  // 0..8191
    int b = ch >> 11, h = ch & 2047;
    float vf = (float)v2[h], vr = (float)v2[2048 + h];
    float bfv = (float)b2[h], brv = (float)b2[2048 + h];
    float c = init ? 0.f : cst[ch];
    const float* u = U + (size_t)b * 8192 + h;       // local rows ls*4+b, cols j*2048+h
    bf16* ho = Hb + ((size_t)(s0)*4 + b) * 2048 + h; // global rows (s0+ls)*4+b
    float xc = u[0], fp = u[2048], rp = u[4096], xh = u[6144];
    for (int ls = 0; ls < 256; ls++) {
        float nxc = 0.f, nfp = 0.f, nrp = 0.f, nxh = 0.f;
        if (ls < 255) {
            const float* un = u + (size_t)(ls + 1) * 32768;
            nxc = un[0]; nfp = un[2048]; nrp = un[4096]; nxh = un[6144];
        }
        float f = 1.f / (1.f + __expf(-(fp + vf * c + bfv)));
        float r = 1.f / (1.f + __expf(-(rp + vr * c + brv)));
        c = f * c + (1.f - f) * xc;
        float hv = r * c + (1.f - r) * xh;
        ho[(size_t)ls * 8192] = (bf16)hv;
        xc = nxc; fp = nfp; rp = nrp; xh = nxh;
    }
    cst[ch] = c;
}

// ---------------------------------------------------------------------------
extern "C" void kernel_launch(void* const* d_in, const int* in_sizes, int n_in,
                              void* d_out, int out_size, void* d_ws, size_t ws_size,
                              hipStream_t stream) {
    const size_t MB = 1u << 20;
    char* ws = (char*)d_ws;

    // ---- normalized bf16 input copies [0, ~28.1 MB) ----
    bf16* memB    = (bf16*)(ws + 0);        // 4096x1024
    bf16* sawinB  = (bf16*)(ws + 8 * MB);   // 3072x1024
    bf16* sawoutB = (bf16*)(ws + 14 * MB);  // 1024x1024
    bf16* cawinB  = (bf16*)(ws + 16 * MB);  // 3072x1024
    bf16* cawoutB = (bf16*)(ws + 22 * MB);  // 1024x1024
    bf16* lin2wB  = (bf16*)(ws + 24 * MB);  // 1024x2048
    char* S0 = ws + 28 * MB;                // 8KB slots for small tensors
    bf16* sabinB  = (bf16*)(S0 + 0 * 8192);
    bf16* cabinB  = (bf16*)(S0 + 1 * 8192);
    bf16* saboutB = (bf16*)(S0 + 2 * 8192);
    bf16* caboutB = (bf16*)(S0 + 3 * 8192);
    bf16* lin2bB  = (bf16*)(S0 + 4 * 8192);
    bf16* sruvB   = (bf16*)(S0 + 5 * 8192);
    bf16* srubB   = (bf16*)(S0 + 6 * 8192);
    bf16* ln1gB   = (bf16*)(S0 + 7 * 8192);
    bf16* ln1bB   = (bf16*)(S0 + 8 * 8192);
    bf16* ln2gB   = (bf16*)(S0 + 9 * 8192);
    bf16* ln2bB   = (bf16*)(S0 + 10 * 8192);
    bf16* ln3gB   = (bf16*)(S0 + 11 * 8192);
    bf16* ln3bB   = (bf16*)(S0 + 12 * 8192);
    int*  flag    = (int*)(S0 + 13 * 8192);

    // ---- pipeline buffers, base P = 29 MB; peak use = P + 96 MB = 125 MB ----
    char* P = ws + 29 * MB;
    float* t0   = (float*)(P + 0);        // 4096x1024 f32   [P+0,  P+16)
    bf16*  qkv  = (bf16*)(P + 16 * MB);   // 4096x3072 bf16  [P+16, P+40)
    bf16*  qca  = qkv;                    // 4096x1024 bf16  (reuse after self-attn)
    bf16*  kvca = (bf16*)(P + 24 * MB);   // 4096x2048 bf16
    float* obuf = (float*)(P + 40 * MB);  // 4096x1024 f32
    float* tmp  = (float*)(P + 56 * MB);  // 4096x1024 f32
    float* t1   = (float*)(P + 72 * MB);  // 4096x1024 f32
    bf16*  t2   = (bf16*)(P + 88 * MB);   // 4096x1024 bf16  [P+88, P+96)
    bf16*  wT   = (bf16*)(P + 0);         // 8192x1024 bf16 (after ln2; t0 dead)
    float* Uc   = (float*)(P + 16 * MB);  // 1024x8192 f32 chunk [P+16, P+48)
    bf16*  hb   = (bf16*)(P + 48 * MB);   // 4096x2048 bf16  [P+48, P+64)
    float* cst  = (float*)(P + 64 * MB);  // 8192 f32 scan state
    float* tmp2 = (float*)(P + 16 * MB);  // 4096x1024 f32 (Uc dead after scan)

    // ---- dtype detect + normalize all inputs to bf16 ----
    k_detect<<<1, 256, 0, stream>>>(d_in[0], flag);
    k_norm<<<2048, 256, 0, stream>>>(flag, d_in[1], memB, 524288);
    k_norm<<<1536, 256, 0, stream>>>(flag, d_in[2], sawinB, 393216);
    k_norm<<<2, 256, 0, stream>>>(flag, d_in[3], sabinB, 384);
    k_norm<<<512, 256, 0, stream>>>(flag, d_in[4], sawoutB, 131072);
    k_norm<<<1, 256, 0, stream>>>(flag, d_in[5], saboutB, 128);
    k_norm<<<1536, 256, 0, stream>>>(flag, d_in[6], cawinB, 393216);
    k_norm<<<2, 256, 0, stream>>>(flag, d_in[7], cabinB, 384);
    k_norm<<<512, 256, 0, stream>>>(flag, d_in[8], cawoutB, 131072);
    k_norm<<<1, 256, 0, stream>>>(flag, d_in[9], caboutB, 128);
    k_norm<<<1024, 256, 0, stream>>>(flag, d_in[13], lin2wB, 262144);
    k_norm<<<1, 256, 0, stream>>>(flag, d_in[14], lin2bB, 128);
    k_norm<<<2, 256, 0, stream>>>(flag, d_in[11], sruvB, 512);
    k_norm<<<2, 256, 0, stream>>>(flag, d_in[12], srubB, 512);
    k_norm<<<1, 256, 0, stream>>>(flag, d_in[15], ln1gB, 128);
    k_norm<<<1, 256, 0, stream>>>(flag, d_in[16], ln1bB, 128);
    k_norm<<<1, 256, 0, stream>>>(flag, d_in[17], ln2gB, 128);
    k_norm<<<1, 256, 0, stream>>>(flag, d_in[18], ln2bB, 128);
    k_norm<<<1, 256, 0, stream>>>(flag, d_in[19], ln3gB, 128);
    k_norm<<<1, 256, 0, stream>>>(flag, d_in[20], ln3bB, 128);

    // residual base
    k_cvt<<<2048, 256, 0, stream>>>(flag, d_in[0], t0);

    // ---- self attention ----
    k_gemm<float><<<dim3(24, 32), 256, 0, stream>>>(t0, 1024, sawinB, 1024, sabinB,
                                                    nullptr, qkv, 3072, 1024, 1024, 0.125f);
    k_attn<<<dim3(16, 16, 4), 256, 0, stream>>>(qkv, qkv + 1024, qkv + 2048, 3072, 3072, obuf);
    k_gemm<float><<<dim3(8, 32), 256, 0, stream>>>(obuf, 1024, sawoutB, 1024, saboutB,
                                                   tmp, nullptr, 1024, 1024, 0, 1.f);
    k_addln<float><<<1024, 256, 0, stream>>>(t0, tmp, ln1gB, ln1bB, t1, nullptr);

    // ---- cross attention ----
    k_gemm<float><<<dim3(8, 32), 256, 0, stream>>>(t1, 1024, cawinB, 1024, cabinB,
                                                   nullptr, qca, 1024, 1024, 1024, 0.125f);
    k_gemm<bf16><<<dim3(16, 32), 256, 0, stream>>>(memB, 1024, cawinB + (size_t)1024 * 1024, 1024,
                                                   cabinB + 1024, nullptr, kvca, 2048, 1024, 0, 1.f);
    k_attn<<<dim3(16, 16, 4), 256, 0, stream>>>(qca, kvca, kvca + 1024, 1024, 2048, obuf);
    k_gemm<float><<<dim3(8, 32), 256, 0, stream>>>(obuf, 1024, cawoutB, 1024, caboutB,
                                                   tmp, nullptr, 1024, 1024, 0, 1.f);
    k_addln<float><<<1024, 256, 0, stream>>>(t1, tmp, ln2gB, ln2bB, nullptr, t2);

    // ---- SRU (wT transpose after ln2: overlays dead t0) ----
    k_transpose<<<dim3(128, 16), 256, 0, stream>>>(flag, d_in[10], wT, 1024, 8192);
    for (int k = 0; k < 4; k++) {
        k_gemm<bf16><<<dim3(64, 8), 256, 0, stream>>>(t2 + (size_t)k * 1024 * 1024, 1024, wT, 1024,
                                                      nullptr, Uc, nullptr, 8192, 1024, 0, 1.f);
        k_sru<<<32, 256, 0, stream>>>(Uc, sruvB, srubB, hb, cst, k * 256, (k == 0) ? 1 : 0);
    }
    k_gemm<bf16><<<dim3(8, 32), 256, 0, stream>>>(hb, 2048, lin2wB, 2048, lin2bB,
                                                  tmp2, nullptr, 1024, 2048, 0, 1.f);
    // final add+LN: write FLOAT32 to d_out (reference output dtype is f32)
    k_addln<bf16><<<1024, 256, 0, stream>>>(t2, tmp2, ln3gB, ln3bB, (float*)d_out, nullptr);
}

// Round 6
// 753.511 us; speedup vs baseline: 1.3174x; 1.3174x over previous
//
#include <hip/hip_runtime.h>
#include <hip/hip_bf16.h>

typedef __bf16 bf16;
typedef bf16 bf16x8 __attribute__((ext_vector_type(8)));
typedef bf16 bf16x4 __attribute__((ext_vector_type(4)));
typedef float f32x4 __attribute__((ext_vector_type(4)));

#define MFMA16(a, b, c) __builtin_amdgcn_mfma_f32_16x16x32_bf16((a), (b), (c), 0, 0, 0)

__device__ __forceinline__ void gl_lds16(const void* g, void* l) {
    __builtin_amdgcn_global_load_lds((const __attribute__((address_space(1))) void*)g,
                                     (__attribute__((address_space(3))) void*)l, 16, 0, 0);
}

// ---------------------------------------------------------------------------
// dtype detection (inputs may be f32 or bf16; decide on-device)
__global__ __launch_bounds__(256) void k_detect(const void* __restrict__ src, int* __restrict__ flag) {
    __shared__ int cnt;
    if (threadIdx.x == 0) cnt = 0;
    __syncthreads();
    const unsigned int* w = (const unsigned int*)src;
    int local = 0;
    for (int i = threadIdx.x; i < 4096; i += 256) {
        unsigned int e = (w[i] >> 7) & 0xFF;
        local += (e > 100 && e < 150) ? 1 : 0;
    }
    atomicAdd(&cnt, local);
    __syncthreads();
    if (threadIdx.x == 0) *flag = (cnt > 2048) ? 1 : 0;
}

__global__ __launch_bounds__(256) void k_norm(const int* __restrict__ flag, const void* __restrict__ src,
                                              bf16* __restrict__ dst, int n8) {
    int i = blockIdx.x * 256 + threadIdx.x;
    if (i >= n8) return;
    if (*flag) {
        ((bf16x8*)dst)[i] = ((const bf16x8*)src)[i];
    } else {
        const float* s = (const float*)src + (size_t)i * 8;
        bf16x8 o;
#pragma unroll
        for (int j = 0; j < 8; j++) o[j] = (bf16)s[j];
        ((bf16x8*)dst)[i] = o;
    }
}

__global__ __launch_bounds__(256) void k_cvt(const int* __restrict__ flag, const void* __restrict__ in,
                                             float* __restrict__ out) {
    size_t i = (size_t)blockIdx.x * 256 + threadIdx.x;
    f32x4 a, b;
    if (*flag) {
        bf16x8 v = ((const bf16x8*)in)[i];
#pragma unroll
        for (int j = 0; j < 4; j++) { a[j] = (float)v[j]; b[j] = (float)v[4 + j]; }
    } else {
        a = ((const f32x4*)in)[i * 2];
        b = ((const f32x4*)in)[i * 2 + 1];
    }
    ((f32x4*)out)[i * 2] = a;
    ((f32x4*)out)[i * 2 + 1] = b;
}

// ---------------------------------------------------------------------------
// transpose+permute: sru_w (1024,8192) -> wT' (8192,1024) with row n'=h*4+j
// (n = j*2048+h). Makes the scan's 4 gate values per channel one float4 in U.
__global__ __launch_bounds__(256) void k_transpose(const int* __restrict__ flag, const void* __restrict__ in,
                                                   bf16* __restrict__ out, int R, int C) {
    __shared__ __align__(16) bf16 t[64][72];
    int tid = threadIdx.x;
    int c0 = blockIdx.x * 64, r0 = blockIdx.y * 64;
#pragma unroll
    for (int i = 0; i < 2; i++) {
        int idx = tid + i * 256;
        int r = idx >> 3, ch = idx & 7;
        size_t base = (size_t)(r0 + r) * C + c0 + ch * 8;
        bf16x8 v;
        if (*flag) {
            v = *(const bf16x8*)((const bf16*)in + base);
        } else {
            const float* f = (const float*)in + base;
            f32x4 x = *(const f32x4*)f, y = *(const f32x4*)(f + 4);
#pragma unroll
            for (int j = 0; j < 4; j++) { v[j] = (bf16)x[j]; v[4 + j] = (bf16)y[j]; }
        }
        *(bf16x8*)&t[r][ch * 8] = v;
    }
    __syncthreads();
    int nbase = c0 & 2047, joff = c0 >> 11;
#pragma unroll
    for (int i = 0; i < 2; i++) {
        int idx = tid + i * 256;
        int cr = idx >> 3, ch = idx & 7;
        bf16x8 v;
#pragma unroll
        for (int j = 0; j < 8; j++) v[j] = t[ch * 8 + j][cr];
        int np = (nbase + cr) * 4 + joff;  // permuted output row
        *(bf16x8*)(out + (size_t)np * R + r0 + ch * 8) = v;
    }
}

// ---------------------------------------------------------------------------
// GEMM: C[M,N] = A[M,K] @ W[N,K]^T (+bias)(*scale). 128x128 tile, BK=32.
// bf16 operands staged via global_load_lds w=16: linear LDS dest, XOR-swizzled
// per-lane SOURCE (rule: both-sides-or-neither); reads use swz().
__device__ __forceinline__ int swz(int r, int byteInRow) {
    return r * 64 + (byteInRow ^ ((r & 3) << 4));
}

template <typename AT>
__global__ __launch_bounds__(256) void k_gemm(
    const AT* __restrict__ A, int lda,
    const bf16* __restrict__ W, int ldw,
    const bf16* __restrict__ bias,
    float* __restrict__ Cf, bf16* __restrict__ Cb, int ldc,
    int K, int scale_end, float scale) {
    __shared__ __align__(16) char Asm[128 * 64];
    __shared__ __align__(16) char Bsm[128 * 64];
    int tid = threadIdx.x, w = tid >> 6, l = tid & 63, lg = l >> 4, lm = l & 15;
    int wm = w >> 1, wn = w & 1;
    int m0 = blockIdx.y * 128, n0 = blockIdx.x * 128;

    f32x4 acc[4][4] = {};

    for (int k0 = 0; k0 < K; k0 += 32) {
        if constexpr (sizeof(AT) == 4) {  // f32 A -> bf16 LDS (reg staging + convert)
#pragma unroll
            for (int i = 0; i < 4; i++) {
                int c = tid + i * 256;
                int r = c >> 3, ch = c & 7;
                f32x4 v = *(const f32x4*)(A + (size_t)(m0 + r) * lda + k0 + ch * 4);
                bf16x4 o;
#pragma unroll
                for (int j = 0; j < 4; j++) o[j] = (bf16)v[j];
                *(bf16x4*)(Asm + swz(r, ch * 8)) = o;
            }
        } else {  // bf16 A via global_load_lds (DMA)
#pragma unroll
            for (int i = 0; i < 2; i++) {
                int r = i * 64 + w * 16 + (l >> 2);
                int gs = (l & 3) ^ (r & 3);
                gl_lds16(A + (size_t)(m0 + r) * lda + k0 + gs * 8,
                         Asm + (i * 64 + w * 16) * 64);
            }
        }
#pragma unroll
        for (int i = 0; i < 2; i++) {
            int r = i * 64 + w * 16 + (l >> 2);
            int gs = (l & 3) ^ (r & 3);
            gl_lds16(W + (size_t)(n0 + r) * ldw + k0 + gs * 8,
                     Bsm + (i * 64 + w * 16) * 64);
        }
        __syncthreads();  // drains vmcnt (DMA) + lgkm (A writes)
        bf16x8 af[4], bfr[4];
#pragma unroll
        for (int i = 0; i < 4; i++)
            af[i] = *(const bf16x8*)(Asm + swz(wm * 64 + i * 16 + lm, lg * 16));
#pragma unroll
        for (int j = 0; j < 4; j++)
            bfr[j] = *(const bf16x8*)(Bsm + swz(wn * 64 + j * 16 + lm, lg * 16));
#pragma unroll
        for (int i = 0; i < 4; i++)
#pragma unroll
            for (int j = 0; j < 4; j++)
                acc[i][j] = MFMA16(af[i], bfr[j], acc[i][j]);
        __syncthreads();
    }
#pragma unroll
    for (int j = 0; j < 4; j++) {
        int col = n0 + wn * 64 + j * 16 + lm;
        float bv = bias ? (float)bias[col] : 0.f;
        float sc = (col < scale_end) ? scale : 1.f;
#pragma unroll
        for (int i = 0; i < 4; i++) {
            int row = m0 + wm * 64 + i * 16 + lg * 4;
#pragma unroll
            for (int r = 0; r < 4; r++) {
                float v = (acc[i][j][r] + bv) * sc;
                size_t idx = (size_t)(row + r) * ldc + col;
                if (Cf) Cf[idx] = v;
                if (Cb) Cb[idx] = (bf16)v;
            }
        }
    }
}

// ---------------------------------------------------------------------------
// Flash attention. Grid (h+16*b, qblk) so consecutive blocks differ in (h,b):
// each XCD keeps its 8 K/V streams L2-resident across all qblks.
// swzV XORs on d>>3 (varies per V-store lane -> full bank spread).
__device__ __forceinline__ int swz2(int row, int byteInRow) {
    return row * 128 + (byteInRow ^ ((row & 7) << 4));
}
__device__ __forceinline__ int swzV(int d, int byteInRow) {
    return d * 128 + (byteInRow ^ (((d >> 3) & 7) << 4));
}
__device__ __forceinline__ int swzP(int row, int byteInRow) {
    return row * 128 + (byteInRow ^ (((row >> 2) & 3) << 4));
}

__global__ __launch_bounds__(256) void k_attn(
    const bf16* __restrict__ Qp, const bf16* __restrict__ Kp, const bf16* __restrict__ Vp,
    int ldq, int ldk, float* __restrict__ Op) {
    int h = blockIdx.x & 15, b = blockIdx.x >> 4, qblk = blockIdx.y;
    int tid = threadIdx.x, w = tid >> 6, l = tid & 63, lg = l >> 4, lm = l & 15;
    int r0 = tid >> 3, ch = tid & 7;

    __shared__ __align__(16) char Ksm[64 * 128];
    __shared__ __align__(16) char Vsm[64 * 128];     // transposed: [dim][krow]
    __shared__ __align__(16) char Psm[4][16 * 128];  // per-wave P

    bf16x8 qf[2];
    int qrow = qblk * 64 + w * 16 + lm;
#pragma unroll
    for (int kk = 0; kk < 2; kk++)
        qf[kk] = *(const bf16x8*)(Qp + (size_t)(qrow * 4 + b) * ldq + h * 64 + kk * 32 + lg * 8);

    // prefetch tile 0 into regs
    bf16x8 kreg[2], vreg[2];
#pragma unroll
    for (int p = 0; p < 2; p++) {
        int r = r0 + p * 32;
        kreg[p] = *(const bf16x8*)(Kp + (size_t)(r * 4 + b) * ldk + h * 64 + ch * 8);
        vreg[p] = *(const bf16x8*)(Vp + (size_t)(r * 4 + b) * ldk + h * 64 + ch * 8);
    }

    f32x4 oa[4] = {};
    float mrun[4], lrun[4];
#pragma unroll
    for (int r = 0; r < 4; r++) { mrun[r] = -1e30f; lrun[r] = 0.f; }

    for (int kt = 0; kt < 16; kt++) {
        __syncthreads();  // prior compute done; safe to overwrite K/V LDS
#pragma unroll
        for (int p = 0; p < 2; p++) {
            int r = r0 + p * 32;
            *(bf16x8*)(Ksm + swz2(r, ch * 16)) = kreg[p];
#pragma unroll
            for (int j = 0; j < 8; j++)
                *(bf16*)(Vsm + swzV(ch * 8 + j, r * 2)) = vreg[p][j];  // Vt[d][r]
        }
        if (kt < 15) {  // issue next-tile loads; hidden under compute phase
#pragma unroll
            for (int p = 0; p < 2; p++) {
                int r = (kt + 1) * 64 + r0 + p * 32;
                kreg[p] = *(const bf16x8*)(Kp + (size_t)(r * 4 + b) * ldk + h * 64 + ch * 8);
                vreg[p] = *(const bf16x8*)(Vp + (size_t)(r * 4 + b) * ldk + h * 64 + ch * 8);
            }
        }
        __syncthreads();  // staging visible

        f32x4 sc[4] = {};
#pragma unroll
        for (int kk = 0; kk < 2; kk++)
#pragma unroll
            for (int jt = 0; jt < 4; jt++) {
                bf16x8 bk = *(const bf16x8*)(Ksm + swz2(jt * 16 + lm, kk * 64 + lg * 16));
                sc[jt] = MFMA16(qf[kk], bk, sc[jt]);
            }

        // online softmax; sc[jt][r]: row lg*4+r, col jt*16+lm
        float al[4], rs[4];
#pragma unroll
        for (int r = 0; r < 4; r++) {
            float m = fmaxf(fmaxf(sc[0][r], sc[1][r]), fmaxf(sc[2][r], sc[3][r]));
#pragma unroll
            for (int d = 1; d < 16; d <<= 1) m = fmaxf(m, __shfl_xor(m, d));
            float mn = fmaxf(mrun[r], m);
            al[r] = __expf(mrun[r] - mn);
            mrun[r] = mn;
            rs[r] = 0.f;
        }
#pragma unroll
        for (int jt = 0; jt < 4; jt++)
#pragma unroll
            for (int r = 0; r < 4; r++) {
                float p = __expf(sc[jt][r] - mrun[r]);
                sc[jt][r] = p;
                rs[r] += p;
            }
#pragma unroll
        for (int r = 0; r < 4; r++) {
#pragma unroll
            for (int d = 1; d < 16; d <<= 1) rs[r] += __shfl_xor(rs[r], d);
            lrun[r] = lrun[r] * al[r] + rs[r];
        }
#pragma unroll
        for (int ot = 0; ot < 4; ot++)
#pragma unroll
            for (int r = 0; r < 4; r++) oa[ot][r] *= al[r];
        // P -> per-wave LDS; wave-local fence (not a block barrier)
#pragma unroll
        for (int jt = 0; jt < 4; jt++)
#pragma unroll
            for (int r = 0; r < 4; r++)
                *(bf16*)(Psm[w] + swzP(lg * 4 + r, (jt * 16 + lm) * 2)) = (bf16)sc[jt][r];
        asm volatile("s_waitcnt lgkmcnt(0)" ::: "memory");
        __builtin_amdgcn_sched_barrier(0);
#pragma unroll
        for (int kk = 0; kk < 2; kk++) {
            bf16x8 pa = *(const bf16x8*)(Psm[w] + swzP(lm, kk * 64 + lg * 16));
#pragma unroll
            for (int ot = 0; ot < 4; ot++) {
                bf16x8 bv = *(const bf16x8*)(Vsm + swzV(ot * 16 + lm, kk * 64 + lg * 16));
                oa[ot] = MFMA16(pa, bv, oa[ot]);
            }
        }
    }
#pragma unroll
    for (int r = 0; r < 4; r++) {
        float inv = 1.f / lrun[r];
        int srow = qblk * 64 + w * 16 + lg * 4 + r;
#pragma unroll
        for (int ot = 0; ot < 4; ot++) {
            int col = h * 64 + ot * 16 + lm;
            Op[(size_t)(srow * 4 + b) * 1024 + col] = oa[ot][r] * inv;
        }
    }
}

// ---------------------------------------------------------------------------
// residual-add + LayerNorm over D=1024. X dtype templated.
template <typename XT>
__global__ __launch_bounds__(256) void k_addln(
    const XT* __restrict__ X, const float* __restrict__ Yd,
    const bf16* __restrict__ g, const bf16* __restrict__ bb,
    float* __restrict__ outF, bf16* __restrict__ outB) {
    int row = blockIdx.x * 4 + (threadIdx.x >> 6);
    int l = threadIdx.x & 63;
    const XT* xr = X + (size_t)row * 1024;
    const float* yr = Yd + (size_t)row * 1024;
    float v[16];
    float s = 0.f, s2 = 0.f;
#pragma unroll
    for (int q = 0; q < 4; q++) {
        float xa[4];
        if constexpr (sizeof(XT) == 4) {
            f32x4 a = *(const f32x4*)(xr + l * 4 + q * 256);
#pragma unroll
            for (int j = 0; j < 4; j++) xa[j] = a[j];
        } else {
            bf16x4 a = *(const bf16x4*)(xr + l * 4 + q * 256);
#pragma unroll
            for (int j = 0; j < 4; j++) xa[j] = (float)a[j];
        }
        f32x4 c = *(const f32x4*)(yr + l * 4 + q * 256);
#pragma unroll
        for (int j = 0; j < 4; j++) {
            float t = xa[j] + c[j];
            v[q * 4 + j] = t;
            s += t;
            s2 += t * t;
        }
    }
#pragma unroll
    for (int d = 1; d < 64; d <<= 1) { s += __shfl_xor(s, d); s2 += __shfl_xor(s2, d); }
    float mu = s * (1.f / 1024.f);
    float var = s2 * (1.f / 1024.f) - mu * mu;
    float rstd = rsqrtf(var + 1e-5f);
#pragma unroll
    for (int q = 0; q < 4; q++)
#pragma unroll
        for (int j = 0; j < 4; j++) {
            int col = l * 4 + q * 256 + j;
            float y = (v[q * 4 + j] - mu) * rstd * (float)g[col] + (float)bb[col];
            if (outF) outF[(size_t)row * 1024 + col] = y;
            if (outB) outB[(size_t)row * 1024 + col] = (bf16)y;
        }
}

// ---------------------------------------------------------------------------
// SRU scan chunk (256 steps). U interleaved: U[(ls*4+b)*8192 + hh*4 + j] so one
// float4 per step. Step stride = 4 rows * 8192 f32 = 8192 f32x4 units.
// Depth-8 statically-indexed prefetch ring hides latency.
__global__ __launch_bounds__(256) void k_sru(
    const float* __restrict__ U, const bf16* __restrict__ v2, const bf16* __restrict__ b2,
    bf16* __restrict__ Hb, float* __restrict__ cst, int s0, int init) {
    int ch = blockIdx.x * 256 + threadIdx.x;  // 0..8191
    int b = ch >> 11, hh = ch & 2047;
    float vf = (float)v2[hh], vr = (float)v2[2048 + hh];
    float bfv = (float)b2[hh], brv = (float)b2[2048 + hh];
    float c = init ? 0.f : cst[ch];
    const f32x4* u = (const f32x4*)(U + (size_t)b * 8192 + (size_t)hh * 4);  // +8192 f32x4/step
    bf16* ho = Hb + ((size_t)s0 * 4 + b) * 2048 + hh;                        // +8192 elem/step
    f32x4 q[8];
#pragma unroll
    for (int i = 0; i < 8; i++) q[i] = u[(size_t)i * 8192];
    for (int it = 0; it < 32; it++) {
#pragma unroll
        for (int j = 0; j < 8; j++) {
            int ls = it * 8 + j;
            f32x4 v = q[j];
            if (ls + 8 < 256) q[j] = u[(size_t)(ls + 8) * 8192];
            float f = 1.f / (1.f + __expf(-(v[1] + vf * c + bfv)));
            float r = 1.f / (1.f + __expf(-(v[2] + vr * c + brv)));
            c = f * c + (1.f - f) * v[0];
            float hv = r * c + (1.f - r) * v[3];
            ho[(size_t)ls * 8192] = (bf16)hv;
        }
    }
    cst[ch] = c;
}

// ---------------------------------------------------------------------------
extern "C" void kernel_launch(void* const* d_in, const int* in_sizes, int n_in,
                              void* d_out, int out_size, void* d_ws, size_t ws_size,
                              hipStream_t stream) {
    const size_t MB = 1u << 20;
    char* ws = (char*)d_ws;

    bf16* memB    = (bf16*)(ws + 0);        // 4096x1024
    bf16* sawinB  = (bf16*)(ws + 8 * MB);   // 3072x1024
    bf16* sawoutB = (bf16*)(ws + 14 * MB);  // 1024x1024
    bf16* cawinB  = (bf16*)(ws + 16 * MB);  // 3072x1024
    bf16* cawoutB = (bf16*)(ws + 22 * MB);  // 1024x1024
    bf16* lin2wB  = (bf16*)(ws + 24 * MB);  // 1024x2048
    char* S0 = ws + 28 * MB;
    bf16* sabinB  = (bf16*)(S0 + 0 * 8192);
    bf16* cabinB  = (bf16*)(S0 + 1 * 8192);
    bf16* saboutB = (bf16*)(S0 + 2 * 8192);
    bf16* caboutB = (bf16*)(S0 + 3 * 8192);
    bf16* lin2bB  = (bf16*)(S0 + 4 * 8192);
    bf16* sruvB   = (bf16*)(S0 + 5 * 8192);
    bf16* srubB   = (bf16*)(S0 + 6 * 8192);
    bf16* ln1gB   = (bf16*)(S0 + 7 * 8192);
    bf16* ln1bB   = (bf16*)(S0 + 8 * 8192);
    bf16* ln2gB   = (bf16*)(S0 + 9 * 8192);
    bf16* ln2bB   = (bf16*)(S0 + 10 * 8192);
    bf16* ln3gB   = (bf16*)(S0 + 11 * 8192);
    bf16* ln3bB   = (bf16*)(S0 + 12 * 8192);
    int*  flag    = (int*)(S0 + 13 * 8192);

    char* P = ws + 29 * MB;
    float* t0   = (float*)(P + 0);        // 4096x1024 f32
    bf16*  qkv  = (bf16*)(P + 16 * MB);   // 4096x3072 bf16
    bf16*  qca  = qkv;
    bf16*  kvca = (bf16*)(P + 24 * MB);   // 4096x2048 bf16
    float* obuf = (float*)(P + 40 * MB);  // 4096x1024 f32
    float* tmp  = (float*)(P + 56 * MB);  // 4096x1024 f32
    float* t1   = (float*)(P + 72 * MB);  // 4096x1024 f32
    bf16*  t2   = (bf16*)(P + 88 * MB);   // 4096x1024 bf16
    bf16*  wT   = (bf16*)(P + 0);         // 8192x1024 bf16 (overlays dead t0)
    float* Uc   = (float*)(P + 16 * MB);  // 1024x8192 f32 chunk
    bf16*  hb   = (bf16*)(P + 48 * MB);   // 4096x2048 bf16
    float* cst  = (float*)(P + 64 * MB);  // 8192 f32
    float* tmp2 = (float*)(P + 16 * MB);  // 4096x1024 f32 (Uc dead)

    k_detect<<<1, 256, 0, stream>>>(d_in[0], flag);
    k_norm<<<2048, 256, 0, stream>>>(flag, d_in[1], memB, 524288);
    k_norm<<<1536, 256, 0, stream>>>(flag, d_in[2], sawinB, 393216);
    k_norm<<<2, 256, 0, stream>>>(flag, d_in[3], sabinB, 384);
    k_norm<<<512, 256, 0, stream>>>(flag, d_in[4], sawoutB, 131072);
    k_norm<<<1, 256, 0, stream>>>(flag, d_in[5], saboutB, 128);
    k_norm<<<1536, 256, 0, stream>>>(flag, d_in[6], cawinB, 393216);
    k_norm<<<2, 256, 0, stream>>>(flag, d_in[7], cabinB, 384);
    k_norm<<<512, 256, 0, stream>>>(flag, d_in[8], cawoutB, 131072);
    k_norm<<<1, 256, 0, stream>>>(flag, d_in[9], caboutB, 128);
    k_norm<<<1024, 256, 0, stream>>>(flag, d_in[13], lin2wB, 262144);
    k_norm<<<1, 256, 0, stream>>>(flag, d_in[14], lin2bB, 128);
    k_norm<<<2, 256, 0, stream>>>(flag, d_in[11], sruvB, 512);
    k_norm<<<2, 256, 0, stream>>>(flag, d_in[12], srubB, 512);
    k_norm<<<1, 256, 0, stream>>>(flag, d_in[15], ln1gB, 128);
    k_norm<<<1, 256, 0, stream>>>(flag, d_in[16], ln1bB, 128);
    k_norm<<<1, 256, 0, stream>>>(flag, d_in[17], ln2gB, 128);
    k_norm<<<1, 256, 0, stream>>>(flag, d_in[18], ln2bB, 128);
    k_norm<<<1, 256, 0, stream>>>(flag, d_in[19], ln3gB, 128);
    k_norm<<<1, 256, 0, stream>>>(flag, d_in[20], ln3bB, 128);

    k_cvt<<<2048, 256, 0, stream>>>(flag, d_in[0], t0);

    // ---- self attention ----
    k_gemm<float><<<dim3(24, 32), 256, 0, stream>>>(t0, 1024, sawinB, 1024, sabinB,
                                                    nullptr, qkv, 3072, 1024, 1024, 0.125f);
    k_attn<<<dim3(64, 16), 256, 0, stream>>>(qkv, qkv + 1024, qkv + 2048, 3072, 3072, obuf);
    k_gemm<float><<<dim3(8, 32), 256, 0, stream>>>(obuf, 1024, sawoutB, 1024, saboutB,
                                                   tmp, nullptr, 1024, 1024, 0, 1.f);
    k_addln<float><<<1024, 256, 0, stream>>>(t0, tmp, ln1gB, ln1bB, t1, nullptr);

    // ---- cross attention ----
    k_gemm<float><<<dim3(8, 32), 256, 0, stream>>>(t1, 1024, cawinB, 1024, cabinB,
                                                   nullptr, qca, 1024, 1024, 1024, 0.125f);
    k_gemm<bf16><<<dim3(16, 32), 256, 0, stream>>>(memB, 1024, cawinB + (size_t)1024 * 1024, 1024,
                                                   cabinB + 1024, nullptr, kvca, 2048, 1024, 0, 1.f);
    k_attn<<<dim3(64, 16), 256, 0, stream>>>(qca, kvca, kvca + 1024, 1024, 2048, obuf);
    k_gemm<float><<<dim3(8, 32), 256, 0, stream>>>(obuf, 1024, cawoutB, 1024, caboutB,
                                                   tmp, nullptr, 1024, 1024, 0, 1.f);
    k_addln<float><<<1024, 256, 0, stream>>>(t1, tmp, ln2gB, ln2bB, nullptr, t2);

    // ---- SRU ----
    k_transpose<<<dim3(128, 16), 256, 0, stream>>>(flag, d_in[10], wT, 1024, 8192);
    for (int k = 0; k < 4; k++) {
        k_gemm<bf16><<<dim3(64, 8), 256, 0, stream>>>(t2 + (size_t)k * 1024 * 1024, 1024, wT, 1024,
                                                      nullptr, Uc, nullptr, 8192, 1024, 0, 1.f);
        k_sru<<<32, 256, 0, stream>>>(Uc, sruvB, srubB, hb, cst, k * 256, (k == 0) ? 1 : 0);
    }
    k_gemm<bf16><<<dim3(8, 32), 256, 0, stream>>>(hb, 2048, lin2wB, 2048, lin2bB,
                                                  tmp2, nullptr, 1024, 2048, 0, 1.f);
    k_addln<bf16><<<1024, 256, 0, stream>>>(t2, tmp2, ln3gB, ln3bB, (float*)d_out, nullptr);
}

// Round 7
// 687.972 us; speedup vs baseline: 1.4429x; 1.0953x over previous
//
#include <hip/hip_runtime.h>
#include <hip/hip_bf16.h>

typedef __bf16 bf16;
typedef bf16 bf16x8 __attribute__((ext_vector_type(8)));
typedef bf16 bf16x4 __attribute__((ext_vector_type(4)));
typedef float f32x4 __attribute__((ext_vector_type(4)));

#define MFMA16(a, b, c) __builtin_amdgcn_mfma_f32_16x16x32_bf16((a), (b), (c), 0, 0, 0)

__device__ __forceinline__ void gl_lds16(const void* g, void* l) {
    __builtin_amdgcn_global_load_lds((const __attribute__((address_space(1))) void*)g,
                                     (__attribute__((address_space(3))) void*)l, 16, 0, 0);
}

// ---------------------------------------------------------------------------
// dtype detection (inputs may be f32 or bf16; decide on-device)
__global__ __launch_bounds__(256) void k_detect(const void* __restrict__ src, int* __restrict__ flag) {
    __shared__ int cnt;
    if (threadIdx.x == 0) cnt = 0;
    __syncthreads();
    const unsigned int* w = (const unsigned int*)src;
    int local = 0;
    for (int i = threadIdx.x; i < 4096; i += 256) {
        unsigned int e = (w[i] >> 7) & 0xFF;
        local += (e > 100 && e < 150) ? 1 : 0;
    }
    atomicAdd(&cnt, local);
    __syncthreads();
    if (threadIdx.x == 0) *flag = (cnt > 2048) ? 1 : 0;
}

__global__ __launch_bounds__(256) void k_norm(const int* __restrict__ flag, const void* __restrict__ src,
                                              bf16* __restrict__ dst, int n8) {
    int i = blockIdx.x * 256 + threadIdx.x;
    if (i >= n8) return;
    if (*flag) {
        ((bf16x8*)dst)[i] = ((const bf16x8*)src)[i];
    } else {
        const float* s = (const float*)src + (size_t)i * 8;
        bf16x8 o;
#pragma unroll
        for (int j = 0; j < 8; j++) o[j] = (bf16)s[j];
        ((bf16x8*)dst)[i] = o;
    }
}

// all 13 small tensors in one launch; block b handles segment b.
struct SmallSegs {
    const void* src[13];
    bf16* dst[13];
    int n8[13];
};
__global__ __launch_bounds__(256) void k_norm_multi(const int* __restrict__ flag, SmallSegs s) {
    int seg = blockIdx.x;
    const void* sp = s.src[seg];
    bf16* dp = s.dst[seg];
    int n = s.n8[seg];
    int f = *flag;
    for (int i = threadIdx.x; i < n; i += 256) {
        if (f) {
            ((bf16x8*)dp)[i] = ((const bf16x8*)sp)[i];
        } else {
            const float* fs = (const float*)sp + (size_t)i * 8;
            bf16x8 o;
#pragma unroll
            for (int j = 0; j < 8; j++) o[j] = (bf16)fs[j];
            ((bf16x8*)dp)[i] = o;
        }
    }
}

__global__ __launch_bounds__(256) void k_cvt(const int* __restrict__ flag, const void* __restrict__ in,
                                             float* __restrict__ out) {
    size_t i = (size_t)blockIdx.x * 256 + threadIdx.x;
    f32x4 a, b;
    if (*flag) {
        bf16x8 v = ((const bf16x8*)in)[i];
#pragma unroll
        for (int j = 0; j < 4; j++) { a[j] = (float)v[j]; b[j] = (float)v[4 + j]; }
    } else {
        a = ((const f32x4*)in)[i * 2];
        b = ((const f32x4*)in)[i * 2 + 1];
    }
    ((f32x4*)out)[i * 2] = a;
    ((f32x4*)out)[i * 2 + 1] = b;
}

// ---------------------------------------------------------------------------
// transpose+permute: sru_w (1024,8192) -> wT' (8192,1024) with row n'=h*4+j
// (n = j*2048+h). Makes the scan's 4 gate values per channel one float4 in U.
__global__ __launch_bounds__(256) void k_transpose(const int* __restrict__ flag, const void* __restrict__ in,
                                                   bf16* __restrict__ out, int R, int C) {
    __shared__ __align__(16) bf16 t[64][72];
    int tid = threadIdx.x;
    int c0 = blockIdx.x * 64, r0 = blockIdx.y * 64;
#pragma unroll
    for (int i = 0; i < 2; i++) {
        int idx = tid + i * 256;
        int r = idx >> 3, ch = idx & 7;
        size_t base = (size_t)(r0 + r) * C + c0 + ch * 8;
        bf16x8 v;
        if (*flag) {
            v = *(const bf16x8*)((const bf16*)in + base);
        } else {
            const float* f = (const float*)in + base;
            f32x4 x = *(const f32x4*)f, y = *(const f32x4*)(f + 4);
#pragma unroll
            for (int j = 0; j < 4; j++) { v[j] = (bf16)x[j]; v[4 + j] = (bf16)y[j]; }
        }
        *(bf16x8*)&t[r][ch * 8] = v;
    }
    __syncthreads();
    int nbase = c0 & 2047, joff = c0 >> 11;
#pragma unroll
    for (int i = 0; i < 2; i++) {
        int idx = tid + i * 256;
        int cr = idx >> 3, ch = idx & 7;
        bf16x8 v;
#pragma unroll
        for (int j = 0; j < 8; j++) v[j] = t[ch * 8 + j][cr];
        int np = (nbase + cr) * 4 + joff;  // permuted output row
        *(bf16x8*)(out + (size_t)np * R + r0 + ch * 8) = v;
    }
}

// ---------------------------------------------------------------------------
// GEMM: C[M,N] = A[M,K] @ W[N,K]^T (+bias)(*scale). 128x128 tile, BK=64.
// LDS rows 128B with 8-way XOR swizzle ((r&7)<<4). bf16 staged via
// global_load_lds w=16: linear LDS dest, inverse-swizzled per-lane SOURCE.
__device__ __forceinline__ int swzB(int r, int byteInRow) {
    return r * 128 + (byteInRow ^ ((r & 7) << 4));
}

template <typename AT>
__global__ __launch_bounds__(256) void k_gemm(
    const AT* __restrict__ A, int lda,
    const bf16* __restrict__ W, int ldw,
    const bf16* __restrict__ bias,
    float* __restrict__ Cf, bf16* __restrict__ Cb, int ldc,
    int K, int scale_end, float scale) {
    __shared__ __align__(16) char Asm[128 * 128];
    __shared__ __align__(16) char Bsm[128 * 128];
    int tid = threadIdx.x, w = tid >> 6, l = tid & 63, lg = l >> 4, lm = l & 15;
    int wm = w >> 1, wn = w & 1;
    int m0 = blockIdx.y * 128, n0 = blockIdx.x * 128;

    f32x4 acc[4][4] = {};

    for (int k0 = 0; k0 < K; k0 += 64) {
        if constexpr (sizeof(AT) == 4) {  // f32 A -> bf16 LDS (reg staging + convert)
#pragma unroll
            for (int i = 0; i < 8; i++) {
                int c = tid + i * 256;          // 0..2047
                int r = c >> 4, ch = c & 15;    // row, 4-f32 chunk (16B global)
                f32x4 v = *(const f32x4*)(A + (size_t)(m0 + r) * lda + k0 + ch * 4);
                bf16x4 o;
#pragma unroll
                for (int j = 0; j < 4; j++) o[j] = (bf16)v[j];
                *(bf16x4*)(Asm + swzB(r, ch * 8)) = o;
            }
        } else {  // bf16 A via global_load_lds: instr i covers rows i*32+w*8+(l>>3)
#pragma unroll
            for (int i = 0; i < 4; i++) {
                int r = i * 32 + w * 8 + (l >> 3);
                int gs = (l & 7) ^ (r & 7);    // physical chunk l&7 holds logical (l&7)^(r&7)
                gl_lds16(A + (size_t)(m0 + r) * lda + k0 + gs * 8,
                         Asm + (i * 32 + w * 8) * 128);
            }
        }
#pragma unroll
        for (int i = 0; i < 4; i++) {
            int r = i * 32 + w * 8 + (l >> 3);
            int gs = (l & 7) ^ (r & 7);
            gl_lds16(W + (size_t)(n0 + r) * ldw + k0 + gs * 8,
                     Bsm + (i * 32 + w * 8) * 128);
        }
        __syncthreads();  // drains vmcnt (DMA) + lgkm
#pragma unroll
        for (int kh = 0; kh < 2; kh++) {
            bf16x8 af[4], bfr[4];
#pragma unroll
            for (int i = 0; i < 4; i++)
                af[i] = *(const bf16x8*)(Asm + swzB(wm * 64 + i * 16 + lm, kh * 64 + lg * 16));
#pragma unroll
            for (int j = 0; j < 4; j++)
                bfr[j] = *(const bf16x8*)(Bsm + swzB(wn * 64 + j * 16 + lm, kh * 64 + lg * 16));
#pragma unroll
            for (int i = 0; i < 4; i++)
#pragma unroll
                for (int j = 0; j < 4; j++)
                    acc[i][j] = MFMA16(af[i], bfr[j], acc[i][j]);
        }
        __syncthreads();
    }
#pragma unroll
    for (int j = 0; j < 4; j++) {
        int col = n0 + wn * 64 + j * 16 + lm;
        float bv = bias ? (float)bias[col] : 0.f;
        float sc = (col < scale_end) ? scale : 1.f;
#pragma unroll
        for (int i = 0; i < 4; i++) {
            int row = m0 + wm * 64 + i * 16 + lg * 4;
#pragma unroll
            for (int r = 0; r < 4; r++) {
                float v = (acc[i][j][r] + bv) * sc;
                size_t idx = (size_t)(row + r) * ldc + col;
                if (Cf) Cf[idx] = v;
                if (Cb) Cb[idx] = (bf16)v;
            }
        }
    }
}

// ---------------------------------------------------------------------------
// Flash attention. Grid (h+16*b, qblk) so consecutive blocks differ in (h,b):
// each XCD keeps its 8 K/V streams L2-resident across all qblks.
__device__ __forceinline__ int swz2(int row, int byteInRow) {
    return row * 128 + (byteInRow ^ ((row & 7) << 4));
}
__device__ __forceinline__ int swzV(int d, int byteInRow) {
    return d * 128 + (byteInRow ^ (((d >> 3) & 7) << 4));
}
__device__ __forceinline__ int swzP(int row, int byteInRow) {
    return row * 128 + (byteInRow ^ (((row >> 2) & 3) << 4));
}

__global__ __launch_bounds__(256) void k_attn(
    const bf16* __restrict__ Qp, const bf16* __restrict__ Kp, const bf16* __restrict__ Vp,
    int ldq, int ldk, float* __restrict__ Op) {
    int h = blockIdx.x & 15, b = blockIdx.x >> 4, qblk = blockIdx.y;
    int tid = threadIdx.x, w = tid >> 6, l = tid & 63, lg = l >> 4, lm = l & 15;
    int r0 = tid >> 3, ch = tid & 7;

    __shared__ __align__(16) char Ksm[64 * 128];
    __shared__ __align__(16) char Vsm[64 * 128];     // transposed: [dim][krow]
    __shared__ __align__(16) char Psm[4][16 * 128];  // per-wave P

    bf16x8 qf[2];
    int qrow = qblk * 64 + w * 16 + lm;
#pragma unroll
    for (int kk = 0; kk < 2; kk++)
        qf[kk] = *(const bf16x8*)(Qp + (size_t)(qrow * 4 + b) * ldq + h * 64 + kk * 32 + lg * 8);

    // prefetch tile 0 into regs
    bf16x8 kreg[2], vreg[2];
#pragma unroll
    for (int p = 0; p < 2; p++) {
        int r = r0 + p * 32;
        kreg[p] = *(const bf16x8*)(Kp + (size_t)(r * 4 + b) * ldk + h * 64 + ch * 8);
        vreg[p] = *(const bf16x8*)(Vp + (size_t)(r * 4 + b) * ldk + h * 64 + ch * 8);
    }

    f32x4 oa[4] = {};
    float mrun[4], lrun[4];
#pragma unroll
    for (int r = 0; r < 4; r++) { mrun[r] = -1e30f; lrun[r] = 0.f; }

    for (int kt = 0; kt < 16; kt++) {
        __syncthreads();  // prior compute done; safe to overwrite K/V LDS
#pragma unroll
        for (int p = 0; p < 2; p++) {
            int r = r0 + p * 32;
            *(bf16x8*)(Ksm + swz2(r, ch * 16)) = kreg[p];
#pragma unroll
            for (int j = 0; j < 8; j++)
                *(bf16*)(Vsm + swzV(ch * 8 + j, r * 2)) = vreg[p][j];  // Vt[d][r]
        }
        if (kt < 15) {  // issue next-tile loads; hidden under compute phase
#pragma unroll
            for (int p = 0; p < 2; p++) {
                int r = (kt + 1) * 64 + r0 + p * 32;
                kreg[p] = *(const bf16x8*)(Kp + (size_t)(r * 4 + b) * ldk + h * 64 + ch * 8);
                vreg[p] = *(const bf16x8*)(Vp + (size_t)(r * 4 + b) * ldk + h * 64 + ch * 8);
            }
        }
        __syncthreads();  // staging visible

        f32x4 sc[4] = {};
#pragma unroll
        for (int kk = 0; kk < 2; kk++)
#pragma unroll
            for (int jt = 0; jt < 4; jt++) {
                bf16x8 bk = *(const bf16x8*)(Ksm + swz2(jt * 16 + lm, kk * 64 + lg * 16));
                sc[jt] = MFMA16(qf[kk], bk, sc[jt]);
            }

        // online softmax; sc[jt][r]: row lg*4+r, col jt*16+lm
        float al[4], rs[4];
#pragma unroll
        for (int r = 0; r < 4; r++) {
            float m = fmaxf(fmaxf(sc[0][r], sc[1][r]), fmaxf(sc[2][r], sc[3][r]));
#pragma unroll
            for (int d = 1; d < 16; d <<= 1) m = fmaxf(m, __shfl_xor(m, d));
            float mn = fmaxf(mrun[r], m);
            al[r] = __expf(mrun[r] - mn);
            mrun[r] = mn;
            rs[r] = 0.f;
        }
#pragma unroll
        for (int jt = 0; jt < 4; jt++)
#pragma unroll
            for (int r = 0; r < 4; r++) {
                float p = __expf(sc[jt][r] - mrun[r]);
                sc[jt][r] = p;
                rs[r] += p;
            }
#pragma unroll
        for (int r = 0; r < 4; r++) {
#pragma unroll
            for (int d = 1; d < 16; d <<= 1) rs[r] += __shfl_xor(rs[r], d);
            lrun[r] = lrun[r] * al[r] + rs[r];
        }
#pragma unroll
        for (int ot = 0; ot < 4; ot++)
#pragma unroll
            for (int r = 0; r < 4; r++) oa[ot][r] *= al[r];
        // P -> per-wave LDS; wave-local fence (not a block barrier)
#pragma unroll
        for (int jt = 0; jt < 4; jt++)
#pragma unroll
            for (int r = 0; r < 4; r++)
                *(bf16*)(Psm[w] + swzP(lg * 4 + r, (jt * 16 + lm) * 2)) = (bf16)sc[jt][r];
        asm volatile("s_waitcnt lgkmcnt(0)" ::: "memory");
        __builtin_amdgcn_sched_barrier(0);
#pragma unroll
        for (int kk = 0; kk < 2; kk++) {
            bf16x8 pa = *(const bf16x8*)(Psm[w] + swzP(lm, kk * 64 + lg * 16));
#pragma unroll
            for (int ot = 0; ot < 4; ot++) {
                bf16x8 bv = *(const bf16x8*)(Vsm + swzV(ot * 16 + lm, kk * 64 + lg * 16));
                oa[ot] = MFMA16(pa, bv, oa[ot]);
            }
        }
    }
#pragma unroll
    for (int r = 0; r < 4; r++) {
        float inv = 1.f / lrun[r];
        int srow = qblk * 64 + w * 16 + lg * 4 + r;
#pragma unroll
        for (int ot = 0; ot < 4; ot++) {
            int col = h * 64 + ot * 16 + lm;
            Op[(size_t)(srow * 4 + b) * 1024 + col] = oa[ot][r] * inv;
        }
    }
}

// ---------------------------------------------------------------------------
// residual-add + LayerNorm over D=1024. X dtype templated.
template <typename XT>
__global__ __launch_bounds__(256) void k_addln(
    const XT* __restrict__ X, const float* __restrict__ Yd,
    const bf16* __restrict__ g, const bf16* __restrict__ bb,
    float* __restrict__ outF, bf16* __restrict__ outB) {
    int row = blockIdx.x * 4 + (threadIdx.x >> 6);
    int l = threadIdx.x & 63;
    const XT* xr = X + (size_t)row * 1024;
    const float* yr = Yd + (size_t)row * 1024;
    float v[16];
    float s = 0.f, s2 = 0.f;
#pragma unroll
    for (int q = 0; q < 4; q++) {
        float xa[4];
        if constexpr (sizeof(XT) == 4) {
            f32x4 a = *(const f32x4*)(xr + l * 4 + q * 256);
#pragma unroll
            for (int j = 0; j < 4; j++) xa[j] = a[j];
        } else {
            bf16x4 a = *(const bf16x4*)(xr + l * 4 + q * 256);
#pragma unroll
            for (int j = 0; j < 4; j++) xa[j] = (float)a[j];
        }
        f32x4 c = *(const f32x4*)(yr + l * 4 + q * 256);
#pragma unroll
        for (int j = 0; j < 4; j++) {
            float t = xa[j] + c[j];
            v[q * 4 + j] = t;
            s += t;
            s2 += t * t;
        }
    }
#pragma unroll
    for (int d = 1; d < 64; d <<= 1) { s += __shfl_xor(s, d); s2 += __shfl_xor(s2, d); }
    float mu = s * (1.f / 1024.f);
    float var = s2 * (1.f / 1024.f) - mu * mu;
    float rstd = rsqrtf(var + 1e-5f);
#pragma unroll
    for (int q = 0; q < 4; q++)
#pragma unroll
        for (int j = 0; j < 4; j++) {
            int col = l * 4 + q * 256 + j;
            float y = (v[q * 4 + j] - mu) * rstd * (float)g[col] + (float)bb[col];
            if (outF) outF[(size_t)row * 1024 + col] = y;
            if (outB) outB[(size_t)row * 1024 + col] = (bf16)y;
        }
}

// ---------------------------------------------------------------------------
// SRU scan chunk (256 steps). U interleaved: U[(ls*4+b)*8192 + hh*4 + j] so one
// float4 per step (step stride 8192 f32x4). 64-thread blocks x128: spread over
// 128 CUs for 4x the aggregate HBM BW of the old 32-block shape.
__global__ __launch_bounds__(64) void k_sru(
    const float* __restrict__ U, const bf16* __restrict__ v2, const bf16* __restrict__ b2,
    bf16* __restrict__ Hb, float* __restrict__ cst, int s0, int init) {
    int ch = blockIdx.x * 64 + threadIdx.x;  // 0..8191
    int b = ch >> 11, hh = ch & 2047;
    float vf = (float)v2[hh], vr = (float)v2[2048 + hh];
    float bfv = (float)b2[hh], brv = (float)b2[2048 + hh];
    float c = init ? 0.f : cst[ch];
    const f32x4* u = (const f32x4*)(U + (size_t)b * 8192 + (size_t)hh * 4);
    bf16* ho = Hb + ((size_t)s0 * 4 + b) * 2048 + hh;
    f32x4 q[8];
#pragma unroll
    for (int i = 0; i < 8; i++) q[i] = u[(size_t)i * 8192];
    for (int it = 0; it < 32; it++) {
#pragma unroll
        for (int j = 0; j < 8; j++) {
            int ls = it * 8 + j;
            f32x4 v = q[j];
            if (ls + 8 < 256) q[j] = u[(size_t)(ls + 8) * 8192];
            float f = 1.f / (1.f + __expf(-(v[1] + vf * c + bfv)));
            float r = 1.f / (1.f + __expf(-(v[2] + vr * c + brv)));
            c = f * c + (1.f - f) * v[0];
            float hv = r * c + (1.f - r) * v[3];
            ho[(size_t)ls * 8192] = (bf16)hv;
        }
    }
    cst[ch] = c;
}

// ---------------------------------------------------------------------------
extern "C" void kernel_launch(void* const* d_in, const int* in_sizes, int n_in,
                              void* d_out, int out_size, void* d_ws, size_t ws_size,
                              hipStream_t stream) {
    const size_t MB = 1u << 20;
    char* ws = (char*)d_ws;

    bf16* memB    = (bf16*)(ws + 0);        // 4096x1024
    bf16* sawinB  = (bf16*)(ws + 8 * MB);   // 3072x1024
    bf16* sawoutB = (bf16*)(ws + 14 * MB);  // 1024x1024
    bf16* cawinB  = (bf16*)(ws + 16 * MB);  // 3072x1024
    bf16* cawoutB = (bf16*)(ws + 22 * MB);  // 1024x1024
    bf16* lin2wB  = (bf16*)(ws + 24 * MB);  // 1024x2048
    char* S0 = ws + 28 * MB;
    bf16* sabinB  = (bf16*)(S0 + 0 * 8192);
    bf16* cabinB  = (bf16*)(S0 + 1 * 8192);
    bf16* saboutB = (bf16*)(S0 + 2 * 8192);
    bf16* caboutB = (bf16*)(S0 + 3 * 8192);
    bf16* lin2bB  = (bf16*)(S0 + 4 * 8192);
    bf16* sruvB   = (bf16*)(S0 + 5 * 8192);
    bf16* srubB   = (bf16*)(S0 + 6 * 8192);
    bf16* ln1gB   = (bf16*)(S0 + 7 * 8192);
    bf16* ln1bB   = (bf16*)(S0 + 8 * 8192);
    bf16* ln2gB   = (bf16*)(S0 + 9 * 8192);
    bf16* ln2bB   = (bf16*)(S0 + 10 * 8192);
    bf16* ln3gB   = (bf16*)(S0 + 11 * 8192);
    bf16* ln3bB   = (bf16*)(S0 + 12 * 8192);
    int*  flag    = (int*)(S0 + 13 * 8192);

    char* P = ws + 29 * MB;
    float* t0   = (float*)(P + 0);        // 4096x1024 f32
    bf16*  qkv  = (bf16*)(P + 16 * MB);   // 4096x3072 bf16
    bf16*  qca  = qkv;
    bf16*  kvca = (bf16*)(P + 24 * MB);   // 4096x2048 bf16
    float* obuf = (float*)(P + 40 * MB);  // 4096x1024 f32
    float* tmp  = (float*)(P + 56 * MB);  // 4096x1024 f32
    float* t1   = (float*)(P + 72 * MB);  // 4096x1024 f32
    bf16*  t2   = (bf16*)(P + 88 * MB);   // 4096x1024 bf16
    bf16*  wT   = (bf16*)(P + 0);         // 8192x1024 bf16 (overlays dead t0)
    float* Uc   = (float*)(P + 16 * MB);  // 1024x8192 f32 chunk
    bf16*  hb   = (bf16*)(P + 48 * MB);   // 4096x2048 bf16
    float* cst  = (float*)(P + 64 * MB);  // 8192 f32
    float* tmp2 = (float*)(P + 16 * MB);  // 4096x1024 f32 (Uc dead)

    k_detect<<<1, 256, 0, stream>>>(d_in[0], flag);
    // big normalizations (6 launches)
    k_norm<<<2048, 256, 0, stream>>>(flag, d_in[1], memB, 524288);
    k_norm<<<1536, 256, 0, stream>>>(flag, d_in[2], sawinB, 393216);
    k_norm<<<512, 256, 0, stream>>>(flag, d_in[4], sawoutB, 131072);
    k_norm<<<1536, 256, 0, stream>>>(flag, d_in[6], cawinB, 393216);
    k_norm<<<512, 256, 0, stream>>>(flag, d_in[8], cawoutB, 131072);
    k_norm<<<1024, 256, 0, stream>>>(flag, d_in[13], lin2wB, 262144);
    // 13 small tensors in one launch
    SmallSegs sg;
    const int srcIdx[13] = {3, 7, 5, 9, 14, 11, 12, 15, 16, 17, 18, 19, 20};
    bf16* dsts[13] = {sabinB, cabinB, saboutB, caboutB, lin2bB, sruvB, srubB,
                      ln1gB, ln1bB, ln2gB, ln2bB, ln3gB, ln3bB};
    const int n8s[13] = {384, 384, 128, 128, 128, 512, 512, 128, 128, 128, 128, 128, 128};
    for (int i = 0; i < 13; i++) { sg.src[i] = d_in[srcIdx[i]]; sg.dst[i] = dsts[i]; sg.n8[i] = n8s[i]; }
    k_norm_multi<<<13, 256, 0, stream>>>(flag, sg);

    k_cvt<<<2048, 256, 0, stream>>>(flag, d_in[0], t0);

    // ---- self attention ----
    k_gemm<float><<<dim3(24, 32), 256, 0, stream>>>(t0, 1024, sawinB, 1024, sabinB,
                                                    nullptr, qkv, 3072, 1024, 1024, 0.125f);
    k_attn<<<dim3(64, 16), 256, 0, stream>>>(qkv, qkv + 1024, qkv + 2048, 3072, 3072, obuf);
    k_gemm<float><<<dim3(8, 32), 256, 0, stream>>>(obuf, 1024, sawoutB, 1024, saboutB,
                                                   tmp, nullptr, 1024, 1024, 0, 1.f);
    k_addln<float><<<1024, 256, 0, stream>>>(t0, tmp, ln1gB, ln1bB, t1, nullptr);

    // ---- cross attention ----
    k_gemm<float><<<dim3(8, 32), 256, 0, stream>>>(t1, 1024, cawinB, 1024, cabinB,
                                                   nullptr, qca, 1024, 1024, 1024, 0.125f);
    k_gemm<bf16><<<dim3(16, 32), 256, 0, stream>>>(memB, 1024, cawinB + (size_t)1024 * 1024, 1024,
                                                   cabinB + 1024, nullptr, kvca, 2048, 1024, 0, 1.f);
    k_attn<<<dim3(64, 16), 256, 0, stream>>>(qca, kvca, kvca + 1024, 1024, 2048, obuf);
    k_gemm<float><<<dim3(8, 32), 256, 0, stream>>>(obuf, 1024, cawoutB, 1024, caboutB,
                                                   tmp, nullptr, 1024, 1024, 0, 1.f);
    k_addln<float><<<1024, 256, 0, stream>>>(t1, tmp, ln2gB, ln2bB, nullptr, t2);

    // ---- SRU ----
    k_transpose<<<dim3(128, 16), 256, 0, stream>>>(flag, d_in[10], wT, 1024, 8192);
    for (int k = 0; k < 4; k++) {
        k_gemm<bf16><<<dim3(64, 8), 256, 0, stream>>>(t2 + (size_t)k * 1024 * 1024, 1024, wT, 1024,
                                                      nullptr, Uc, nullptr, 8192, 1024, 0, 1.f);
        k_sru<<<128, 64, 0, stream>>>(Uc, sruvB, srubB, hb, cst, k * 256, (k == 0) ? 1 : 0);
    }
    k_gemm<bf16><<<dim3(8, 32), 256, 0, stream>>>(hb, 2048, lin2wB, 2048, lin2bB,
                                                  tmp2, nullptr, 1024, 2048, 0, 1.f);
    k_addln<bf16><<<1024, 256, 0, stream>>>(t2, tmp2, ln3gB, ln3bB, (float*)d_out, nullptr);
}

// Round 8
// 621.256 us; speedup vs baseline: 1.5979x; 1.1074x over previous
//
#include <hip/hip_runtime.h>
#include <hip/hip_bf16.h>

typedef __bf16 bf16;
typedef bf16 bf16x8 __attribute__((ext_vector_type(8)));
typedef bf16 bf16x4 __attribute__((ext_vector_type(4)));
typedef float f32x4 __attribute__((ext_vector_type(4)));

#define MFMA16(a, b, c) __builtin_amdgcn_mfma_f32_16x16x32_bf16((a), (b), (c), 0, 0, 0)

__device__ __forceinline__ void gl_lds16(const void* g, void* l) {
    __builtin_amdgcn_global_load_lds((const __attribute__((address_space(1))) void*)g,
                                     (__attribute__((address_space(3))) void*)l, 16, 0, 0);
}

// ---------------------------------------------------------------------------
// dtype detection (inputs may be f32 or bf16; decide on-device)
__global__ __launch_bounds__(256) void k_detect(const void* __restrict__ src, int* __restrict__ flag) {
    __shared__ int cnt;
    if (threadIdx.x == 0) cnt = 0;
    __syncthreads();
    const unsigned int* w = (const unsigned int*)src;
    int local = 0;
    for (int i = threadIdx.x; i < 4096; i += 256) {
        unsigned int e = (w[i] >> 7) & 0xFF;
        local += (e > 100 && e < 150) ? 1 : 0;
    }
    atomicAdd(&cnt, local);
    __syncthreads();
    if (threadIdx.x == 0) *flag = (cnt > 2048) ? 1 : 0;
}

__global__ __launch_bounds__(256) void k_norm(const int* __restrict__ flag, const void* __restrict__ src,
                                              bf16* __restrict__ dst, int n8) {
    int i = blockIdx.x * 256 + threadIdx.x;
    if (i >= n8) return;
    if (*flag) {
        ((bf16x8*)dst)[i] = ((const bf16x8*)src)[i];
    } else {
        const float* s = (const float*)src + (size_t)i * 8;
        bf16x8 o;
#pragma unroll
        for (int j = 0; j < 8; j++) o[j] = (bf16)s[j];
        ((bf16x8*)dst)[i] = o;
    }
}

// all 13 small tensors in one launch; block b handles segment b.
struct SmallSegs {
    const void* src[13];
    bf16* dst[13];
    int n8[13];
};
__global__ __launch_bounds__(256) void k_norm_multi(const int* __restrict__ flag, SmallSegs s) {
    int seg = blockIdx.x;
    const void* sp = s.src[seg];
    bf16* dp = s.dst[seg];
    int n = s.n8[seg];
    int f = *flag;
    for (int i = threadIdx.x; i < n; i += 256) {
        if (f) {
            ((bf16x8*)dp)[i] = ((const bf16x8*)sp)[i];
        } else {
            const float* fs = (const float*)sp + (size_t)i * 8;
            bf16x8 o;
#pragma unroll
            for (int j = 0; j < 8; j++) o[j] = (bf16)fs[j];
            ((bf16x8*)dp)[i] = o;
        }
    }
}

__global__ __launch_bounds__(256) void k_cvt(const int* __restrict__ flag, const void* __restrict__ in,
                                             float* __restrict__ out) {
    size_t i = (size_t)blockIdx.x * 256 + threadIdx.x;
    f32x4 a, b;
    if (*flag) {
        bf16x8 v = ((const bf16x8*)in)[i];
#pragma unroll
        for (int j = 0; j < 4; j++) { a[j] = (float)v[j]; b[j] = (float)v[4 + j]; }
    } else {
        a = ((const f32x4*)in)[i * 2];
        b = ((const f32x4*)in)[i * 2 + 1];
    }
    ((f32x4*)out)[i * 2] = a;
    ((f32x4*)out)[i * 2 + 1] = b;
}

// ---------------------------------------------------------------------------
// transpose+permute: sru_w (1024,8192) -> wT' (8192,1024) with row n'=h*4+j
__global__ __launch_bounds__(256) void k_transpose(const int* __restrict__ flag, const void* __restrict__ in,
                                                   bf16* __restrict__ out, int R, int C) {
    __shared__ __align__(16) bf16 t[64][72];
    int tid = threadIdx.x;
    int c0 = blockIdx.x * 64, r0 = blockIdx.y * 64;
#pragma unroll
    for (int i = 0; i < 2; i++) {
        int idx = tid + i * 256;
        int r = idx >> 3, ch = idx & 7;
        size_t base = (size_t)(r0 + r) * C + c0 + ch * 8;
        bf16x8 v;
        if (*flag) {
            v = *(const bf16x8*)((const bf16*)in + base);
        } else {
            const float* f = (const float*)in + base;
            f32x4 x = *(const f32x4*)f, y = *(const f32x4*)(f + 4);
#pragma unroll
            for (int j = 0; j < 4; j++) { v[j] = (bf16)x[j]; v[4 + j] = (bf16)y[j]; }
        }
        *(bf16x8*)&t[r][ch * 8] = v;
    }
    __syncthreads();
    int nbase = c0 & 2047, joff = c0 >> 11;
#pragma unroll
    for (int i = 0; i < 2; i++) {
        int idx = tid + i * 256;
        int cr = idx >> 3, ch = idx & 7;
        bf16x8 v;
#pragma unroll
        for (int j = 0; j < 8; j++) v[j] = t[ch * 8 + j][cr];
        int np = (nbase + cr) * 4 + joff;
        *(bf16x8*)(out + (size_t)np * R + r0 + ch * 8) = v;
    }
}

// ---------------------------------------------------------------------------
// V pre-transpose for attention: in rows m=s*4+b, 64 cols at base -> Vt[b][n][s]
// (Vt layout [4][1024][1024] bf16). Caller passes in+col0.
__global__ __launch_bounds__(256) void k_vtr(const bf16* __restrict__ in, int ldv, bf16* __restrict__ out) {
    int nt = blockIdx.x, st = blockIdx.y, b = blockIdx.z;
    __shared__ __align__(16) bf16 t[64][72];
    int tid = threadIdx.x;
#pragma unroll
    for (int i = 0; i < 2; i++) {
        int idx = tid + i * 256;
        int r = idx >> 3, ch = idx & 7;  // r = local s, ch = 16B chunk
        bf16x8 v = *(const bf16x8*)(in + (size_t)((st * 64 + r) * 4 + b) * ldv + nt * 64 + ch * 8);
        *(bf16x8*)&t[r][ch * 8] = v;
    }
    __syncthreads();
#pragma unroll
    for (int i = 0; i < 2; i++) {
        int idx = tid + i * 256;
        int dr = idx >> 3, ch = idx & 7;  // dr = local n, ch over s
        bf16x8 v;
#pragma unroll
        for (int j = 0; j < 8; j++) v[j] = t[ch * 8 + j][dr];
        *(bf16x8*)(out + (size_t)(b * 1024 + nt * 64 + dr) * 1024 + st * 64 + ch * 8) = v;
    }
}

// ---------------------------------------------------------------------------
// GEMM: C[M,N] = A[M,K] @ W[N,K]^T (+bias)(*scale). BMx128 tile, BK=64.
// LDS rows 128B with 8-way XOR swizzle. bf16 staged via global_load_lds w=16.
__device__ __forceinline__ int swzB(int r, int byteInRow) {
    return r * 128 + (byteInRow ^ ((r & 7) << 4));
}

template <typename AT, int BM>
__global__ __launch_bounds__(256) void k_gemm(
    const AT* __restrict__ A, int lda,
    const bf16* __restrict__ W, int ldw,
    const bf16* __restrict__ bias,
    float* __restrict__ Cf, bf16* __restrict__ Cb, int ldc,
    int K, int scale_end, float scale) {
    constexpr int MI = BM / 32;  // 16-row frags per wave (wave covers BM/2 rows)
    __shared__ __align__(16) char Asm[BM * 128];
    __shared__ __align__(16) char Bsm[128 * 128];
    int tid = threadIdx.x, w = tid >> 6, l = tid & 63, lg = l >> 4, lm = l & 15;
    int wm = w >> 1, wn = w & 1;
    int m0 = blockIdx.y * BM, n0 = blockIdx.x * 128;

    f32x4 acc[MI][4] = {};

    for (int k0 = 0; k0 < K; k0 += 64) {
        if constexpr (sizeof(AT) == 4) {  // f32 A -> bf16 LDS (reg staging + convert)
#pragma unroll
            for (int i = 0; i < BM / 16; i++) {
                int c = tid + i * 256;
                int r = c >> 4, ch = c & 15;
                f32x4 v = *(const f32x4*)(A + (size_t)(m0 + r) * lda + k0 + ch * 4);
                bf16x4 o;
#pragma unroll
                for (int j = 0; j < 4; j++) o[j] = (bf16)v[j];
                *(bf16x4*)(Asm + swzB(r, ch * 8)) = o;
            }
        } else {  // bf16 A via global_load_lds
#pragma unroll
            for (int i = 0; i < BM / 32; i++) {
                int r = i * 32 + w * 8 + (l >> 3);
                int gs = (l & 7) ^ (r & 7);
                gl_lds16(A + (size_t)(m0 + r) * lda + k0 + gs * 8,
                         Asm + (i * 32 + w * 8) * 128);
            }
        }
#pragma unroll
        for (int i = 0; i < 4; i++) {
            int r = i * 32 + w * 8 + (l >> 3);
            int gs = (l & 7) ^ (r & 7);
            gl_lds16(W + (size_t)(n0 + r) * ldw + k0 + gs * 8,
                     Bsm + (i * 32 + w * 8) * 128);
        }
        __syncthreads();
#pragma unroll
        for (int kh = 0; kh < 2; kh++) {
            bf16x8 af[MI], bfr[4];
#pragma unroll
            for (int i = 0; i < MI; i++)
                af[i] = *(const bf16x8*)(Asm + swzB(wm * (BM / 2) + i * 16 + lm, kh * 64 + lg * 16));
#pragma unroll
            for (int j = 0; j < 4; j++)
                bfr[j] = *(const bf16x8*)(Bsm + swzB(wn * 64 + j * 16 + lm, kh * 64 + lg * 16));
#pragma unroll
            for (int i = 0; i < MI; i++)
#pragma unroll
                for (int j = 0; j < 4; j++)
                    acc[i][j] = MFMA16(af[i], bfr[j], acc[i][j]);
        }
        __syncthreads();
    }
#pragma unroll
    for (int j = 0; j < 4; j++) {
        int col = n0 + wn * 64 + j * 16 + lm;
        float bv = bias ? (float)bias[col] : 0.f;
        float sc = (col < scale_end) ? scale : 1.f;
#pragma unroll
        for (int i = 0; i < MI; i++) {
            int row = m0 + wm * (BM / 2) + i * 16 + lg * 4;
#pragma unroll
            for (int r = 0; r < 4; r++) {
                float v = (acc[i][j][r] + bv) * sc;
                size_t idx = (size_t)(row + r) * ldc + col;
                if (Cf) Cf[idx] = v;
                if (Cb) Cb[idx] = (bf16)v;
            }
        }
    }
}

// ---------------------------------------------------------------------------
// Flash attention. V is pre-transposed (Vt[b][1024 d][1024 k]) so both K and V
// stage with vector b128 stores. Grid (h+16*b, qblk) for XCD L2 locality.
__device__ __forceinline__ int swz2(int row, int byteInRow) {
    return row * 128 + (byteInRow ^ ((row & 7) << 4));
}
// P swizzle: spread reads over all 8 16B windows (bits 4-5 from row&3, bit 6
// from (row>>2)&1). Store/read use identical mask -> bijective per row.
__device__ __forceinline__ int swzP(int row, int byteInRow) {
    return row * 128 + (byteInRow ^ ((row & 3) << 4) ^ (((row >> 2) & 1) << 6));
}

__global__ __launch_bounds__(256) void k_attn(
    const bf16* __restrict__ Qp, const bf16* __restrict__ Kp, const bf16* __restrict__ Vt,
    int ldq, int ldk, float* __restrict__ Op) {
    int h = blockIdx.x & 15, b = blockIdx.x >> 4, qblk = blockIdx.y;
    int tid = threadIdx.x, w = tid >> 6, l = tid & 63, lg = l >> 4, lm = l & 15;
    int r0 = tid >> 3, ch = tid & 7;

    __shared__ __align__(16) char Ksm[64 * 128];
    __shared__ __align__(16) char Vsm[64 * 128];     // [dim][krow] via Vt
    __shared__ __align__(16) char Psm[4][16 * 128];  // per-wave P

    bf16x8 qf[2];
    int qrow = qblk * 64 + w * 16 + lm;
#pragma unroll
    for (int kk = 0; kk < 2; kk++)
        qf[kk] = *(const bf16x8*)(Qp + (size_t)(qrow * 4 + b) * ldq + h * 64 + kk * 32 + lg * 8);

    const bf16* vbase = Vt + (size_t)(b * 1024 + h * 64) * 1024;  // rows d=0..63, ld=1024

    // prefetch tile 0 into regs
    bf16x8 kreg[2], vreg[2];
#pragma unroll
    for (int p = 0; p < 2; p++) {
        int r = r0 + p * 32;
        kreg[p] = *(const bf16x8*)(Kp + (size_t)(r * 4 + b) * ldk + h * 64 + ch * 8);
        vreg[p] = *(const bf16x8*)(vbase + (size_t)r * 1024 + ch * 8);
    }

    f32x4 oa[4] = {};
    float mrun[4], lrun[4];
#pragma unroll
    for (int r = 0; r < 4; r++) { mrun[r] = -1e30f; lrun[r] = 0.f; }

    for (int kt = 0; kt < 16; kt++) {
        __syncthreads();  // prior compute done; safe to overwrite K/V LDS
#pragma unroll
        for (int p = 0; p < 2; p++) {
            int r = r0 + p * 32;
            *(bf16x8*)(Ksm + swz2(r, ch * 16)) = kreg[p];
            *(bf16x8*)(Vsm + swz2(r, ch * 16)) = vreg[p];  // row = d, bytes over k
        }
        if (kt < 15) {  // issue next-tile loads; hidden under compute phase
#pragma unroll
            for (int p = 0; p < 2; p++) {
                int r = (kt + 1) * 64 + r0 + p * 32;
                kreg[p] = *(const bf16x8*)(Kp + (size_t)(r * 4 + b) * ldk + h * 64 + ch * 8);
                vreg[p] = *(const bf16x8*)(vbase + (size_t)(r0 + p * 32) * 1024 + (kt + 1) * 64 + ch * 8);
            }
        }
        __syncthreads();  // staging visible

        f32x4 sc[4] = {};
#pragma unroll
        for (int kk = 0; kk < 2; kk++)
#pragma unroll
            for (int jt = 0; jt < 4; jt++) {
                bf16x8 bk = *(const bf16x8*)(Ksm + swz2(jt * 16 + lm, kk * 64 + lg * 16));
                sc[jt] = MFMA16(qf[kk], bk, sc[jt]);
            }

        // online softmax; sc[jt][r]: row lg*4+r, col jt*16+lm
        float al[4], rs[4];
#pragma unroll
        for (int r = 0; r < 4; r++) {
            float m = fmaxf(fmaxf(sc[0][r], sc[1][r]), fmaxf(sc[2][r], sc[3][r]));
#pragma unroll
            for (int d = 1; d < 16; d <<= 1) m = fmaxf(m, __shfl_xor(m, d));
            float mn = fmaxf(mrun[r], m);
            al[r] = __expf(mrun[r] - mn);
            mrun[r] = mn;
            rs[r] = 0.f;
        }
#pragma unroll
        for (int jt = 0; jt < 4; jt++)
#pragma unroll
            for (int r = 0; r < 4; r++) {
                float p = __expf(sc[jt][r] - mrun[r]);
                sc[jt][r] = p;
                rs[r] += p;
            }
#pragma unroll
        for (int r = 0; r < 4; r++) {
#pragma unroll
            for (int d = 1; d < 16; d <<= 1) rs[r] += __shfl_xor(rs[r], d);
            lrun[r] = lrun[r] * al[r] + rs[r];
        }
#pragma unroll
        for (int ot = 0; ot < 4; ot++)
#pragma unroll
            for (int r = 0; r < 4; r++) oa[ot][r] *= al[r];
        // P -> per-wave LDS; wave-local fence (not a block barrier)
#pragma unroll
        for (int jt = 0; jt < 4; jt++)
#pragma unroll
            for (int r = 0; r < 4; r++)
                *(bf16*)(Psm[w] + swzP(lg * 4 + r, (jt * 16 + lm) * 2)) = (bf16)sc[jt][r];
        asm volatile("s_waitcnt lgkmcnt(0)" ::: "memory");
        __builtin_amdgcn_sched_barrier(0);
#pragma unroll
        for (int kk = 0; kk < 2; kk++) {
            bf16x8 pa = *(const bf16x8*)(Psm[w] + swzP(lm, kk * 64 + lg * 16));
#pragma unroll
            for (int ot = 0; ot < 4; ot++) {
                bf16x8 bv = *(const bf16x8*)(Vsm + swz2(ot * 16 + lm, kk * 64 + lg * 16));
                oa[ot] = MFMA16(pa, bv, oa[ot]);
            }
        }
    }
#pragma unroll
    for (int r = 0; r < 4; r++) {
        float inv = 1.f / lrun[r];
        int srow = qblk * 64 + w * 16 + lg * 4 + r;
#pragma unroll
        for (int ot = 0; ot < 4; ot++) {
            int col = h * 64 + ot * 16 + lm;
            Op[(size_t)(srow * 4 + b) * 1024 + col] = oa[ot][r] * inv;
        }
    }
}

// ---------------------------------------------------------------------------
// residual-add + LayerNorm over D=1024. X dtype templated.
template <typename XT>
__global__ __launch_bounds__(256) void k_addln(
    const XT* __restrict__ X, const float* __restrict__ Yd,
    const bf16* __restrict__ g, const bf16* __restrict__ bb,
    float* __restrict__ outF, bf16* __restrict__ outB) {
    int row = blockIdx.x * 4 + (threadIdx.x >> 6);
    int l = threadIdx.x & 63;
    const XT* xr = X + (size_t)row * 1024;
    const float* yr = Yd + (size_t)row * 1024;
    float v[16];
    float s = 0.f, s2 = 0.f;
#pragma unroll
    for (int q = 0; q < 4; q++) {
        float xa[4];
        if constexpr (sizeof(XT) == 4) {
            f32x4 a = *(const f32x4*)(xr + l * 4 + q * 256);
#pragma unroll
            for (int j = 0; j < 4; j++) xa[j] = a[j];
        } else {
            bf16x4 a = *(const bf16x4*)(xr + l * 4 + q * 256);
#pragma unroll
            for (int j = 0; j < 4; j++) xa[j] = (float)a[j];
        }
        f32x4 c = *(const f32x4*)(yr + l * 4 + q * 256);
#pragma unroll
        for (int j = 0; j < 4; j++) {
            float t = xa[j] + c[j];
            v[q * 4 + j] = t;
            s += t;
            s2 += t * t;
        }
    }
#pragma unroll
    for (int d = 1; d < 64; d <<= 1) { s += __shfl_xor(s, d); s2 += __shfl_xor(s2, d); }
    float mu = s * (1.f / 1024.f);
    float var = s2 * (1.f / 1024.f) - mu * mu;
    float rstd = rsqrtf(var + 1e-5f);
#pragma unroll
    for (int q = 0; q < 4; q++)
#pragma unroll
        for (int j = 0; j < 4; j++) {
            int col = l * 4 + q * 256 + j;
            float y = (v[q * 4 + j] - mu) * rstd * (float)g[col] + (float)bb[col];
            if (outF) outF[(size_t)row * 1024 + col] = y;
            if (outB) outB[(size_t)row * 1024 + col] = (bf16)y;
        }
}

// ---------------------------------------------------------------------------
// SRU scan chunk (256 steps). U interleaved: one float4 per step/channel,
// step stride 8192 f32x4. 128 blocks x 64 threads for CU spread.
__global__ __launch_bounds__(64) void k_sru(
    const float* __restrict__ U, const bf16* __restrict__ v2, const bf16* __restrict__ b2,
    bf16* __restrict__ Hb, float* __restrict__ cst, int s0, int init) {
    int ch = blockIdx.x * 64 + threadIdx.x;  // 0..8191
    int b = ch >> 11, hh = ch & 2047;
    float vf = (float)v2[hh], vr = (float)v2[2048 + hh];
    float bfv = (float)b2[hh], brv = (float)b2[2048 + hh];
    float c = init ? 0.f : cst[ch];
    const f32x4* u = (const f32x4*)(U + (size_t)b * 8192 + (size_t)hh * 4);
    bf16* ho = Hb + ((size_t)s0 * 4 + b) * 2048 + hh;
    f32x4 q[8];
#pragma unroll
    for (int i = 0; i < 8; i++) q[i] = u[(size_t)i * 8192];
    for (int it = 0; it < 32; it++) {
#pragma unroll
        for (int j = 0; j < 8; j++) {
            int ls = it * 8 + j;
            f32x4 v = q[j];
            if (ls + 8 < 256) q[j] = u[(size_t)(ls + 8) * 8192];
            float f = 1.f / (1.f + __expf(-(v[1] + vf * c + bfv)));
            float r = 1.f / (1.f + __expf(-(v[2] + vr * c + brv)));
            c = f * c + (1.f - f) * v[0];
            float hv = r * c + (1.f - r) * v[3];
            ho[(size_t)ls * 8192] = (bf16)hv;
        }
    }
    cst[ch] = c;
}

// ---------------------------------------------------------------------------
extern "C" void kernel_launch(void* const* d_in, const int* in_sizes, int n_in,
                              void* d_out, int out_size, void* d_ws, size_t ws_size,
                              hipStream_t stream) {
    const size_t MB = 1u << 20;
    char* ws = (char*)d_ws;

    bf16* memB    = (bf16*)(ws + 0);        // 4096x1024
    bf16* sawinB  = (bf16*)(ws + 8 * MB);   // 3072x1024
    bf16* sawoutB = (bf16*)(ws + 14 * MB);  // 1024x1024
    bf16* cawinB  = (bf16*)(ws + 16 * MB);  // 3072x1024
    bf16* cawoutB = (bf16*)(ws + 22 * MB);  // 1024x1024
    bf16* lin2wB  = (bf16*)(ws + 24 * MB);  // 1024x2048
    char* S0 = ws + 28 * MB;
    bf16* sabinB  = (bf16*)(S0 + 0 * 8192);
    bf16* cabinB  = (bf16*)(S0 + 1 * 8192);
    bf16* saboutB = (bf16*)(S0 + 2 * 8192);
    bf16* caboutB = (bf16*)(S0 + 3 * 8192);
    bf16* lin2bB  = (bf16*)(S0 + 4 * 8192);
    bf16* sruvB   = (bf16*)(S0 + 5 * 8192);
    bf16* srubB   = (bf16*)(S0 + 6 * 8192);
    bf16* ln1gB   = (bf16*)(S0 + 7 * 8192);
    bf16* ln1bB   = (bf16*)(S0 + 8 * 8192);
    bf16* ln2gB   = (bf16*)(S0 + 9 * 8192);
    bf16* ln2bB   = (bf16*)(S0 + 10 * 8192);
    bf16* ln3gB   = (bf16*)(S0 + 11 * 8192);
    bf16* ln3bB   = (bf16*)(S0 + 12 * 8192);
    int*  flag    = (int*)(S0 + 13 * 8192);

    char* P = ws + 29 * MB;
    float* t0   = (float*)(P + 0);        // 4096x1024 f32
    bf16*  qkv  = (bf16*)(P + 16 * MB);   // 4096x3072 bf16
    bf16*  qca  = qkv;
    bf16*  kvca = (bf16*)(P + 24 * MB);   // 4096x2048 bf16
    float* obuf = (float*)(P + 40 * MB);  // 4096x1024 f32
    bf16*  Vt   = (bf16*)(P + 56 * MB);   // 4x1024x1024 bf16 (overlays tmp head)
    float* tmp  = (float*)(P + 56 * MB);  // 4096x1024 f32 (written after attn)
    float* t1   = (float*)(P + 72 * MB);  // 4096x1024 f32
    bf16*  t2   = (bf16*)(P + 88 * MB);   // 4096x1024 bf16
    bf16*  wT   = (bf16*)(P + 0);         // 8192x1024 bf16 (overlays dead t0)
    float* Uc   = (float*)(P + 16 * MB);  // 1024x8192 f32 chunk
    bf16*  hb   = (bf16*)(P + 48 * MB);   // 4096x2048 bf16
    float* cst  = (float*)(P + 64 * MB);  // 8192 f32 (after Vt dead... lives in tmp region, dead post-scan reads? -> place at P+87MB)
    cst = (float*)(P + 87 * MB);          // keep clear of tmp/t2
    float* tmp2 = (float*)(P + 16 * MB);  // 4096x1024 f32 (Uc dead)

    k_detect<<<1, 256, 0, stream>>>(d_in[0], flag);
    k_norm<<<2048, 256, 0, stream>>>(flag, d_in[1], memB, 524288);
    k_norm<<<1536, 256, 0, stream>>>(flag, d_in[2], sawinB, 393216);
    k_norm<<<512, 256, 0, stream>>>(flag, d_in[4], sawoutB, 131072);
    k_norm<<<1536, 256, 0, stream>>>(flag, d_in[6], cawinB, 393216);
    k_norm<<<512, 256, 0, stream>>>(flag, d_in[8], cawoutB, 131072);
    k_norm<<<1024, 256, 0, stream>>>(flag, d_in[13], lin2wB, 262144);
    SmallSegs sg;
    const int srcIdx[13] = {3, 7, 5, 9, 14, 11, 12, 15, 16, 17, 18, 19, 20};
    bf16* dsts[13] = {sabinB, cabinB, saboutB, caboutB, lin2bB, sruvB, srubB,
                      ln1gB, ln1bB, ln2gB, ln2bB, ln3gB, ln3bB};
    const int n8s[13] = {384, 384, 128, 128, 128, 512, 512, 128, 128, 128, 128, 128, 128};
    for (int i = 0; i < 13; i++) { sg.src[i] = d_in[srcIdx[i]]; sg.dst[i] = dsts[i]; sg.n8[i] = n8s[i]; }
    k_norm_multi<<<13, 256, 0, stream>>>(flag, sg);

    k_cvt<<<2048, 256, 0, stream>>>(flag, d_in[0], t0);

    // ---- self attention ----
    k_gemm<float, 128><<<dim3(24, 32), 256, 0, stream>>>(t0, 1024, sawinB, 1024, sabinB,
                                                         nullptr, qkv, 3072, 1024, 1024, 0.125f);
    k_vtr<<<dim3(16, 16, 4), 256, 0, stream>>>(qkv + 2048, 3072, Vt);
    k_attn<<<dim3(64, 16), 256, 0, stream>>>(qkv, qkv + 1024, Vt, 3072, 3072, obuf);
    k_gemm<float, 64><<<dim3(8, 64), 256, 0, stream>>>(obuf, 1024, sawoutB, 1024, saboutB,
                                                       tmp, nullptr, 1024, 1024, 0, 1.f);
    k_addln<float><<<1024, 256, 0, stream>>>(t0, tmp, ln1gB, ln1bB, t1, nullptr);

    // ---- cross attention ----
    k_gemm<float, 64><<<dim3(8, 64), 256, 0, stream>>>(t1, 1024, cawinB, 1024, cabinB,
                                                       nullptr, qca, 1024, 1024, 1024, 0.125f);
    k_gemm<bf16, 128><<<dim3(16, 32), 256, 0, stream>>>(memB, 1024, cawinB + (size_t)1024 * 1024, 1024,
                                                        cabinB + 1024, nullptr, kvca, 2048, 1024, 0, 1.f);
    k_vtr<<<dim3(16, 16, 4), 256, 0, stream>>>(kvca + 1024, 2048, Vt);
    k_attn<<<dim3(64, 16), 256, 0, stream>>>(qca, kvca, Vt, 1024, 2048, obuf);
    k_gemm<float, 64><<<dim3(8, 64), 256, 0, stream>>>(obuf, 1024, cawoutB, 1024, caboutB,
                                                       tmp, nullptr, 1024, 1024, 0, 1.f);
    k_addln<float><<<1024, 256, 0, stream>>>(t1, tmp, ln2gB, ln2bB, nullptr, t2);

    // ---- SRU ----
    k_transpose<<<dim3(128, 16), 256, 0, stream>>>(flag, d_in[10], wT, 1024, 8192);
    for (int k = 0; k < 4; k++) {
        k_gemm<bf16, 128><<<dim3(64, 8), 256, 0, stream>>>(t2 + (size_t)k * 1024 * 1024, 1024, wT, 1024,
                                                           nullptr, Uc, nullptr, 8192, 1024, 0, 1.f);
        k_sru<<<128, 64, 0, stream>>>(Uc, sruvB, srubB, hb, cst, k * 256, (k == 0) ? 1 : 0);
    }
    k_gemm<bf16, 64><<<dim3(8, 64), 256, 0, stream>>>(hb, 2048, lin2wB, 2048, lin2bB,
                                                      tmp2, nullptr, 1024, 2048, 0, 1.f);
    k_addln<bf16><<<1024, 256, 0, stream>>>(t2, tmp2, ln3gB, ln3bB, (float*)d_out, nullptr);
}

// Round 9
// 603.026 us; speedup vs baseline: 1.6462x; 1.0302x over previous
//
#include <hip/hip_runtime.h>
#include <hip/hip_bf16.h>

typedef __bf16 bf16;
typedef bf16 bf16x8 __attribute__((ext_vector_type(8)));
typedef bf16 bf16x4 __attribute__((ext_vector_type(4)));
typedef float f32x4 __attribute__((ext_vector_type(4)));

#define MFMA16(a, b, c) __builtin_amdgcn_mfma_f32_16x16x32_bf16((a), (b), (c), 0, 0, 0)

__device__ __forceinline__ void gl_lds16(const void* g, void* l) {
    __builtin_amdgcn_global_load_lds((const __attribute__((address_space(1))) void*)g,
                                     (__attribute__((address_space(3))) void*)l, 16, 0, 0);
}

// ---------------------------------------------------------------------------
// dtype detection (inputs may be f32 or bf16; decide on-device)
__global__ __launch_bounds__(256) void k_detect(const void* __restrict__ src, int* __restrict__ flag) {
    __shared__ int cnt;
    if (threadIdx.x == 0) cnt = 0;
    __syncthreads();
    const unsigned int* w = (const unsigned int*)src;
    int local = 0;
    for (int i = threadIdx.x; i < 4096; i += 256) {
        unsigned int e = (w[i] >> 7) & 0xFF;
        local += (e > 100 && e < 150) ? 1 : 0;
    }
    atomicAdd(&cnt, local);
    __syncthreads();
    if (threadIdx.x == 0) *flag = (cnt > 2048) ? 1 : 0;
}

__global__ __launch_bounds__(256) void k_norm(const int* __restrict__ flag, const void* __restrict__ src,
                                              bf16* __restrict__ dst, int n8) {
    int i = blockIdx.x * 256 + threadIdx.x;
    if (i >= n8) return;
    if (*flag) {
        ((bf16x8*)dst)[i] = ((const bf16x8*)src)[i];
    } else {
        const float* s = (const float*)src + (size_t)i * 8;
        bf16x8 o;
#pragma unroll
        for (int j = 0; j < 8; j++) o[j] = (bf16)s[j];
        ((bf16x8*)dst)[i] = o;
    }
}

struct SmallSegs {
    const void* src[13];
    bf16* dst[13];
    int n8[13];
};
__global__ __launch_bounds__(256) void k_norm_multi(const int* __restrict__ flag, SmallSegs s) {
    int seg = blockIdx.x;
    const void* sp = s.src[seg];
    bf16* dp = s.dst[seg];
    int n = s.n8[seg];
    int f = *flag;
    for (int i = threadIdx.x; i < n; i += 256) {
        if (f) {
            ((bf16x8*)dp)[i] = ((const bf16x8*)sp)[i];
        } else {
            const float* fs = (const float*)sp + (size_t)i * 8;
            bf16x8 o;
#pragma unroll
            for (int j = 0; j < 8; j++) o[j] = (bf16)fs[j];
            ((bf16x8*)dp)[i] = o;
        }
    }
}

// tgt -> f32 residual t0 AND bf16 copy t0b (GEMM A operand)
__global__ __launch_bounds__(256) void k_cvt(const int* __restrict__ flag, const void* __restrict__ in,
                                             float* __restrict__ out, bf16* __restrict__ outb) {
    size_t i = (size_t)blockIdx.x * 256 + threadIdx.x;
    f32x4 a, b;
    bf16x8 v;
    if (*flag) {
        v = ((const bf16x8*)in)[i];
#pragma unroll
        for (int j = 0; j < 4; j++) { a[j] = (float)v[j]; b[j] = (float)v[4 + j]; }
    } else {
        a = ((const f32x4*)in)[i * 2];
        b = ((const f32x4*)in)[i * 2 + 1];
#pragma unroll
        for (int j = 0; j < 4; j++) { v[j] = (bf16)a[j]; v[4 + j] = (bf16)b[j]; }
    }
    ((f32x4*)out)[i * 2] = a;
    ((f32x4*)out)[i * 2 + 1] = b;
    ((bf16x8*)outb)[i] = v;
}

// ---------------------------------------------------------------------------
// transpose+permute: sru_w (1024,8192) -> wT' (8192,1024) with row n'=h*4+j
__global__ __launch_bounds__(256) void k_transpose(const int* __restrict__ flag, const void* __restrict__ in,
                                                   bf16* __restrict__ out, int R, int C) {
    __shared__ __align__(16) bf16 t[64][72];
    int tid = threadIdx.x;
    int c0 = blockIdx.x * 64, r0 = blockIdx.y * 64;
#pragma unroll
    for (int i = 0; i < 2; i++) {
        int idx = tid + i * 256;
        int r = idx >> 3, ch = idx & 7;
        size_t base = (size_t)(r0 + r) * C + c0 + ch * 8;
        bf16x8 v;
        if (*flag) {
            v = *(const bf16x8*)((const bf16*)in + base);
        } else {
            const float* f = (const float*)in + base;
            f32x4 x = *(const f32x4*)f, y = *(const f32x4*)(f + 4);
#pragma unroll
            for (int j = 0; j < 4; j++) { v[j] = (bf16)x[j]; v[4 + j] = (bf16)y[j]; }
        }
        *(bf16x8*)&t[r][ch * 8] = v;
    }
    __syncthreads();
    int nbase = c0 & 2047, joff = c0 >> 11;
#pragma unroll
    for (int i = 0; i < 2; i++) {
        int idx = tid + i * 256;
        int cr = idx >> 3, ch = idx & 7;
        bf16x8 v;
#pragma unroll
        for (int j = 0; j < 8; j++) v[j] = t[ch * 8 + j][cr];
        int np = (nbase + cr) * 4 + joff;
        *(bf16x8*)(out + (size_t)np * R + r0 + ch * 8) = v;
    }
}

// ---------------------------------------------------------------------------
// V pre-transpose: in rows m=s*4+b, 64 cols -> Vt[b][n][s] ([4][1024][1024] bf16)
__global__ __launch_bounds__(256) void k_vtr(const bf16* __restrict__ in, int ldv, bf16* __restrict__ out) {
    int nt = blockIdx.x, st = blockIdx.y, b = blockIdx.z;
    __shared__ __align__(16) bf16 t[64][72];
    int tid = threadIdx.x;
#pragma unroll
    for (int i = 0; i < 2; i++) {
        int idx = tid + i * 256;
        int r = idx >> 3, ch = idx & 7;
        bf16x8 v = *(const bf16x8*)(in + (size_t)((st * 64 + r) * 4 + b) * ldv + nt * 64 + ch * 8);
        *(bf16x8*)&t[r][ch * 8] = v;
    }
    __syncthreads();
#pragma unroll
    for (int i = 0; i < 2; i++) {
        int idx = tid + i * 256;
        int dr = idx >> 3, ch = idx & 7;
        bf16x8 v;
#pragma unroll
        for (int j = 0; j < 8; j++) v[j] = t[ch * 8 + j][dr];
        *(bf16x8*)(out + (size_t)(b * 1024 + nt * 64 + dr) * 1024 + st * 64 + ch * 8) = v;
    }
}

// ---------------------------------------------------------------------------
// GEMM (bf16 A): C[M,N] = A @ W^T (+bias)(*scale). BMx128 tile, BK=64.
// All staging via global_load_lds w=16, linear LDS dest + inverse-swz source.
__device__ __forceinline__ int swzB(int r, int byteInRow) {
    return r * 128 + (byteInRow ^ ((r & 7) << 4));
}

template <int BM>
__global__ __launch_bounds__(256) void k_gemm(
    const bf16* __restrict__ A, int lda,
    const bf16* __restrict__ W, int ldw,
    const bf16* __restrict__ bias,
    float* __restrict__ Cf, bf16* __restrict__ Cb, int ldc,
    int K, int scale_end, float scale) {
    constexpr int MI = BM / 32;
    __shared__ __align__(16) char Asm[BM * 128];
    __shared__ __align__(16) char Bsm[128 * 128];
    int tid = threadIdx.x, w = tid >> 6, l = tid & 63, lg = l >> 4, lm = l & 15;
    int wm = w >> 1, wn = w & 1;
    int m0 = blockIdx.y * BM, n0 = blockIdx.x * 128;

    f32x4 acc[MI][4] = {};

    for (int k0 = 0; k0 < K; k0 += 64) {
#pragma unroll
        for (int i = 0; i < BM / 32; i++) {
            int r = i * 32 + w * 8 + (l >> 3);
            int gs = (l & 7) ^ (r & 7);
            gl_lds16(A + (size_t)(m0 + r) * lda + k0 + gs * 8,
                     Asm + (i * 32 + w * 8) * 128);
        }
#pragma unroll
        for (int i = 0; i < 4; i++) {
            int r = i * 32 + w * 8 + (l >> 3);
            int gs = (l & 7) ^ (r & 7);
            gl_lds16(W + (size_t)(n0 + r) * ldw + k0 + gs * 8,
                     Bsm + (i * 32 + w * 8) * 128);
        }
        __syncthreads();
#pragma unroll
        for (int kh = 0; kh < 2; kh++) {
            bf16x8 af[MI], bfr[4];
#pragma unroll
            for (int i = 0; i < MI; i++)
                af[i] = *(const bf16x8*)(Asm + swzB(wm * (BM / 2) + i * 16 + lm, kh * 64 + lg * 16));
#pragma unroll
            for (int j = 0; j < 4; j++)
                bfr[j] = *(const bf16x8*)(Bsm + swzB(wn * 64 + j * 16 + lm, kh * 64 + lg * 16));
#pragma unroll
            for (int i = 0; i < MI; i++)
#pragma unroll
                for (int j = 0; j < 4; j++)
                    acc[i][j] = MFMA16(af[i], bfr[j], acc[i][j]);
        }
        __syncthreads();
    }
#pragma unroll
    for (int j = 0; j < 4; j++) {
        int col = n0 + wn * 64 + j * 16 + lm;
        float bv = bias ? (float)bias[col] : 0.f;
        float sc = (col < scale_end) ? scale : 1.f;
#pragma unroll
        for (int i = 0; i < MI; i++) {
            int row = m0 + wm * (BM / 2) + i * 16 + lg * 4;
#pragma unroll
            for (int r = 0; r < 4; r++) {
                float v = (acc[i][j][r] + bv) * sc;
                size_t idx = (size_t)(row + r) * ldc + col;
                if (Cf) Cf[idx] = v;
                if (Cb) Cb[idx] = (bf16)v;
            }
        }
    }
}

// ---------------------------------------------------------------------------
// Flash attention (V pre-transposed). bf16 output. Defer-max (THR=8) + lane-
// partial lrun (sum-reduce once in epilogue).
__device__ __forceinline__ int swz2(int row, int byteInRow) {
    return row * 128 + (byteInRow ^ ((row & 7) << 4));
}
__device__ __forceinline__ int swzP(int row, int byteInRow) {
    return row * 128 + (byteInRow ^ ((row & 3) << 4) ^ (((row >> 2) & 1) << 6));
}

__global__ __launch_bounds__(256) void k_attn(
    const bf16* __restrict__ Qp, const bf16* __restrict__ Kp, const bf16* __restrict__ Vt,
    int ldq, int ldk, bf16* __restrict__ Op) {
    int h = blockIdx.x & 15, b = blockIdx.x >> 4, qblk = blockIdx.y;
    int tid = threadIdx.x, w = tid >> 6, l = tid & 63, lg = l >> 4, lm = l & 15;
    int r0 = tid >> 3, ch = tid & 7;

    __shared__ __align__(16) char Ksm[64 * 128];
    __shared__ __align__(16) char Vsm[64 * 128];
    __shared__ __align__(16) char Psm[4][16 * 128];

    bf16x8 qf[2];
    int qrow = qblk * 64 + w * 16 + lm;
#pragma unroll
    for (int kk = 0; kk < 2; kk++)
        qf[kk] = *(const bf16x8*)(Qp + (size_t)(qrow * 4 + b) * ldq + h * 64 + kk * 32 + lg * 8);

    const bf16* vbase = Vt + (size_t)(b * 1024 + h * 64) * 1024;

    bf16x8 kreg[2], vreg[2];
#pragma unroll
    for (int p = 0; p < 2; p++) {
        int r = r0 + p * 32;
        kreg[p] = *(const bf16x8*)(Kp + (size_t)(r * 4 + b) * ldk + h * 64 + ch * 8);
        vreg[p] = *(const bf16x8*)(vbase + (size_t)r * 1024 + ch * 8);
    }

    f32x4 oa[4] = {};
    float mrun[4], lrun[4];  // lrun is LANE-PARTIAL (reduced in epilogue)
#pragma unroll
    for (int r = 0; r < 4; r++) { mrun[r] = -1e30f; lrun[r] = 0.f; }

    for (int kt = 0; kt < 16; kt++) {
        __syncthreads();
#pragma unroll
        for (int p = 0; p < 2; p++) {
            int r = r0 + p * 32;
            *(bf16x8*)(Ksm + swz2(r, ch * 16)) = kreg[p];
            *(bf16x8*)(Vsm + swz2(r, ch * 16)) = vreg[p];
        }
        if (kt < 15) {
#pragma unroll
            for (int p = 0; p < 2; p++) {
                int r = (kt + 1) * 64 + r0 + p * 32;
                kreg[p] = *(const bf16x8*)(Kp + (size_t)(r * 4 + b) * ldk + h * 64 + ch * 8);
                vreg[p] = *(const bf16x8*)(vbase + (size_t)(r0 + p * 32) * 1024 + (kt + 1) * 64 + ch * 8);
            }
        }
        __syncthreads();

        f32x4 sc[4] = {};
#pragma unroll
        for (int kk = 0; kk < 2; kk++)
#pragma unroll
            for (int jt = 0; jt < 4; jt++) {
                bf16x8 bk = *(const bf16x8*)(Ksm + swz2(jt * 16 + lm, kk * 64 + lg * 16));
                sc[jt] = MFMA16(qf[kk], bk, sc[jt]);
            }

        // tile row max (16-lane reduce)
        float m_[4];
#pragma unroll
        for (int r = 0; r < 4; r++) {
            float m = fmaxf(fmaxf(sc[0][r], sc[1][r]), fmaxf(sc[2][r], sc[3][r]));
#pragma unroll
            for (int d = 1; d < 16; d <<= 1) m = fmaxf(m, __shfl_xor(m, d));
            m_[r] = m;
        }
        // defer-max: rescale only if some row grew past mrun+8 (wave-uniform)
        bool grow = (m_[0] > mrun[0] + 8.f) || (m_[1] > mrun[1] + 8.f) ||
                    (m_[2] > mrun[2] + 8.f) || (m_[3] > mrun[3] + 8.f);
        if (__any(grow)) {
#pragma unroll
            for (int r = 0; r < 4; r++) {
                float mn = fmaxf(mrun[r], m_[r]);
                float al = __expf(mrun[r] - mn);
                mrun[r] = mn;
                lrun[r] *= al;
#pragma unroll
                for (int ot = 0; ot < 4; ot++) oa[ot][r] *= al;
            }
        }
        // P = exp(S - mrun); accumulate lane-partial row sums (no shuffle here)
#pragma unroll
        for (int jt = 0; jt < 4; jt++)
#pragma unroll
            for (int r = 0; r < 4; r++) {
                float p = __expf(sc[jt][r] - mrun[r]);
                sc[jt][r] = p;
                lrun[r] += p;
            }
#pragma unroll
        for (int jt = 0; jt < 4; jt++)
#pragma unroll
            for (int r = 0; r < 4; r++)
                *(bf16*)(Psm[w] + swzP(lg * 4 + r, (jt * 16 + lm) * 2)) = (bf16)sc[jt][r];
        asm volatile("s_waitcnt lgkmcnt(0)" ::: "memory");
        __builtin_amdgcn_sched_barrier(0);
#pragma unroll
        for (int kk = 0; kk < 2; kk++) {
            bf16x8 pa = *(const bf16x8*)(Psm[w] + swzP(lm, kk * 64 + lg * 16));
#pragma unroll
            for (int ot = 0; ot < 4; ot++) {
                bf16x8 bv = *(const bf16x8*)(Vsm + swz2(ot * 16 + lm, kk * 64 + lg * 16));
                oa[ot] = MFMA16(pa, bv, oa[ot]);
            }
        }
    }
    // epilogue: reduce lane-partial lrun across the 16 lanes of each row group
#pragma unroll
    for (int r = 0; r < 4; r++) {
#pragma unroll
        for (int d = 1; d < 16; d <<= 1) lrun[r] += __shfl_xor(lrun[r], d);
        float inv = 1.f / lrun[r];
        int srow = qblk * 64 + w * 16 + lg * 4 + r;
#pragma unroll
        for (int ot = 0; ot < 4; ot++) {
            int col = h * 64 + ot * 16 + lm;
            Op[(size_t)(srow * 4 + b) * 1024 + col] = (bf16)(oa[ot][r] * inv);
        }
    }
}

// ---------------------------------------------------------------------------
// residual-add + LayerNorm over D=1024 (f32 math). X dtype templated.
template <typename XT>
__global__ __launch_bounds__(256) void k_addln(
    const XT* __restrict__ X, const float* __restrict__ Yd,
    const bf16* __restrict__ g, const bf16* __restrict__ bb,
    float* __restrict__ outF, bf16* __restrict__ outB) {
    int row = blockIdx.x * 4 + (threadIdx.x >> 6);
    int l = threadIdx.x & 63;
    const XT* xr = X + (size_t)row * 1024;
    const float* yr = Yd + (size_t)row * 1024;
    float v[16];
    float s = 0.f, s2 = 0.f;
#pragma unroll
    for (int q = 0; q < 4; q++) {
        float xa[4];
        if constexpr (sizeof(XT) == 4) {
            f32x4 a = *(const f32x4*)(xr + l * 4 + q * 256);
#pragma unroll
            for (int j = 0; j < 4; j++) xa[j] = a[j];
        } else {
            bf16x4 a = *(const bf16x4*)(xr + l * 4 + q * 256);
#pragma unroll
            for (int j = 0; j < 4; j++) xa[j] = (float)a[j];
        }
        f32x4 c = *(const f32x4*)(yr + l * 4 + q * 256);
#pragma unroll
        for (int j = 0; j < 4; j++) {
            float t = xa[j] + c[j];
            v[q * 4 + j] = t;
            s += t;
            s2 += t * t;
        }
    }
#pragma unroll
    for (int d = 1; d < 64; d <<= 1) { s += __shfl_xor(s, d); s2 += __shfl_xor(s2, d); }
    float mu = s * (1.f / 1024.f);
    float var = s2 * (1.f / 1024.f) - mu * mu;
    float rstd = rsqrtf(var + 1e-5f);
#pragma unroll
    for (int q = 0; q < 4; q++)
#pragma unroll
        for (int j = 0; j < 4; j++) {
            int col = l * 4 + q * 256 + j;
            float y = (v[q * 4 + j] - mu) * rstd * (float)g[col] + (float)bb[col];
            if (outF) outF[(size_t)row * 1024 + col] = y;
            if (outB) outB[(size_t)row * 1024 + col] = (bf16)y;
        }
}

// ---------------------------------------------------------------------------
// SRU scan chunk (256 steps), U in bf16 (one bf16x4 gate group per step).
__global__ __launch_bounds__(64) void k_sru(
    const bf16* __restrict__ U, const bf16* __restrict__ v2, const bf16* __restrict__ b2,
    bf16* __restrict__ Hb, float* __restrict__ cst, int s0, int init) {
    int ch = blockIdx.x * 64 + threadIdx.x;  // 0..8191
    int b = ch >> 11, hh = ch & 2047;
    float vf = (float)v2[hh], vr = (float)v2[2048 + hh];
    float bfv = (float)b2[hh], brv = (float)b2[2048 + hh];
    float c = init ? 0.f : cst[ch];
    const bf16x4* u = (const bf16x4*)(U + (size_t)b * 8192 + (size_t)hh * 4);  // +8192 units/step
    bf16* ho = Hb + ((size_t)s0 * 4 + b) * 2048 + hh;
    bf16x4 q[8];
#pragma unroll
    for (int i = 0; i < 8; i++) q[i] = u[(size_t)i * 8192];
    for (int it = 0; it < 32; it++) {
#pragma unroll
        for (int j = 0; j < 8; j++) {
            int ls = it * 8 + j;
            bf16x4 v = q[j];
            if (ls + 8 < 256) q[j] = u[(size_t)(ls + 8) * 8192];
            float xc = (float)v[0], fp = (float)v[1], rp = (float)v[2], xh = (float)v[3];
            float f = 1.f / (1.f + __expf(-(fp + vf * c + bfv)));
            float r = 1.f / (1.f + __expf(-(rp + vr * c + brv)));
            c = f * c + (1.f - f) * xc;
            float hv = r * c + (1.f - r) * xh;
            ho[(size_t)ls * 8192] = (bf16)hv;
        }
    }
    cst[ch] = c;
}

// ---------------------------------------------------------------------------
extern "C" void kernel_launch(void* const* d_in, const int* in_sizes, int n_in,
                              void* d_out, int out_size, void* d_ws, size_t ws_size,
                              hipStream_t stream) {
    const size_t MB = 1u << 20;
    char* ws = (char*)d_ws;

    bf16* memB    = (bf16*)(ws + 0);        // 4096x1024
    bf16* sawinB  = (bf16*)(ws + 8 * MB);   // 3072x1024
    bf16* sawoutB = (bf16*)(ws + 14 * MB);  // 1024x1024
    bf16* cawinB  = (bf16*)(ws + 16 * MB);  // 3072x1024
    bf16* cawoutB = (bf16*)(ws + 22 * MB);  // 1024x1024
    bf16* lin2wB  = (bf16*)(ws + 24 * MB);  // 1024x2048
    char* S0 = ws + 28 * MB;
    bf16* sabinB  = (bf16*)(S0 + 0 * 8192);
    bf16* cabinB  = (bf16*)(S0 + 1 * 8192);
    bf16* saboutB = (bf16*)(S0 + 2 * 8192);
    bf16* caboutB = (bf16*)(S0 + 3 * 8192);
    bf16* lin2bB  = (bf16*)(S0 + 4 * 8192);
    bf16* sruvB   = (bf16*)(S0 + 5 * 8192);
    bf16* srubB   = (bf16*)(S0 + 6 * 8192);
    bf16* ln1gB   = (bf16*)(S0 + 7 * 8192);
    bf16* ln1bB   = (bf16*)(S0 + 8 * 8192);
    bf16* ln2gB   = (bf16*)(S0 + 9 * 8192);
    bf16* ln2bB   = (bf16*)(S0 + 10 * 8192);
    bf16* ln3gB   = (bf16*)(S0 + 11 * 8192);
    bf16* ln3bB   = (bf16*)(S0 + 12 * 8192);
    int*  flag    = (int*)(S0 + 13 * 8192);

    // pipeline region P (peak P+96MB = ws+125MB, proven safe in round 4)
    char* P = ws + 29 * MB;
    float* t0   = (float*)(P + 0);        // 4096x1024 f32 (ln1 residual)
    bf16*  qkv  = (bf16*)(P + 16 * MB);   // 4096x3072 bf16
    bf16*  qca  = qkv;                    // 4096x1024 (reuse after sa attn)
    bf16*  kvca = (bf16*)(P + 24 * MB);   // 4096x2048
    bf16*  obuf = (bf16*)(P + 40 * MB);   // 4096x1024 bf16 attn out
    bf16*  hb   = (bf16*)(P + 48 * MB);   // 4096x2048 (SRU phase)
    bf16*  Vt   = (bf16*)(P + 56 * MB);   // 4x1024x1024 (attn phases)
    bf16*  t0b  = (bf16*)(P + 64 * MB);   // 4096x1024 (QKV A; dead before tmp)
    float* tmp  = (float*)(P + 64 * MB);  // 4096x1024 f32 (out-proj results)
    bf16*  t1   = (bf16*)(P + 80 * MB);   // 4096x1024 (ln1 out)
    bf16*  t2   = (bf16*)(P + 88 * MB);   // 4096x1024 (ln2 out)
    bf16*  wT   = (bf16*)(P + 0);         // 8192x1024 (SRU; overlays dead t0)
    bf16*  Uc   = (bf16*)(P + 16 * MB);   // 1024x8192 bf16 chunk (overlays dead qkv)
    float* tmp2 = (float*)(P + 16 * MB);  // 4096x1024 f32 (after scan)
    float* cst  = (float*)(P + 96 * MB);  // 8192 f32 scan state

    k_detect<<<1, 256, 0, stream>>>(d_in[0], flag);
    k_norm<<<2048, 256, 0, stream>>>(flag, d_in[1], memB, 524288);
    k_norm<<<1536, 256, 0, stream>>>(flag, d_in[2], sawinB, 393216);
    k_norm<<<512, 256, 0, stream>>>(flag, d_in[4], sawoutB, 131072);
    k_norm<<<1536, 256, 0, stream>>>(flag, d_in[6], cawinB, 393216);
    k_norm<<<512, 256, 0, stream>>>(flag, d_in[8], cawoutB, 131072);
    k_norm<<<1024, 256, 0, stream>>>(flag, d_in[13], lin2wB, 262144);
    SmallSegs sg;
    const int srcIdx[13] = {3, 7, 5, 9, 14, 11, 12, 15, 16, 17, 18, 19, 20};
    bf16* dsts[13] = {sabinB, cabinB, saboutB, caboutB, lin2bB, sruvB, srubB,
                      ln1gB, ln1bB, ln2gB, ln2bB, ln3gB, ln3bB};
    const int n8s[13] = {384, 384, 128, 128, 128, 512, 512, 128, 128, 128, 128, 128, 128};
    for (int i = 0; i < 13; i++) { sg.src[i] = d_in[srcIdx[i]]; sg.dst[i] = dsts[i]; sg.n8[i] = n8s[i]; }
    k_norm_multi<<<13, 256, 0, stream>>>(flag, sg);

    k_cvt<<<2048, 256, 0, stream>>>(flag, d_in[0], t0, t0b);

    // ---- self attention ----
    k_gemm<128><<<dim3(24, 32), 256, 0, stream>>>(t0b, 1024, sawinB, 1024, sabinB,
                                                  nullptr, qkv, 3072, 1024, 1024, 0.125f);
    k_vtr<<<dim3(16, 16, 4), 256, 0, stream>>>(qkv + 2048, 3072, Vt);
    k_attn<<<dim3(64, 16), 256, 0, stream>>>(qkv, qkv + 1024, Vt, 3072, 3072, obuf);
    k_gemm<64><<<dim3(8, 64), 256, 0, stream>>>(obuf, 1024, sawoutB, 1024, saboutB,
                                                tmp, nullptr, 1024, 1024, 0, 1.f);
    k_addln<float><<<1024, 256, 0, stream>>>(t0, tmp, ln1gB, ln1bB, nullptr, t1);

    // ---- cross attention ----
    k_gemm<64><<<dim3(8, 64), 256, 0, stream>>>(t1, 1024, cawinB, 1024, cabinB,
                                                nullptr, qca, 1024, 1024, 1024, 0.125f);
    k_gemm<128><<<dim3(16, 32), 256, 0, stream>>>(memB, 1024, cawinB + (size_t)1024 * 1024, 1024,
                                                  cabinB + 1024, nullptr, kvca, 2048, 1024, 0, 1.f);
    k_vtr<<<dim3(16, 16, 4), 256, 0, stream>>>(kvca + 1024, 2048, Vt);
    k_attn<<<dim3(64, 16), 256, 0, stream>>>(qca, kvca, Vt, 1024, 2048, obuf);
    k_gemm<64><<<dim3(8, 64), 256, 0, stream>>>(obuf, 1024, cawoutB, 1024, caboutB,
                                                tmp, nullptr, 1024, 1024, 0, 1.f);
    k_addln<bf16><<<1024, 256, 0, stream>>>(t1, tmp, ln2gB, ln2bB, nullptr, t2);

    // ---- SRU ----
    k_transpose<<<dim3(128, 16), 256, 0, stream>>>(flag, d_in[10], wT, 1024, 8192);
    for (int k = 0; k < 4; k++) {
        k_gemm<128><<<dim3(64, 8), 256, 0, stream>>>(t2 + (size_t)k * 1024 * 1024, 1024, wT, 1024,
                                                     nullptr, nullptr, Uc, 8192, 1024, 0, 1.f);
        k_sru<<<128, 64, 0, stream>>>(Uc, sruvB, srubB, hb, cst, k * 256, (k == 0) ? 1 : 0);
    }
    k_gemm<64><<<dim3(8, 64), 256, 0, stream>>>(hb, 2048, lin2wB, 2048, lin2bB,
                                                tmp2, nullptr, 1024, 2048, 0, 1.f);
    k_addln<bf16><<<1024, 256, 0, stream>>>(t2, tmp2, ln3gB, ln3bB, (float*)d_out, nullptr);
}

// Round 10
// 552.305 us; speedup vs baseline: 1.7974x; 1.0918x over previous
//
#include <hip/hip_runtime.h>
#include <hip/hip_bf16.h>

typedef __bf16 bf16;
typedef bf16 bf16x8 __attribute__((ext_vector_type(8)));
typedef bf16 bf16x4 __attribute__((ext_vector_type(4)));
typedef float f32x4 __attribute__((ext_vector_type(4)));

#define MFMA16(a, b, c) __builtin_amdgcn_mfma_f32_16x16x32_bf16((a), (b), (c), 0, 0, 0)

__device__ __forceinline__ void gl_lds16(const void* g, void* l) {
    __builtin_amdgcn_global_load_lds((const __attribute__((address_space(1))) void*)g,
                                     (__attribute__((address_space(3))) void*)l, 16, 0, 0);
}

// ---------------------------------------------------------------------------
__global__ __launch_bounds__(256) void k_detect(const void* __restrict__ src, int* __restrict__ flag) {
    __shared__ int cnt;
    if (threadIdx.x == 0) cnt = 0;
    __syncthreads();
    const unsigned int* w = (const unsigned int*)src;
    int local = 0;
    for (int i = threadIdx.x; i < 4096; i += 256) {
        unsigned int e = (w[i] >> 7) & 0xFF;
        local += (e > 100 && e < 150) ? 1 : 0;
    }
    atomicAdd(&cnt, local);
    __syncthreads();
    if (threadIdx.x == 0) *flag = (cnt > 2048) ? 1 : 0;
}

// 6 large tensors in one segmented launch (exact block counts, no tail)
struct BigSegs {
    const void* src[6];
    bf16* dst[6];
    int cum[7];
};
__global__ __launch_bounds__(256) void k_norm_big(const int* __restrict__ flag, BigSegs s) {
    int seg = 0;
#pragma unroll
    for (int t = 0; t < 5; t++) seg += (blockIdx.x >= s.cum[t + 1]) ? 1 : 0;
    int i = (blockIdx.x - s.cum[seg]) * 256 + threadIdx.x;
    const void* sp = s.src[seg];
    bf16* dp = s.dst[seg];
    if (*flag) {
        ((bf16x8*)dp)[i] = ((const bf16x8*)sp)[i];
    } else {
        const float* fs = (const float*)sp + (size_t)i * 8;
        bf16x8 o;
#pragma unroll
        for (int j = 0; j < 8; j++) o[j] = (bf16)fs[j];
        ((bf16x8*)dp)[i] = o;
    }
}

struct SmallSegs {
    const void* src[13];
    bf16* dst[13];
    int n8[13];
};
__global__ __launch_bounds__(256) void k_norm_multi(const int* __restrict__ flag, SmallSegs s) {
    int seg = blockIdx.x;
    const void* sp = s.src[seg];
    bf16* dp = s.dst[seg];
    int n = s.n8[seg];
    int f = *flag;
    for (int i = threadIdx.x; i < n; i += 256) {
        if (f) {
            ((bf16x8*)dp)[i] = ((const bf16x8*)sp)[i];
        } else {
            const float* fs = (const float*)sp + (size_t)i * 8;
            bf16x8 o;
#pragma unroll
            for (int j = 0; j < 8; j++) o[j] = (bf16)fs[j];
            ((bf16x8*)dp)[i] = o;
        }
    }
}

// tgt -> f32 residual t0 AND bf16 copy t0b
__global__ __launch_bounds__(256) void k_cvt(const int* __restrict__ flag, const void* __restrict__ in,
                                             float* __restrict__ out, bf16* __restrict__ outb) {
    size_t i = (size_t)blockIdx.x * 256 + threadIdx.x;
    f32x4 a, b;
    bf16x8 v;
    if (*flag) {
        v = ((const bf16x8*)in)[i];
#pragma unroll
        for (int j = 0; j < 4; j++) { a[j] = (float)v[j]; b[j] = (float)v[4 + j]; }
    } else {
        a = ((const f32x4*)in)[i * 2];
        b = ((const f32x4*)in)[i * 2 + 1];
#pragma unroll
        for (int j = 0; j < 4; j++) { v[j] = (bf16)a[j]; v[4 + j] = (bf16)b[j]; }
    }
    ((f32x4*)out)[i * 2] = a;
    ((f32x4*)out)[i * 2 + 1] = b;
    ((bf16x8*)outb)[i] = v;
}

// ---------------------------------------------------------------------------
// transpose+permute: sru_w (1024,8192) -> wT' (8192,1024) with row n'=h*4+j
__global__ __launch_bounds__(256) void k_transpose(const int* __restrict__ flag, const void* __restrict__ in,
                                                   bf16* __restrict__ out, int R, int C) {
    __shared__ __align__(16) bf16 t[64][72];
    int tid = threadIdx.x;
    int c0 = blockIdx.x * 64, r0 = blockIdx.y * 64;
#pragma unroll
    for (int i = 0; i < 2; i++) {
        int idx = tid + i * 256;
        int r = idx >> 3, ch = idx & 7;
        size_t base = (size_t)(r0 + r) * C + c0 + ch * 8;
        bf16x8 v;
        if (*flag) {
            v = *(const bf16x8*)((const bf16*)in + base);
        } else {
            const float* f = (const float*)in + base;
            f32x4 x = *(const f32x4*)f, y = *(const f32x4*)(f + 4);
#pragma unroll
            for (int j = 0; j < 4; j++) { v[j] = (bf16)x[j]; v[4 + j] = (bf16)y[j]; }
        }
        *(bf16x8*)&t[r][ch * 8] = v;
    }
    __syncthreads();
    int nbase = c0 & 2047, joff = c0 >> 11;
#pragma unroll
    for (int i = 0; i < 2; i++) {
        int idx = tid + i * 256;
        int cr = idx >> 3, ch = idx & 7;
        bf16x8 v;
#pragma unroll
        for (int j = 0; j < 8; j++) v[j] = t[ch * 8 + j][cr];
        int np = (nbase + cr) * 4 + joff;
        *(bf16x8*)(out + (size_t)np * R + r0 + ch * 8) = v;
    }
}

// ---------------------------------------------------------------------------
// V pre-transpose: in rows m=s*4+b, 64 cols -> Vt[b][n][s] ([4][1024][1024])
__global__ __launch_bounds__(256) void k_vtr(const bf16* __restrict__ in, int ldv, bf16* __restrict__ out) {
    int nt = blockIdx.x, st = blockIdx.y, b = blockIdx.z;
    __shared__ __align__(16) bf16 t[64][72];
    int tid = threadIdx.x;
#pragma unroll
    for (int i = 0; i < 2; i++) {
        int idx = tid + i * 256;
        int r = idx >> 3, ch = idx & 7;
        bf16x8 v = *(const bf16x8*)(in + (size_t)((st * 64 + r) * 4 + b) * ldv + nt * 64 + ch * 8);
        *(bf16x8*)&t[r][ch * 8] = v;
    }
    __syncthreads();
#pragma unroll
    for (int i = 0; i < 2; i++) {
        int idx = tid + i * 256;
        int dr = idx >> 3, ch = idx & 7;
        bf16x8 v;
#pragma unroll
        for (int j = 0; j < 8; j++) v[j] = t[ch * 8 + j][dr];
        *(bf16x8*)(out + (size_t)(b * 1024 + nt * 64 + dr) * 1024 + st * 64 + ch * 8) = v;
    }
}

// ---------------------------------------------------------------------------
// GEMM (bf16 A): C[M,N] = A @ W^T (+bias)(*scale). BMx128 tile, BK=64.
__device__ __forceinline__ int swzB(int r, int byteInRow) {
    return r * 128 + (byteInRow ^ ((r & 7) << 4));
}

template <int BM>
__global__ __launch_bounds__(256) void k_gemm(
    const bf16* __restrict__ A, int lda,
    const bf16* __restrict__ W, int ldw,
    const bf16* __restrict__ bias,
    float* __restrict__ Cf, bf16* __restrict__ Cb, int ldc,
    int K, int scale_end, float scale) {
    constexpr int MI = BM / 32;
    __shared__ __align__(16) char Asm[BM * 128];
    __shared__ __align__(16) char Bsm[128 * 128];
    int tid = threadIdx.x, w = tid >> 6, l = tid & 63, lg = l >> 4, lm = l & 15;
    int wm = w >> 1, wn = w & 1;
    int m0 = blockIdx.y * BM, n0 = blockIdx.x * 128;

    f32x4 acc[MI][4] = {};

    for (int k0 = 0; k0 < K; k0 += 64) {
#pragma unroll
        for (int i = 0; i < BM / 32; i++) {
            int r = i * 32 + w * 8 + (l >> 3);
            int gs = (l & 7) ^ (r & 7);
            gl_lds16(A + (size_t)(m0 + r) * lda + k0 + gs * 8,
                     Asm + (i * 32 + w * 8) * 128);
        }
#pragma unroll
        for (int i = 0; i < 4; i++) {
            int r = i * 32 + w * 8 + (l >> 3);
            int gs = (l & 7) ^ (r & 7);
            gl_lds16(W + (size_t)(n0 + r) * ldw + k0 + gs * 8,
                     Bsm + (i * 32 + w * 8) * 128);
        }
        __syncthreads();
#pragma unroll
        for (int kh = 0; kh < 2; kh++) {
            bf16x8 af[MI], bfr[4];
#pragma unroll
            for (int i = 0; i < MI; i++)
                af[i] = *(const bf16x8*)(Asm + swzB(wm * (BM / 2) + i * 16 + lm, kh * 64 + lg * 16));
#pragma unroll
            for (int j = 0; j < 4; j++)
                bfr[j] = *(const bf16x8*)(Bsm + swzB(wn * 64 + j * 16 + lm, kh * 64 + lg * 16));
#pragma unroll
            for (int i = 0; i < MI; i++)
#pragma unroll
                for (int j = 0; j < 4; j++)
                    acc[i][j] = MFMA16(af[i], bfr[j], acc[i][j]);
        }
        __syncthreads();
    }
#pragma unroll
    for (int j = 0; j < 4; j++) {
        int col = n0 + wn * 64 + j * 16 + lm;
        float bv = bias ? (float)bias[col] : 0.f;
        float sc = (col < scale_end) ? scale : 1.f;
#pragma unroll
        for (int i = 0; i < MI; i++) {
            int row = m0 + wm * (BM / 2) + i * 16 + lg * 4;
#pragma unroll
            for (int r = 0; r < 4; r++) {
                float v = (acc[i][j][r] + bv) * sc;
                size_t idx = (size_t)(row + r) * ldc + col;
                if (Cf) Cf[idx] = v;
                if (Cb) Cb[idx] = (bf16)v;
            }
        }
    }
}

// ---------------------------------------------------------------------------
// Flash attention, QBLK=128 (each wave owns 2 row-tiles u=0,1): K/V staging and
// the 2 barriers per kt amortize over 2x output. V pre-transposed; defer-max;
// lane-partial lrun. Grid (h+16*b, qblk of 128 rows).
__device__ __forceinline__ int swz2(int row, int byteInRow) {
    return row * 128 + (byteInRow ^ ((row & 7) << 4));
}
__device__ __forceinline__ int swzP(int row, int byteInRow) {
    return row * 128 + (byteInRow ^ ((row & 3) << 4) ^ (((row >> 2) & 1) << 6));
}

__global__ __launch_bounds__(256) void k_attn(
    const bf16* __restrict__ Qp, const bf16* __restrict__ Kp, const bf16* __restrict__ Vt,
    int ldq, int ldk, bf16* __restrict__ Op) {
    int h = blockIdx.x & 15, b = blockIdx.x >> 4, qblk = blockIdx.y;
    int tid = threadIdx.x, w = tid >> 6, l = tid & 63, lg = l >> 4, lm = l & 15;
    int r0 = tid >> 3, ch = tid & 7;

    __shared__ __align__(16) char Ksm[64 * 128];
    __shared__ __align__(16) char Vsm[64 * 128];
    __shared__ __align__(16) char Psm[4][32 * 128];  // per-wave P (32 rows)

    bf16x8 qf[2][2];
#pragma unroll
    for (int u = 0; u < 2; u++) {
        int qrow = qblk * 128 + w * 32 + u * 16 + lm;
#pragma unroll
        for (int kk = 0; kk < 2; kk++)
            qf[u][kk] = *(const bf16x8*)(Qp + (size_t)(qrow * 4 + b) * ldq + h * 64 + kk * 32 + lg * 8);
    }

    const bf16* vbase = Vt + (size_t)(b * 1024 + h * 64) * 1024;

    bf16x8 kreg[2], vreg[2];
#pragma unroll
    for (int p = 0; p < 2; p++) {
        int r = r0 + p * 32;
        kreg[p] = *(const bf16x8*)(Kp + (size_t)(r * 4 + b) * ldk + h * 64 + ch * 8);
        vreg[p] = *(const bf16x8*)(vbase + (size_t)r * 1024 + ch * 8);
    }

    f32x4 oa[2][4] = {};
    float mrun[2][4], lrun[2][4];  // lrun lane-partial
#pragma unroll
    for (int u = 0; u < 2; u++)
#pragma unroll
        for (int r = 0; r < 4; r++) { mrun[u][r] = -1e30f; lrun[u][r] = 0.f; }

    for (int kt = 0; kt < 16; kt++) {
        __syncthreads();
#pragma unroll
        for (int p = 0; p < 2; p++) {
            int r = r0 + p * 32;
            *(bf16x8*)(Ksm + swz2(r, ch * 16)) = kreg[p];
            *(bf16x8*)(Vsm + swz2(r, ch * 16)) = vreg[p];
        }
        if (kt < 15) {
#pragma unroll
            for (int p = 0; p < 2; p++) {
                int r = (kt + 1) * 64 + r0 + p * 32;
                kreg[p] = *(const bf16x8*)(Kp + (size_t)(r * 4 + b) * ldk + h * 64 + ch * 8);
                vreg[p] = *(const bf16x8*)(vbase + (size_t)(r0 + p * 32) * 1024 + (kt + 1) * 64 + ch * 8);
            }
        }
        __syncthreads();

        f32x4 sc[2][4] = {};
#pragma unroll
        for (int kk = 0; kk < 2; kk++)
#pragma unroll
            for (int jt = 0; jt < 4; jt++) {
                bf16x8 bk = *(const bf16x8*)(Ksm + swz2(jt * 16 + lm, kk * 64 + lg * 16));
#pragma unroll
                for (int u = 0; u < 2; u++)
                    sc[u][jt] = MFMA16(qf[u][kk], bk, sc[u][jt]);
            }

        // row max per u (16-lane reduce)
        float m_[2][4];
#pragma unroll
        for (int u = 0; u < 2; u++)
#pragma unroll
            for (int r = 0; r < 4; r++) {
                float m = fmaxf(fmaxf(sc[u][0][r], sc[u][1][r]), fmaxf(sc[u][2][r], sc[u][3][r]));
#pragma unroll
                for (int d = 1; d < 16; d <<= 1) m = fmaxf(m, __shfl_xor(m, d));
                m_[u][r] = m;
            }
        bool grow = false;
#pragma unroll
        for (int u = 0; u < 2; u++)
#pragma unroll
            for (int r = 0; r < 4; r++) grow = grow || (m_[u][r] > mrun[u][r] + 8.f);
        if (__any(grow)) {
#pragma unroll
            for (int u = 0; u < 2; u++)
#pragma unroll
                for (int r = 0; r < 4; r++) {
                    float mn = fmaxf(mrun[u][r], m_[u][r]);
                    float al = __expf(mrun[u][r] - mn);
                    mrun[u][r] = mn;
                    lrun[u][r] *= al;
#pragma unroll
                    for (int ot = 0; ot < 4; ot++) oa[u][ot][r] *= al;
                }
        }
#pragma unroll
        for (int u = 0; u < 2; u++)
#pragma unroll
            for (int jt = 0; jt < 4; jt++)
#pragma unroll
                for (int r = 0; r < 4; r++) {
                    float p = __expf(sc[u][jt][r] - mrun[u][r]);
                    sc[u][jt][r] = p;
                    lrun[u][r] += p;
                }
#pragma unroll
        for (int u = 0; u < 2; u++)
#pragma unroll
            for (int jt = 0; jt < 4; jt++)
#pragma unroll
                for (int r = 0; r < 4; r++)
                    *(bf16*)(Psm[w] + swzP(u * 16 + lg * 4 + r, (jt * 16 + lm) * 2)) = (bf16)sc[u][jt][r];
        asm volatile("s_waitcnt lgkmcnt(0)" ::: "memory");
        __builtin_amdgcn_sched_barrier(0);
#pragma unroll
        for (int kk = 0; kk < 2; kk++) {
            bf16x8 pa[2];
#pragma unroll
            for (int u = 0; u < 2; u++)
                pa[u] = *(const bf16x8*)(Psm[w] + swzP(u * 16 + lm, kk * 64 + lg * 16));
#pragma unroll
            for (int ot = 0; ot < 4; ot++) {
                bf16x8 bv = *(const bf16x8*)(Vsm + swz2(ot * 16 + lm, kk * 64 + lg * 16));
#pragma unroll
                for (int u = 0; u < 2; u++)
                    oa[u][ot] = MFMA16(pa[u], bv, oa[u][ot]);
            }
        }
    }
#pragma unroll
    for (int u = 0; u < 2; u++)
#pragma unroll
        for (int r = 0; r < 4; r++) {
#pragma unroll
            for (int d = 1; d < 16; d <<= 1) lrun[u][r] += __shfl_xor(lrun[u][r], d);
            float inv = 1.f / lrun[u][r];
            int srow = qblk * 128 + w * 32 + u * 16 + lg * 4 + r;
#pragma unroll
            for (int ot = 0; ot < 4; ot++) {
                int col = h * 64 + ot * 16 + lm;
                Op[(size_t)(srow * 4 + b) * 1024 + col] = (bf16)(oa[u][ot][r] * inv);
            }
        }
}

// ---------------------------------------------------------------------------
// residual-add + LayerNorm over D=1024 (f32 math). X dtype templated.
template <typename XT>
__global__ __launch_bounds__(256) void k_addln(
    const XT* __restrict__ X, const float* __restrict__ Yd,
    const bf16* __restrict__ g, const bf16* __restrict__ bb,
    float* __restrict__ outF, bf16* __restrict__ outB) {
    int row = blockIdx.x * 4 + (threadIdx.x >> 6);
    int l = threadIdx.x & 63;
    const XT* xr = X + (size_t)row * 1024;
    const float* yr = Yd + (size_t)row * 1024;
    float v[16];
    float s = 0.f, s2 = 0.f;
#pragma unroll
    for (int q = 0; q < 4; q++) {
        float xa[4];
        if constexpr (sizeof(XT) == 4) {
            f32x4 a = *(const f32x4*)(xr + l * 4 + q * 256);
#pragma unroll
            for (int j = 0; j < 4; j++) xa[j] = a[j];
        } else {
            bf16x4 a = *(const bf16x4*)(xr + l * 4 + q * 256);
#pragma unroll
            for (int j = 0; j < 4; j++) xa[j] = (float)a[j];
        }
        f32x4 c = *(const f32x4*)(yr + l * 4 + q * 256);
#pragma unroll
        for (int j = 0; j < 4; j++) {
            float t = xa[j] + c[j];
            v[q * 4 + j] = t;
            s += t;
            s2 += t * t;
        }
    }
#pragma unroll
    for (int d = 1; d < 64; d <<= 1) { s += __shfl_xor(s, d); s2 += __shfl_xor(s2, d); }
    float mu = s * (1.f / 1024.f);
    float var = s2 * (1.f / 1024.f) - mu * mu;
    float rstd = rsqrtf(var + 1e-5f);
#pragma unroll
    for (int q = 0; q < 4; q++)
#pragma unroll
        for (int j = 0; j < 4; j++) {
            int col = l * 4 + q * 256 + j;
            float y = (v[q * 4 + j] - mu) * rstd * (float)g[col] + (float)bb[col];
            if (outF) outF[(size_t)row * 1024 + col] = y;
            if (outB) outB[(size_t)row * 1024 + col] = (bf16)y;
        }
}

// ---------------------------------------------------------------------------
// SRU scan, full 1024 steps (U bf16, one bf16x4 gate group per step/channel).
__global__ __launch_bounds__(64) void k_sru(
    const bf16* __restrict__ U, const bf16* __restrict__ v2, const bf16* __restrict__ b2,
    bf16* __restrict__ Hb) {
    int ch = blockIdx.x * 64 + threadIdx.x;  // 0..8191
    int b = ch >> 11, hh = ch & 2047;
    float vf = (float)v2[hh], vr = (float)v2[2048 + hh];
    float bfv = (float)b2[hh], brv = (float)b2[2048 + hh];
    float c = 0.f;
    const bf16x4* u = (const bf16x4*)(U + (size_t)b * 8192 + (size_t)hh * 4);  // +8192 units/step
    bf16* ho = Hb + (size_t)b * 2048 + hh;                                     // +8192 elem/step
    bf16x4 q[8];
#pragma unroll
    for (int i = 0; i < 8; i++) q[i] = u[(size_t)i * 8192];
    for (int it = 0; it < 128; it++) {
#pragma unroll
        for (int j = 0; j < 8; j++) {
            int ls = it * 8 + j;
            bf16x4 v = q[j];
            if (ls + 8 < 1024) q[j] = u[(size_t)(ls + 8) * 8192];
            float xc = (float)v[0], fp = (float)v[1], rp = (float)v[2], xh = (float)v[3];
            float f = 1.f / (1.f + __expf(-(fp + vf * c + bfv)));
            float r = 1.f / (1.f + __expf(-(rp + vr * c + brv)));
            c = f * c + (1.f - f) * xc;
            float hv = r * c + (1.f - r) * xh;
            ho[(size_t)ls * 8192] = (bf16)hv;
        }
    }
}

// ---------------------------------------------------------------------------
extern "C" void kernel_launch(void* const* d_in, const int* in_sizes, int n_in,
                              void* d_out, int out_size, void* d_ws, size_t ws_size,
                              hipStream_t stream) {
    const size_t MB = 1u << 20;
    char* ws = (char*)d_ws;

    bf16* memB    = (bf16*)(ws + 0);        // 4096x1024 (dead after ca-kv GEMM)
    bf16* sawinB  = (bf16*)(ws + 8 * MB);
    bf16* sawoutB = (bf16*)(ws + 14 * MB);
    bf16* cawinB  = (bf16*)(ws + 16 * MB);
    bf16* cawoutB = (bf16*)(ws + 22 * MB);
    bf16* lin2wB  = (bf16*)(ws + 24 * MB);
    char* S0 = ws + 28 * MB;
    bf16* sabinB  = (bf16*)(S0 + 0 * 8192);
    bf16* cabinB  = (bf16*)(S0 + 1 * 8192);
    bf16* saboutB = (bf16*)(S0 + 2 * 8192);
    bf16* caboutB = (bf16*)(S0 + 3 * 8192);
    bf16* lin2bB  = (bf16*)(S0 + 4 * 8192);
    bf16* sruvB   = (bf16*)(S0 + 5 * 8192);
    bf16* srubB   = (bf16*)(S0 + 6 * 8192);
    bf16* ln1gB   = (bf16*)(S0 + 7 * 8192);
    bf16* ln1bB   = (bf16*)(S0 + 8 * 8192);
    bf16* ln2gB   = (bf16*)(S0 + 9 * 8192);
    bf16* ln2bB   = (bf16*)(S0 + 10 * 8192);
    bf16* ln3gB   = (bf16*)(S0 + 11 * 8192);
    bf16* ln3bB   = (bf16*)(S0 + 12 * 8192);
    int*  flag    = (int*)(S0 + 13 * 8192);

    // pipeline region P; peak use P+96MB = ws+125MB (proven envelope)
    char* P = ws + 29 * MB;
    float* t0   = (float*)(P + 0);        // 4096x1024 f32 (ln1 residual)
    bf16*  qkv  = (bf16*)(P + 16 * MB);   // 4096x3072
    bf16*  qca  = qkv;                    // 4096x1024 (reuse)
    bf16*  kvca = (bf16*)(P + 24 * MB);   // 4096x2048 (overlays dead sa-K/V)
    bf16*  obuf = (bf16*)(P + 40 * MB);   // 4096x1024 attn out
    bf16*  Vt   = (bf16*)(P + 56 * MB);   // 4x1024x1024
    bf16*  t0b  = (bf16*)(P + 64 * MB);   // 4096x1024 (dead after QKV GEMM)
    float* tmp  = (float*)(P + 64 * MB);  // 4096x1024 f32 out-proj results
    bf16*  t1   = (bf16*)(P + 80 * MB);   // 4096x1024 (ln1 out)
    bf16*  t2   = (bf16*)(ws + 0);        // 4096x1024 (ln2 out; overlays dead memB)
    bf16*  wT   = (bf16*)(P + 0);         // 8192x1024 (SRU; overlays dead t0)
    bf16*  U    = (bf16*)(P + 16 * MB);   // 4096x8192 bf16 = 64MB (dead qkv..tmp)
    bf16*  hb   = (bf16*)(P + 80 * MB);   // 4096x2048 (overlays dead t1)
    float* tmp2 = (float*)(P + 16 * MB);  // 4096x1024 f32 (U dead after scan)

    k_detect<<<1, 256, 0, stream>>>(d_in[0], flag);
    BigSegs bg;
    {
        const void* bsrc[6] = {d_in[1], d_in[2], d_in[4], d_in[6], d_in[8], d_in[13]};
        bf16* bdst[6] = {memB, sawinB, sawoutB, cawinB, cawoutB, lin2wB};
        const int cum[7] = {0, 2048, 3584, 4096, 5632, 6144, 7168};
        for (int i = 0; i < 6; i++) { bg.src[i] = bsrc[i]; bg.dst[i] = bdst[i]; }
        for (int i = 0; i < 7; i++) bg.cum[i] = cum[i];
    }
    k_norm_big<<<7168, 256, 0, stream>>>(flag, bg);
    SmallSegs sg;
    const int srcIdx[13] = {3, 7, 5, 9, 14, 11, 12, 15, 16, 17, 18, 19, 20};
    bf16* dsts[13] = {sabinB, cabinB, saboutB, caboutB, lin2bB, sruvB, srubB,
                      ln1gB, ln1bB, ln2gB, ln2bB, ln3gB, ln3bB};
    const int n8s[13] = {384, 384, 128, 128, 128, 512, 512, 128, 128, 128, 128, 128, 128};
    for (int i = 0; i < 13; i++) { sg.src[i] = d_in[srcIdx[i]]; sg.dst[i] = dsts[i]; sg.n8[i] = n8s[i]; }
    k_norm_multi<<<13, 256, 0, stream>>>(flag, sg);

    k_cvt<<<2048, 256, 0, stream>>>(flag, d_in[0], t0, t0b);

    // ---- self attention ----
    k_gemm<128><<<dim3(24, 32), 256, 0, stream>>>(t0b, 1024, sawinB, 1024, sabinB,
                                                  nullptr, qkv, 3072, 1024, 1024, 0.125f);
    k_vtr<<<dim3(16, 16, 4), 256, 0, stream>>>(qkv + 2048, 3072, Vt);
    k_attn<<<dim3(64, 8), 256, 0, stream>>>(qkv, qkv + 1024, Vt, 3072, 3072, obuf);
    k_gemm<64><<<dim3(8, 64), 256, 0, stream>>>(obuf, 1024, sawoutB, 1024, saboutB,
                                                tmp, nullptr, 1024, 1024, 0, 1.f);
    k_addln<float><<<1024, 256, 0, stream>>>(t0, tmp, ln1gB, ln1bB, nullptr, t1);

    // ---- cross attention ----
    k_gemm<64><<<dim3(8, 64), 256, 0, stream>>>(t1, 1024, cawinB, 1024, cabinB,
                                                nullptr, qca, 1024, 1024, 1024, 0.125f);
    k_gemm<128><<<dim3(16, 32), 256, 0, stream>>>(memB, 1024, cawinB + (size_t)1024 * 1024, 1024,
                                                  cabinB + 1024, nullptr, kvca, 2048, 1024, 0, 1.f);
    k_vtr<<<dim3(16, 16, 4), 256, 0, stream>>>(kvca + 1024, 2048, Vt);
    k_attn<<<dim3(64, 8), 256, 0, stream>>>(qca, kvca, Vt, 1024, 2048, obuf);
    k_gemm<64><<<dim3(8, 64), 256, 0, stream>>>(obuf, 1024, cawoutB, 1024, caboutB,
                                                tmp, nullptr, 1024, 1024, 0, 1.f);
    k_addln<bf16><<<1024, 256, 0, stream>>>(t1, tmp, ln2gB, ln2bB, nullptr, t2);

    // ---- SRU (single GEMM + single scan) ----
    k_transpose<<<dim3(128, 16), 256, 0, stream>>>(flag, d_in[10], wT, 1024, 8192);
    k_gemm<128><<<dim3(64, 32), 256, 0, stream>>>(t2, 1024, wT, 1024,
                                                  nullptr, nullptr, U, 8192, 1024, 0, 1.f);
    k_sru<<<128, 64, 0, stream>>>(U, sruvB, srubB, hb);
    k_gemm<64><<<dim3(8, 64), 256, 0, stream>>>(hb, 2048, lin2wB, 2048, lin2bB,
                                                tmp2, nullptr, 1024, 2048, 0, 1.f);
    k_addln<bf16><<<1024, 256, 0, stream>>>(t2, tmp2, ln3gB, ln3bB, (float*)d_out, nullptr);
}

// Round 11
// 518.507 us; speedup vs baseline: 1.9145x; 1.0652x over previous
//
#include <hip/hip_runtime.h>
#include <hip/hip_bf16.h>

typedef __bf16 bf16;
typedef bf16 bf16x8 __attribute__((ext_vector_type(8)));
typedef bf16 bf16x4 __attribute__((ext_vector_type(4)));
typedef float f32x4 __attribute__((ext_vector_type(4)));

#define MFMA16(a, b, c) __builtin_amdgcn_mfma_f32_16x16x32_bf16((a), (b), (c), 0, 0, 0)

__device__ __forceinline__ void gl_lds16(const void* g, void* l) {
    __builtin_amdgcn_global_load_lds((const __attribute__((address_space(1))) void*)g,
                                     (__attribute__((address_space(3))) void*)l, 16, 0, 0);
}

// ---------------------------------------------------------------------------
__global__ __launch_bounds__(256) void k_detect(const void* __restrict__ src, int* __restrict__ flag) {
    __shared__ int cnt;
    if (threadIdx.x == 0) cnt = 0;
    __syncthreads();
    const unsigned int* w = (const unsigned int*)src;
    int local = 0;
    for (int i = threadIdx.x; i < 4096; i += 256) {
        unsigned int e = (w[i] >> 7) & 0xFF;
        local += (e > 100 && e < 150) ? 1 : 0;
    }
    atomicAdd(&cnt, local);
    __syncthreads();
    if (threadIdx.x == 0) *flag = (cnt > 2048) ? 1 : 0;
}

struct BigSegs {
    const void* src[6];
    bf16* dst[6];
    int cum[7];
};
__global__ __launch_bounds__(256) void k_norm_big(const int* __restrict__ flag, BigSegs s) {
    int seg = 0;
#pragma unroll
    for (int t = 0; t < 5; t++) seg += (blockIdx.x >= s.cum[t + 1]) ? 1 : 0;
    int i = (blockIdx.x - s.cum[seg]) * 256 + threadIdx.x;
    const void* sp = s.src[seg];
    bf16* dp = s.dst[seg];
    if (*flag) {
        ((bf16x8*)dp)[i] = ((const bf16x8*)sp)[i];
    } else {
        const float* fs = (const float*)sp + (size_t)i * 8;
        bf16x8 o;
#pragma unroll
        for (int j = 0; j < 8; j++) o[j] = (bf16)fs[j];
        ((bf16x8*)dp)[i] = o;
    }
}

struct SmallSegs {
    const void* src[13];
    bf16* dst[13];
    int n8[13];
};
__global__ __launch_bounds__(256) void k_norm_multi(const int* __restrict__ flag, SmallSegs s) {
    int seg = blockIdx.x;
    const void* sp = s.src[seg];
    bf16* dp = s.dst[seg];
    int n = s.n8[seg];
    int f = *flag;
    for (int i = threadIdx.x; i < n; i += 256) {
        if (f) {
            ((bf16x8*)dp)[i] = ((const bf16x8*)sp)[i];
        } else {
            const float* fs = (const float*)sp + (size_t)i * 8;
            bf16x8 o;
#pragma unroll
            for (int j = 0; j < 8; j++) o[j] = (bf16)fs[j];
            ((bf16x8*)dp)[i] = o;
        }
    }
}

// tgt -> f32 residual t0 AND bf16 copy t0b
__global__ __launch_bounds__(256) void k_cvt(const int* __restrict__ flag, const void* __restrict__ in,
                                             float* __restrict__ out, bf16* __restrict__ outb) {
    size_t i = (size_t)blockIdx.x * 256 + threadIdx.x;
    f32x4 a, b;
    bf16x8 v;
    if (*flag) {
        v = ((const bf16x8*)in)[i];
#pragma unroll
        for (int j = 0; j < 4; j++) { a[j] = (float)v[j]; b[j] = (float)v[4 + j]; }
    } else {
        a = ((const f32x4*)in)[i * 2];
        b = ((const f32x4*)in)[i * 2 + 1];
#pragma unroll
        for (int j = 0; j < 4; j++) { v[j] = (bf16)a[j]; v[4 + j] = (bf16)b[j]; }
    }
    ((f32x4*)out)[i * 2] = a;
    ((f32x4*)out)[i * 2 + 1] = b;
    ((bf16x8*)outb)[i] = v;
}

// ---------------------------------------------------------------------------
// transpose+permute: sru_w (1024,8192) -> wT' (8192,1024) with row n'=h*4+j
__global__ __launch_bounds__(256) void k_transpose(const int* __restrict__ flag, const void* __restrict__ in,
                                                   bf16* __restrict__ out, int R, int C) {
    __shared__ __align__(16) bf16 t[64][72];
    int tid = threadIdx.x;
    int c0 = blockIdx.x * 64, r0 = blockIdx.y * 64;
#pragma unroll
    for (int i = 0; i < 2; i++) {
        int idx = tid + i * 256;
        int r = idx >> 3, ch = idx & 7;
        size_t base = (size_t)(r0 + r) * C + c0 + ch * 8;
        bf16x8 v;
        if (*flag) {
            v = *(const bf16x8*)((const bf16*)in + base);
        } else {
            const float* f = (const float*)in + base;
            f32x4 x = *(const f32x4*)f, y = *(const f32x4*)(f + 4);
#pragma unroll
            for (int j = 0; j < 4; j++) { v[j] = (bf16)x[j]; v[4 + j] = (bf16)y[j]; }
        }
        *(bf16x8*)&t[r][ch * 8] = v;
    }
    __syncthreads();
    int nbase = c0 & 2047, joff = c0 >> 11;
#pragma unroll
    for (int i = 0; i < 2; i++) {
        int idx = tid + i * 256;
        int cr = idx >> 3, ch = idx & 7;
        bf16x8 v;
#pragma unroll
        for (int j = 0; j < 8; j++) v[j] = t[ch * 8 + j][cr];
        int np = (nbase + cr) * 4 + joff;
        *(bf16x8*)(out + (size_t)np * R + r0 + ch * 8) = v;
    }
}

// ---------------------------------------------------------------------------
// V pre-transpose: in rows m=s*4+b, 64 cols -> Vt[b][n][s] ([4][1024][1024])
__global__ __launch_bounds__(256) void k_vtr(const bf16* __restrict__ in, int ldv, bf16* __restrict__ out) {
    int nt = blockIdx.x, st = blockIdx.y, b = blockIdx.z;
    __shared__ __align__(16) bf16 t[64][72];
    int tid = threadIdx.x;
#pragma unroll
    for (int i = 0; i < 2; i++) {
        int idx = tid + i * 256;
        int r = idx >> 3, ch = idx & 7;
        bf16x8 v = *(const bf16x8*)(in + (size_t)((st * 64 + r) * 4 + b) * ldv + nt * 64 + ch * 8);
        *(bf16x8*)&t[r][ch * 8] = v;
    }
    __syncthreads();
#pragma unroll
    for (int i = 0; i < 2; i++) {
        int idx = tid + i * 256;
        int dr = idx >> 3, ch = idx & 7;
        bf16x8 v;
#pragma unroll
        for (int j = 0; j < 8; j++) v[j] = t[ch * 8 + j][dr];
        *(bf16x8*)(out + (size_t)(b * 1024 + nt * 64 + dr) * 1024 + st * 64 + ch * 8) = v;
    }
}

// ---------------------------------------------------------------------------
// GEMM (bf16 A): C[M,N] = A @ W^T (+bias)(*scale). BMx128 tile, BK=64.
// USCAT: scatter write into U2[ch][step][gate] (ch=(row&3)*2048+(col>>2),
// step=row>>2, gate=col&3) for the contiguous-channel SRU scan.
__device__ __forceinline__ int swzB(int r, int byteInRow) {
    return r * 128 + (byteInRow ^ ((r & 7) << 4));
}

template <int BM, bool USCAT>
__global__ __launch_bounds__(256) void k_gemm(
    const bf16* __restrict__ A, int lda,
    const bf16* __restrict__ W, int ldw,
    const bf16* __restrict__ bias,
    float* __restrict__ Cf, bf16* __restrict__ Cb, int ldc,
    int K, int scale_end, float scale) {
    constexpr int MI = BM / 32;
    __shared__ __align__(16) char Asm[BM * 128];
    __shared__ __align__(16) char Bsm[128 * 128];
    int tid = threadIdx.x, w = tid >> 6, l = tid & 63, lg = l >> 4, lm = l & 15;
    int wm = w >> 1, wn = w & 1;
    int m0 = blockIdx.y * BM, n0 = blockIdx.x * 128;

    f32x4 acc[MI][4] = {};

    for (int k0 = 0; k0 < K; k0 += 64) {
#pragma unroll
        for (int i = 0; i < BM / 32; i++) {
            int r = i * 32 + w * 8 + (l >> 3);
            int gs = (l & 7) ^ (r & 7);
            gl_lds16(A + (size_t)(m0 + r) * lda + k0 + gs * 8,
                     Asm + (i * 32 + w * 8) * 128);
        }
#pragma unroll
        for (int i = 0; i < 4; i++) {
            int r = i * 32 + w * 8 + (l >> 3);
            int gs = (l & 7) ^ (r & 7);
            gl_lds16(W + (size_t)(n0 + r) * ldw + k0 + gs * 8,
                     Bsm + (i * 32 + w * 8) * 128);
        }
        __syncthreads();
#pragma unroll
        for (int kh = 0; kh < 2; kh++) {
            bf16x8 af[MI], bfr[4];
#pragma unroll
            for (int i = 0; i < MI; i++)
                af[i] = *(const bf16x8*)(Asm + swzB(wm * (BM / 2) + i * 16 + lm, kh * 64 + lg * 16));
#pragma unroll
            for (int j = 0; j < 4; j++)
                bfr[j] = *(const bf16x8*)(Bsm + swzB(wn * 64 + j * 16 + lm, kh * 64 + lg * 16));
#pragma unroll
            for (int i = 0; i < MI; i++)
#pragma unroll
                for (int j = 0; j < 4; j++)
                    acc[i][j] = MFMA16(af[i], bfr[j], acc[i][j]);
        }
        __syncthreads();
    }
#pragma unroll
    for (int j = 0; j < 4; j++) {
        int col = n0 + wn * 64 + j * 16 + lm;
        float bv = bias ? (float)bias[col] : 0.f;
        float sc = (col < scale_end) ? scale : 1.f;
#pragma unroll
        for (int i = 0; i < MI; i++) {
            int row = m0 + wm * (BM / 2) + i * 16 + lg * 4;
#pragma unroll
            for (int r = 0; r < 4; r++) {
                float v = (acc[i][j][r] + bv) * sc;
                if constexpr (USCAT) {
                    int rw = row + r;
                    int ch = (rw & 3) * 2048 + (col >> 2);
                    size_t idx = (size_t)ch * 4096 + (size_t)(rw >> 2) * 4 + (col & 3);
                    Cb[idx] = (bf16)v;
                } else {
                    size_t idx = (size_t)(row + r) * ldc + col;
                    if (Cf) Cf[idx] = v;
                    if (Cb) Cb[idx] = (bf16)v;
                }
            }
        }
    }
}

// ---------------------------------------------------------------------------
// Flash attention, QBLK=128, V pre-transposed, defer-max, lane-partial lrun.
__device__ __forceinline__ int swz2(int row, int byteInRow) {
    return row * 128 + (byteInRow ^ ((row & 7) << 4));
}
__device__ __forceinline__ int swzP(int row, int byteInRow) {
    return row * 128 + (byteInRow ^ ((row & 3) << 4) ^ (((row >> 2) & 1) << 6));
}

__global__ __launch_bounds__(256) void k_attn(
    const bf16* __restrict__ Qp, const bf16* __restrict__ Kp, const bf16* __restrict__ Vt,
    int ldq, int ldk, bf16* __restrict__ Op) {
    int h = blockIdx.x & 15, b = blockIdx.x >> 4, qblk = blockIdx.y;
    int tid = threadIdx.x, w = tid >> 6, l = tid & 63, lg = l >> 4, lm = l & 15;
    int r0 = tid >> 3, ch = tid & 7;

    __shared__ __align__(16) char Ksm[64 * 128];
    __shared__ __align__(16) char Vsm[64 * 128];
    __shared__ __align__(16) char Psm[4][32 * 128];

    bf16x8 qf[2][2];
#pragma unroll
    for (int u = 0; u < 2; u++) {
        int qrow = qblk * 128 + w * 32 + u * 16 + lm;
#pragma unroll
        for (int kk = 0; kk < 2; kk++)
            qf[u][kk] = *(const bf16x8*)(Qp + (size_t)(qrow * 4 + b) * ldq + h * 64 + kk * 32 + lg * 8);
    }

    const bf16* vbase = Vt + (size_t)(b * 1024 + h * 64) * 1024;

    bf16x8 kreg[2], vreg[2];
#pragma unroll
    for (int p = 0; p < 2; p++) {
        int r = r0 + p * 32;
        kreg[p] = *(const bf16x8*)(Kp + (size_t)(r * 4 + b) * ldk + h * 64 + ch * 8);
        vreg[p] = *(const bf16x8*)(vbase + (size_t)r * 1024 + ch * 8);
    }

    f32x4 oa[2][4] = {};
    float mrun[2][4], lrun[2][4];
#pragma unroll
    for (int u = 0; u < 2; u++)
#pragma unroll
        for (int r = 0; r < 4; r++) { mrun[u][r] = -1e30f; lrun[u][r] = 0.f; }

    for (int kt = 0; kt < 16; kt++) {
        __syncthreads();
#pragma unroll
        for (int p = 0; p < 2; p++) {
            int r = r0 + p * 32;
            *(bf16x8*)(Ksm + swz2(r, ch * 16)) = kreg[p];
            *(bf16x8*)(Vsm + swz2(r, ch * 16)) = vreg[p];
        }
        if (kt < 15) {
#pragma unroll
            for (int p = 0; p < 2; p++) {
                int r = (kt + 1) * 64 + r0 + p * 32;
                kreg[p] = *(const bf16x8*)(Kp + (size_t)(r * 4 + b) * ldk + h * 64 + ch * 8);
                vreg[p] = *(const bf16x8*)(vbase + (size_t)(r0 + p * 32) * 1024 + (kt + 1) * 64 + ch * 8);
            }
        }
        __syncthreads();

        f32x4 sc[2][4] = {};
#pragma unroll
        for (int kk = 0; kk < 2; kk++)
#pragma unroll
            for (int jt = 0; jt < 4; jt++) {
                bf16x8 bk = *(const bf16x8*)(Ksm + swz2(jt * 16 + lm, kk * 64 + lg * 16));
#pragma unroll
                for (int u = 0; u < 2; u++)
                    sc[u][jt] = MFMA16(qf[u][kk], bk, sc[u][jt]);
            }

        float m_[2][4];
#pragma unroll
        for (int u = 0; u < 2; u++)
#pragma unroll
            for (int r = 0; r < 4; r++) {
                float m = fmaxf(fmaxf(sc[u][0][r], sc[u][1][r]), fmaxf(sc[u][2][r], sc[u][3][r]));
#pragma unroll
                for (int d = 1; d < 16; d <<= 1) m = fmaxf(m, __shfl_xor(m, d));
                m_[u][r] = m;
            }
        bool grow = false;
#pragma unroll
        for (int u = 0; u < 2; u++)
#pragma unroll
            for (int r = 0; r < 4; r++) grow = grow || (m_[u][r] > mrun[u][r] + 8.f);
        if (__any(grow)) {
#pragma unroll
            for (int u = 0; u < 2; u++)
#pragma unroll
                for (int r = 0; r < 4; r++) {
                    float mn = fmaxf(mrun[u][r], m_[u][r]);
                    float al = __expf(mrun[u][r] - mn);
                    mrun[u][r] = mn;
                    lrun[u][r] *= al;
#pragma unroll
                    for (int ot = 0; ot < 4; ot++) oa[u][ot][r] *= al;
                }
        }
#pragma unroll
        for (int u = 0; u < 2; u++)
#pragma unroll
            for (int jt = 0; jt < 4; jt++)
#pragma unroll
                for (int r = 0; r < 4; r++) {
                    float p = __expf(sc[u][jt][r] - mrun[u][r]);
                    sc[u][jt][r] = p;
                    lrun[u][r] += p;
                }
#pragma unroll
        for (int u = 0; u < 2; u++)
#pragma unroll
            for (int jt = 0; jt < 4; jt++)
#pragma unroll
                for (int r = 0; r < 4; r++)
                    *(bf16*)(Psm[w] + swzP(u * 16 + lg * 4 + r, (jt * 16 + lm) * 2)) = (bf16)sc[u][jt][r];
        asm volatile("s_waitcnt lgkmcnt(0)" ::: "memory");
        __builtin_amdgcn_sched_barrier(0);
#pragma unroll
        for (int kk = 0; kk < 2; kk++) {
            bf16x8 pa[2];
#pragma unroll
            for (int u = 0; u < 2; u++)
                pa[u] = *(const bf16x8*)(Psm[w] + swzP(u * 16 + lm, kk * 64 + lg * 16));
#pragma unroll
            for (int ot = 0; ot < 4; ot++) {
                bf16x8 bv = *(const bf16x8*)(Vsm + swz2(ot * 16 + lm, kk * 64 + lg * 16));
#pragma unroll
                for (int u = 0; u < 2; u++)
                    oa[u][ot] = MFMA16(pa[u], bv, oa[u][ot]);
            }
        }
    }
#pragma unroll
    for (int u = 0; u < 2; u++)
#pragma unroll
        for (int r = 0; r < 4; r++) {
#pragma unroll
            for (int d = 1; d < 16; d <<= 1) lrun[u][r] += __shfl_xor(lrun[u][r], d);
            float inv = 1.f / lrun[u][r];
            int srow = qblk * 128 + w * 32 + u * 16 + lg * 4 + r;
#pragma unroll
            for (int ot = 0; ot < 4; ot++) {
                int col = h * 64 + ot * 16 + lm;
                Op[(size_t)(srow * 4 + b) * 1024 + col] = (bf16)(oa[u][ot][r] * inv);
            }
        }
}

// ---------------------------------------------------------------------------
// residual-add + LayerNorm over D=1024 (f32 math). X dtype templated.
template <typename XT>
__global__ __launch_bounds__(256) void k_addln(
    const XT* __restrict__ X, const float* __restrict__ Yd,
    const bf16* __restrict__ g, const bf16* __restrict__ bb,
    float* __restrict__ outF, bf16* __restrict__ outB) {
    int row = blockIdx.x * 4 + (threadIdx.x >> 6);
    int l = threadIdx.x & 63;
    const XT* xr = X + (size_t)row * 1024;
    const float* yr = Yd + (size_t)row * 1024;
    float v[16];
    float s = 0.f, s2 = 0.f;
#pragma unroll
    for (int q = 0; q < 4; q++) {
        float xa[4];
        if constexpr (sizeof(XT) == 4) {
            f32x4 a = *(const f32x4*)(xr + l * 4 + q * 256);
#pragma unroll
            for (int j = 0; j < 4; j++) xa[j] = a[j];
        } else {
            bf16x4 a = *(const bf16x4*)(xr + l * 4 + q * 256);
#pragma unroll
            for (int j = 0; j < 4; j++) xa[j] = (float)a[j];
        }
        f32x4 c = *(const f32x4*)(yr + l * 4 + q * 256);
#pragma unroll
        for (int j = 0; j < 4; j++) {
            float t = xa[j] + c[j];
            v[q * 4 + j] = t;
            s += t;
            s2 += t * t;
        }
    }
#pragma unroll
    for (int d = 1; d < 64; d <<= 1) { s += __shfl_xor(s, d); s2 += __shfl_xor(s2, d); }
    float mu = s * (1.f / 1024.f);
    float var = s2 * (1.f / 1024.f) - mu * mu;
    float rstd = rsqrtf(var + 1e-5f);
#pragma unroll
    for (int q = 0; q < 4; q++)
#pragma unroll
        for (int j = 0; j < 4; j++) {
            int col = l * 4 + q * 256 + j;
            float y = (v[q * 4 + j] - mu) * rstd * (float)g[col] + (float)bb[col];
            if (outF) outF[(size_t)row * 1024 + col] = y;
            if (outB) outB[(size_t)row * 1024 + col] = (bf16)y;
        }
}

// ---------------------------------------------------------------------------
// SRU scan over contiguous-channel U2[ch][1024 steps][4 gates] bf16.
// Ring of 16 x bf16x8 (2 steps/slot) = 256 B in flight per thread.
__global__ __launch_bounds__(64) void k_sru(
    const bf16* __restrict__ U2, const bf16* __restrict__ v2, const bf16* __restrict__ b2,
    bf16* __restrict__ Hb) {
    int ch = blockIdx.x * 64 + threadIdx.x;  // 0..8191
    int b = ch >> 11, hh = ch & 2047;
    float vf = (float)v2[hh], vr = (float)v2[2048 + hh];
    float bfv = (float)b2[hh], brv = (float)b2[2048 + hh];
    float c = 0.f;
    const bf16x8* u = (const bf16x8*)(U2 + (size_t)ch * 4096);  // 512 chunks (2 steps each)
    bf16* ho = Hb + (size_t)b * 2048 + hh;                      // +8192 elem/step
    bf16x8 q[16];
#pragma unroll
    for (int i = 0; i < 16; i++) q[i] = u[i];
    for (int it = 0; it < 32; it++) {
#pragma unroll
        for (int j = 0; j < 16; j++) {
            int cidx = it * 16 + j;  // chunk index 0..511
            bf16x8 v = q[j];
            if (cidx + 16 < 512) q[j] = u[cidx + 16];
#pragma unroll
            for (int t = 0; t < 2; t++) {
                float xc = (float)v[t * 4 + 0], fp = (float)v[t * 4 + 1];
                float rp = (float)v[t * 4 + 2], xh = (float)v[t * 4 + 3];
                float f = 1.f / (1.f + __expf(-(fp + vf * c + bfv)));
                float r = 1.f / (1.f + __expf(-(rp + vr * c + brv)));
                c = f * c + (1.f - f) * xc;
                float hv = r * c + (1.f - r) * xh;
                ho[(size_t)(cidx * 2 + t) * 8192] = (bf16)hv;
            }
        }
    }
}

// ---------------------------------------------------------------------------
extern "C" void kernel_launch(void* const* d_in, const int* in_sizes, int n_in,
                              void* d_out, int out_size, void* d_ws, size_t ws_size,
                              hipStream_t stream) {
    const size_t MB = 1u << 20;
    char* ws = (char*)d_ws;

    bf16* memB    = (bf16*)(ws + 0);
    bf16* sawinB  = (bf16*)(ws + 8 * MB);
    bf16* sawoutB = (bf16*)(ws + 14 * MB);
    bf16* cawinB  = (bf16*)(ws + 16 * MB);
    bf16* cawoutB = (bf16*)(ws + 22 * MB);
    bf16* lin2wB  = (bf16*)(ws + 24 * MB);
    char* S0 = ws + 28 * MB;
    bf16* sabinB  = (bf16*)(S0 + 0 * 8192);
    bf16* cabinB  = (bf16*)(S0 + 1 * 8192);
    bf16* saboutB = (bf16*)(S0 + 2 * 8192);
    bf16* caboutB = (bf16*)(S0 + 3 * 8192);
    bf16* lin2bB  = (bf16*)(S0 + 4 * 8192);
    bf16* sruvB   = (bf16*)(S0 + 5 * 8192);
    bf16* srubB   = (bf16*)(S0 + 6 * 8192);
    bf16* ln1gB   = (bf16*)(S0 + 7 * 8192);
    bf16* ln1bB   = (bf16*)(S0 + 8 * 8192);
    bf16* ln2gB   = (bf16*)(S0 + 9 * 8192);
    bf16* ln2bB   = (bf16*)(S0 + 10 * 8192);
    bf16* ln3gB   = (bf16*)(S0 + 11 * 8192);
    bf16* ln3bB   = (bf16*)(S0 + 12 * 8192);
    int*  flag    = (int*)(S0 + 13 * 8192);

    char* P = ws + 29 * MB;
    float* t0   = (float*)(P + 0);
    bf16*  qkv  = (bf16*)(P + 16 * MB);
    bf16*  qca  = qkv;
    bf16*  kvca = (bf16*)(P + 24 * MB);
    bf16*  obuf = (bf16*)(P + 40 * MB);
    bf16*  Vt   = (bf16*)(P + 56 * MB);
    bf16*  t0b  = (bf16*)(P + 64 * MB);
    float* tmp  = (float*)(P + 64 * MB);
    bf16*  t1   = (bf16*)(P + 80 * MB);
    bf16*  t2   = (bf16*)(ws + 0);        // overlays dead memB
    bf16*  wT   = (bf16*)(P + 0);         // overlays dead t0
    bf16*  U2   = (bf16*)(P + 16 * MB);   // 8192ch x 1024step x 4gate bf16 = 64MB
    bf16*  hb   = (bf16*)(P + 80 * MB);   // overlays dead t1
    float* tmp2 = (float*)(P + 16 * MB);  // U2 dead after scan

    k_detect<<<1, 256, 0, stream>>>(d_in[0], flag);
    BigSegs bg;
    {
        const void* bsrc[6] = {d_in[1], d_in[2], d_in[4], d_in[6], d_in[8], d_in[13]};
        bf16* bdst[6] = {memB, sawinB, sawoutB, cawinB, cawoutB, lin2wB};
        const int cum[7] = {0, 2048, 3584, 4096, 5632, 6144, 7168};
        for (int i = 0; i < 6; i++) { bg.src[i] = bsrc[i]; bg.dst[i] = bdst[i]; }
        for (int i = 0; i < 7; i++) bg.cum[i] = cum[i];
    }
    k_norm_big<<<7168, 256, 0, stream>>>(flag, bg);
    SmallSegs sg;
    const int srcIdx[13] = {3, 7, 5, 9, 14, 11, 12, 15, 16, 17, 18, 19, 20};
    bf16* dsts[13] = {sabinB, cabinB, saboutB, caboutB, lin2bB, sruvB, srubB,
                      ln1gB, ln1bB, ln2gB, ln2bB, ln3gB, ln3bB};
    const int n8s[13] = {384, 384, 128, 128, 128, 512, 512, 128, 128, 128, 128, 128, 128};
    for (int i = 0; i < 13; i++) { sg.src[i] = d_in[srcIdx[i]]; sg.dst[i] = dsts[i]; sg.n8[i] = n8s[i]; }
    k_norm_multi<<<13, 256, 0, stream>>>(flag, sg);

    k_cvt<<<2048, 256, 0, stream>>>(flag, d_in[0], t0, t0b);

    // ---- self attention ----
    k_gemm<128, false><<<dim3(24, 32), 256, 0, stream>>>(t0b, 1024, sawinB, 1024, sabinB,
                                                         nullptr, qkv, 3072, 1024, 1024, 0.125f);
    k_vtr<<<dim3(16, 16, 4), 256, 0, stream>>>(qkv + 2048, 3072, Vt);
    k_attn<<<dim3(64, 8), 256, 0, stream>>>(qkv, qkv + 1024, Vt, 3072, 3072, obuf);
    k_gemm<64, false><<<dim3(8, 64), 256, 0, stream>>>(obuf, 1024, sawoutB, 1024, saboutB,
                                                       tmp, nullptr, 1024, 1024, 0, 1.f);
    k_addln<float><<<1024, 256, 0, stream>>>(t0, tmp, ln1gB, ln1bB, nullptr, t1);

    // ---- cross attention ----
    k_gemm<64, false><<<dim3(8, 64), 256, 0, stream>>>(t1, 1024, cawinB, 1024, cabinB,
                                                       nullptr, qca, 1024, 1024, 1024, 0.125f);
    k_gemm<128, false><<<dim3(16, 32), 256, 0, stream>>>(memB, 1024, cawinB + (size_t)1024 * 1024, 1024,
                                                         cabinB + 1024, nullptr, kvca, 2048, 1024, 0, 1.f);
    k_vtr<<<dim3(16, 16, 4), 256, 0, stream>>>(kvca + 1024, 2048, Vt);
    k_attn<<<dim3(64, 8), 256, 0, stream>>>(qca, kvca, Vt, 1024, 2048, obuf);
    k_gemm<64, false><<<dim3(8, 64), 256, 0, stream>>>(obuf, 1024, cawoutB, 1024, caboutB,
                                                       tmp, nullptr, 1024, 1024, 0, 1.f);
    k_addln<bf16><<<1024, 256, 0, stream>>>(t1, tmp, ln2gB, ln2bB, nullptr, t2);

    // ---- SRU (GEMM scatters U2; single contiguous-channel scan) ----
    k_transpose<<<dim3(128, 16), 256, 0, stream>>>(flag, d_in[10], wT, 1024, 8192);
    k_gemm<128, true><<<dim3(64, 32), 256, 0, stream>>>(t2, 1024, wT, 1024,
                                                        nullptr, nullptr, U2, 0, 1024, 0, 1.f);
    k_sru<<<128, 64, 0, stream>>>(U2, sruvB, srubB, hb);
    k_gemm<64, false><<<dim3(8, 64), 256, 0, stream>>>(hb, 2048, lin2wB, 2048, lin2bB,
                                                       tmp2, nullptr, 1024, 2048, 0, 1.f);
    k_addln<bf16><<<1024, 256, 0, stream>>>(t2, tmp2, ln3gB, ln3bB, (float*)d_out, nullptr);
}

// Round 12
// 507.148 us; speedup vs baseline: 1.9574x; 1.0224x over previous
//
#include <hip/hip_runtime.h>
#include <hip/hip_bf16.h>

typedef __bf16 bf16;
typedef bf16 bf16x8 __attribute__((ext_vector_type(8)));
typedef bf16 bf16x4 __attribute__((ext_vector_type(4)));
typedef float f32x4 __attribute__((ext_vector_type(4)));

#define MFMA16(a, b, c) __builtin_amdgcn_mfma_f32_16x16x32_bf16((a), (b), (c), 0, 0, 0)

__device__ __forceinline__ void gl_lds16(const void* g, void* l) {
    __builtin_amdgcn_global_load_lds((const __attribute__((address_space(1))) void*)g,
                                     (__attribute__((address_space(3))) void*)l, 16, 0, 0);
}

// ---------------------------------------------------------------------------
__global__ __launch_bounds__(256) void k_detect(const void* __restrict__ src, int* __restrict__ flag) {
    __shared__ int cnt;
    if (threadIdx.x == 0) cnt = 0;
    __syncthreads();
    const unsigned int* w = (const unsigned int*)src;
    int local = 0;
    for (int i = threadIdx.x; i < 4096; i += 256) {
        unsigned int e = (w[i] >> 7) & 0xFF;
        local += (e > 100 && e < 150) ? 1 : 0;
    }
    atomicAdd(&cnt, local);
    __syncthreads();
    if (threadIdx.x == 0) *flag = (cnt > 2048) ? 1 : 0;
}

struct BigSegs {
    const void* src[6];
    bf16* dst[6];
    int cum[7];
};
__global__ __launch_bounds__(256) void k_norm_big(const int* __restrict__ flag, BigSegs s) {
    int seg = 0;
#pragma unroll
    for (int t = 0; t < 5; t++) seg += (blockIdx.x >= s.cum[t + 1]) ? 1 : 0;
    int i = (blockIdx.x - s.cum[seg]) * 256 + threadIdx.x;
    const void* sp = s.src[seg];
    bf16* dp = s.dst[seg];
    if (*flag) {
        ((bf16x8*)dp)[i] = ((const bf16x8*)sp)[i];
    } else {
        const float* fs = (const float*)sp + (size_t)i * 8;
        bf16x8 o;
#pragma unroll
        for (int j = 0; j < 8; j++) o[j] = (bf16)fs[j];
        ((bf16x8*)dp)[i] = o;
    }
}

struct SmallSegs {
    const void* src[13];
    bf16* dst[13];
    int n8[13];
};
__global__ __launch_bounds__(256) void k_norm_multi(const int* __restrict__ flag, SmallSegs s) {
    int seg = blockIdx.x;
    const void* sp = s.src[seg];
    bf16* dp = s.dst[seg];
    int n = s.n8[seg];
    int f = *flag;
    for (int i = threadIdx.x; i < n; i += 256) {
        if (f) {
            ((bf16x8*)dp)[i] = ((const bf16x8*)sp)[i];
        } else {
            const float* fs = (const float*)sp + (size_t)i * 8;
            bf16x8 o;
#pragma unroll
            for (int j = 0; j < 8; j++) o[j] = (bf16)fs[j];
            ((bf16x8*)dp)[i] = o;
        }
    }
}

// tgt -> f32 residual t0 AND bf16 copy t0b
__global__ __launch_bounds__(256) void k_cvt(const int* __restrict__ flag, const void* __restrict__ in,
                                             float* __restrict__ out, bf16* __restrict__ outb) {
    size_t i = (size_t)blockIdx.x * 256 + threadIdx.x;
    f32x4 a, b;
    bf16x8 v;
    if (*flag) {
        v = ((const bf16x8*)in)[i];
#pragma unroll
        for (int j = 0; j < 4; j++) { a[j] = (float)v[j]; b[j] = (float)v[4 + j]; }
    } else {
        a = ((const f32x4*)in)[i * 2];
        b = ((const f32x4*)in)[i * 2 + 1];
#pragma unroll
        for (int j = 0; j < 4; j++) { v[j] = (bf16)a[j]; v[4 + j] = (bf16)b[j]; }
    }
    ((f32x4*)out)[i * 2] = a;
    ((f32x4*)out)[i * 2 + 1] = b;
    ((bf16x8*)outb)[i] = v;
}

// ---------------------------------------------------------------------------
// transpose+permute: sru_w (1024,8192) -> wT' (8192,1024) with row n'=h*4+j
__global__ __launch_bounds__(256) void k_transpose(const int* __restrict__ flag, const void* __restrict__ in,
                                                   bf16* __restrict__ out, int R, int C) {
    __shared__ __align__(16) bf16 t[64][72];
    int tid = threadIdx.x;
    int c0 = blockIdx.x * 64, r0 = blockIdx.y * 64;
#pragma unroll
    for (int i = 0; i < 2; i++) {
        int idx = tid + i * 256;
        int r = idx >> 3, ch = idx & 7;
        size_t base = (size_t)(r0 + r) * C + c0 + ch * 8;
        bf16x8 v;
        if (*flag) {
            v = *(const bf16x8*)((const bf16*)in + base);
        } else {
            const float* f = (const float*)in + base;
            f32x4 x = *(const f32x4*)f, y = *(const f32x4*)(f + 4);
#pragma unroll
            for (int j = 0; j < 4; j++) { v[j] = (bf16)x[j]; v[4 + j] = (bf16)y[j]; }
        }
        *(bf16x8*)&t[r][ch * 8] = v;
    }
    __syncthreads();
    int nbase = c0 & 2047, joff = c0 >> 11;
#pragma unroll
    for (int i = 0; i < 2; i++) {
        int idx = tid + i * 256;
        int cr = idx >> 3, ch = idx & 7;
        bf16x8 v;
#pragma unroll
        for (int j = 0; j < 8; j++) v[j] = t[ch * 8 + j][cr];
        int np = (nbase + cr) * 4 + joff;
        *(bf16x8*)(out + (size_t)np * R + r0 + ch * 8) = v;
    }
}

// ---------------------------------------------------------------------------
// V pre-transpose: in rows m=s*4+b, 64 cols -> Vt[b][n][s] ([4][1024][1024])
__global__ __launch_bounds__(256) void k_vtr(const bf16* __restrict__ in, int ldv, bf16* __restrict__ out) {
    int nt = blockIdx.x, st = blockIdx.y, b = blockIdx.z;
    __shared__ __align__(16) bf16 t[64][72];
    int tid = threadIdx.x;
#pragma unroll
    for (int i = 0; i < 2; i++) {
        int idx = tid + i * 256;
        int r = idx >> 3, ch = idx & 7;
        bf16x8 v = *(const bf16x8*)(in + (size_t)((st * 64 + r) * 4 + b) * ldv + nt * 64 + ch * 8);
        *(bf16x8*)&t[r][ch * 8] = v;
    }
    __syncthreads();
#pragma unroll
    for (int i = 0; i < 2; i++) {
        int idx = tid + i * 256;
        int dr = idx >> 3, ch = idx & 7;
        bf16x8 v;
#pragma unroll
        for (int j = 0; j < 8; j++) v[j] = t[ch * 8 + j][dr];
        *(bf16x8*)(out + (size_t)(b * 1024 + nt * 64 + dr) * 1024 + st * 64 + ch * 8) = v;
    }
}

// ---------------------------------------------------------------------------
// GEMM (bf16 A): C[M,N] = A @ W^T (+bias)(*scale). BMx128 tile, BK=64.
// USCAT: scatter into U2a[ch][step][{xc,fp}] (via Cb) and U2b[ch][step][{rp,xh}]
// (via Cf reinterpreted) for the segmented SRU scan. ch=(row&3)*2048+(col>>2),
// step=row>>2, gate=col&3.
__device__ __forceinline__ int swzB(int r, int byteInRow) {
    return r * 128 + (byteInRow ^ ((r & 7) << 4));
}

template <int BM, bool USCAT>
__global__ __launch_bounds__(256) void k_gemm(
    const bf16* __restrict__ A, int lda,
    const bf16* __restrict__ W, int ldw,
    const bf16* __restrict__ bias,
    float* __restrict__ Cf, bf16* __restrict__ Cb, int ldc,
    int K, int scale_end, float scale) {
    constexpr int MI = BM / 32;
    __shared__ __align__(16) char Asm[BM * 128];
    __shared__ __align__(16) char Bsm[128 * 128];
    int tid = threadIdx.x, w = tid >> 6, l = tid & 63, lg = l >> 4, lm = l & 15;
    int wm = w >> 1, wn = w & 1;
    int m0 = blockIdx.y * BM, n0 = blockIdx.x * 128;

    f32x4 acc[MI][4] = {};

    for (int k0 = 0; k0 < K; k0 += 64) {
#pragma unroll
        for (int i = 0; i < BM / 32; i++) {
            int r = i * 32 + w * 8 + (l >> 3);
            int gs = (l & 7) ^ (r & 7);
            gl_lds16(A + (size_t)(m0 + r) * lda + k0 + gs * 8,
                     Asm + (i * 32 + w * 8) * 128);
        }
#pragma unroll
        for (int i = 0; i < 4; i++) {
            int r = i * 32 + w * 8 + (l >> 3);
            int gs = (l & 7) ^ (r & 7);
            gl_lds16(W + (size_t)(n0 + r) * ldw + k0 + gs * 8,
                     Bsm + (i * 32 + w * 8) * 128);
        }
        __syncthreads();
#pragma unroll
        for (int kh = 0; kh < 2; kh++) {
            bf16x8 af[MI], bfr[4];
#pragma unroll
            for (int i = 0; i < MI; i++)
                af[i] = *(const bf16x8*)(Asm + swzB(wm * (BM / 2) + i * 16 + lm, kh * 64 + lg * 16));
#pragma unroll
            for (int j = 0; j < 4; j++)
                bfr[j] = *(const bf16x8*)(Bsm + swzB(wn * 64 + j * 16 + lm, kh * 64 + lg * 16));
#pragma unroll
            for (int i = 0; i < MI; i++)
#pragma unroll
                for (int j = 0; j < 4; j++)
                    acc[i][j] = MFMA16(af[i], bfr[j], acc[i][j]);
        }
        __syncthreads();
    }
#pragma unroll
    for (int j = 0; j < 4; j++) {
        int col = n0 + wn * 64 + j * 16 + lm;
        float bv = bias ? (float)bias[col] : 0.f;
        float sc = (col < scale_end) ? scale : 1.f;
#pragma unroll
        for (int i = 0; i < MI; i++) {
            int row = m0 + wm * (BM / 2) + i * 16 + lg * 4;
#pragma unroll
            for (int r = 0; r < 4; r++) {
                float v = (acc[i][j][r] + bv) * sc;
                if constexpr (USCAT) {
                    int rw = row + r;
                    int ch = (rw & 3) * 2048 + (col >> 2);
                    int gate = col & 3;
                    bf16* dst = (gate < 2) ? Cb : (bf16*)Cf;  // U2a / U2b
                    dst[(size_t)ch * 2048 + (size_t)(rw >> 2) * 2 + (gate & 1)] = (bf16)v;
                } else {
                    size_t idx = (size_t)(row + r) * ldc + col;
                    if (Cf) Cf[idx] = v;
                    if (Cb) Cb[idx] = (bf16)v;
                }
            }
        }
    }
}

// ---------------------------------------------------------------------------
// Flash attention, QBLK=128, V pre-transposed, defer-max, lane-partial lrun.
__device__ __forceinline__ int swz2(int row, int byteInRow) {
    return row * 128 + (byteInRow ^ ((row & 7) << 4));
}
__device__ __forceinline__ int swzP(int row, int byteInRow) {
    return row * 128 + (byteInRow ^ ((row & 3) << 4) ^ (((row >> 2) & 1) << 6));
}

__global__ __launch_bounds__(256) void k_attn(
    const bf16* __restrict__ Qp, const bf16* __restrict__ Kp, const bf16* __restrict__ Vt,
    int ldq, int ldk, bf16* __restrict__ Op) {
    int h = blockIdx.x & 15, b = blockIdx.x >> 4, qblk = blockIdx.y;
    int tid = threadIdx.x, w = tid >> 6, l = tid & 63, lg = l >> 4, lm = l & 15;
    int r0 = tid >> 3, ch = tid & 7;

    __shared__ __align__(16) char Ksm[64 * 128];
    __shared__ __align__(16) char Vsm[64 * 128];
    __shared__ __align__(16) char Psm[4][32 * 128];

    bf16x8 qf[2][2];
#pragma unroll
    for (int u = 0; u < 2; u++) {
        int qrow = qblk * 128 + w * 32 + u * 16 + lm;
#pragma unroll
        for (int kk = 0; kk < 2; kk++)
            qf[u][kk] = *(const bf16x8*)(Qp + (size_t)(qrow * 4 + b) * ldq + h * 64 + kk * 32 + lg * 8);
    }

    const bf16* vbase = Vt + (size_t)(b * 1024 + h * 64) * 1024;

    bf16x8 kreg[2], vreg[2];
#pragma unroll
    for (int p = 0; p < 2; p++) {
        int r = r0 + p * 32;
        kreg[p] = *(const bf16x8*)(Kp + (size_t)(r * 4 + b) * ldk + h * 64 + ch * 8);
        vreg[p] = *(const bf16x8*)(vbase + (size_t)r * 1024 + ch * 8);
    }

    f32x4 oa[2][4] = {};
    float mrun[2][4], lrun[2][4];
#pragma unroll
    for (int u = 0; u < 2; u++)
#pragma unroll
        for (int r = 0; r < 4; r++) { mrun[u][r] = -1e30f; lrun[u][r] = 0.f; }

    for (int kt = 0; kt < 16; kt++) {
        __syncthreads();
#pragma unroll
        for (int p = 0; p < 2; p++) {
            int r = r0 + p * 32;
            *(bf16x8*)(Ksm + swz2(r, ch * 16)) = kreg[p];
            *(bf16x8*)(Vsm + swz2(r, ch * 16)) = vreg[p];
        }
        if (kt < 15) {
#pragma unroll
            for (int p = 0; p < 2; p++) {
                int r = (kt + 1) * 64 + r0 + p * 32;
                kreg[p] = *(const bf16x8*)(Kp + (size_t)(r * 4 + b) * ldk + h * 64 + ch * 8);
                vreg[p] = *(const bf16x8*)(vbase + (size_t)(r0 + p * 32) * 1024 + (kt + 1) * 64 + ch * 8);
            }
        }
        __syncthreads();

        f32x4 sc[2][4] = {};
#pragma unroll
        for (int kk = 0; kk < 2; kk++)
#pragma unroll
            for (int jt = 0; jt < 4; jt++) {
                bf16x8 bk = *(const bf16x8*)(Ksm + swz2(jt * 16 + lm, kk * 64 + lg * 16));
#pragma unroll
                for (int u = 0; u < 2; u++)
                    sc[u][jt] = MFMA16(qf[u][kk], bk, sc[u][jt]);
            }

        float m_[2][4];
#pragma unroll
        for (int u = 0; u < 2; u++)
#pragma unroll
            for (int r = 0; r < 4; r++) {
                float m = fmaxf(fmaxf(sc[u][0][r], sc[u][1][r]), fmaxf(sc[u][2][r], sc[u][3][r]));
#pragma unroll
                for (int d = 1; d < 16; d <<= 1) m = fmaxf(m, __shfl_xor(m, d));
                m_[u][r] = m;
            }
        bool grow = false;
#pragma unroll
        for (int u = 0; u < 2; u++)
#pragma unroll
            for (int r = 0; r < 4; r++) grow = grow || (m_[u][r] > mrun[u][r] + 8.f);
        if (__any(grow)) {
#pragma unroll
            for (int u = 0; u < 2; u++)
#pragma unroll
                for (int r = 0; r < 4; r++) {
                    float mn = fmaxf(mrun[u][r], m_[u][r]);
                    float al = __expf(mrun[u][r] - mn);
                    mrun[u][r] = mn;
                    lrun[u][r] *= al;
#pragma unroll
                    for (int ot = 0; ot < 4; ot++) oa[u][ot][r] *= al;
                }
        }
#pragma unroll
        for (int u = 0; u < 2; u++)
#pragma unroll
            for (int jt = 0; jt < 4; jt++)
#pragma unroll
                for (int r = 0; r < 4; r++) {
                    float p = __expf(sc[u][jt][r] - mrun[u][r]);
                    sc[u][jt][r] = p;
                    lrun[u][r] += p;
                }
#pragma unroll
        for (int u = 0; u < 2; u++)
#pragma unroll
            for (int jt = 0; jt < 4; jt++)
#pragma unroll
                for (int r = 0; r < 4; r++)
                    *(bf16*)(Psm[w] + swzP(u * 16 + lg * 4 + r, (jt * 16 + lm) * 2)) = (bf16)sc[u][jt][r];
        asm volatile("s_waitcnt lgkmcnt(0)" ::: "memory");
        __builtin_amdgcn_sched_barrier(0);
#pragma unroll
        for (int kk = 0; kk < 2; kk++) {
            bf16x8 pa[2];
#pragma unroll
            for (int u = 0; u < 2; u++)
                pa[u] = *(const bf16x8*)(Psm[w] + swzP(u * 16 + lm, kk * 64 + lg * 16));
#pragma unroll
            for (int ot = 0; ot < 4; ot++) {
                bf16x8 bv = *(const bf16x8*)(Vsm + swz2(ot * 16 + lm, kk * 64 + lg * 16));
#pragma unroll
                for (int u = 0; u < 2; u++)
                    oa[u][ot] = MFMA16(pa[u], bv, oa[u][ot]);
            }
        }
    }
#pragma unroll
    for (int u = 0; u < 2; u++)
#pragma unroll
        for (int r = 0; r < 4; r++) {
#pragma unroll
            for (int d = 1; d < 16; d <<= 1) lrun[u][r] += __shfl_xor(lrun[u][r], d);
            float inv = 1.f / lrun[u][r];
            int srow = qblk * 128 + w * 32 + u * 16 + lg * 4 + r;
#pragma unroll
            for (int ot = 0; ot < 4; ot++) {
                int col = h * 64 + ot * 16 + lm;
                Op[(size_t)(srow * 4 + b) * 1024 + col] = (bf16)(oa[u][ot][r] * inv);
            }
        }
}

// ---------------------------------------------------------------------------
// residual-add + LayerNorm over D=1024 (f32 math). X dtype templated.
template <typename XT>
__global__ __launch_bounds__(256) void k_addln(
    const XT* __restrict__ X, const float* __restrict__ Yd,
    const bf16* __restrict__ g, const bf16* __restrict__ bb,
    float* __restrict__ outF, bf16* __restrict__ outB) {
    int row = blockIdx.x * 4 + (threadIdx.x >> 6);
    int l = threadIdx.x & 63;
    const XT* xr = X + (size_t)row * 1024;
    const float* yr = Yd + (size_t)row * 1024;
    float v[16];
    float s = 0.f, s2 = 0.f;
#pragma unroll
    for (int q = 0; q < 4; q++) {
        float xa[4];
        if constexpr (sizeof(XT) == 4) {
            f32x4 a = *(const f32x4*)(xr + l * 4 + q * 256);
#pragma unroll
            for (int j = 0; j < 4; j++) xa[j] = a[j];
        } else {
            bf16x4 a = *(const bf16x4*)(xr + l * 4 + q * 256);
#pragma unroll
            for (int j = 0; j < 4; j++) xa[j] = (float)a[j];
        }
        f32x4 c = *(const f32x4*)(yr + l * 4 + q * 256);
#pragma unroll
        for (int j = 0; j < 4; j++) {
            float t = xa[j] + c[j];
            v[q * 4 + j] = t;
            s += t;
            s2 += t * t;
        }
    }
#pragma unroll
    for (int d = 1; d < 64; d <<= 1) { s += __shfl_xor(s, d); s2 += __shfl_xor(s2, d); }
    float mu = s * (1.f / 1024.f);
    float var = s2 * (1.f / 1024.f) - mu * mu;
    float rstd = rsqrtf(var + 1e-5f);
#pragma unroll
    for (int q = 0; q < 4; q++)
#pragma unroll
        for (int j = 0; j < 4; j++) {
            int col = l * 4 + q * 256 + j;
            float y = (v[q * 4 + j] - mu) * rstd * (float)g[col] + (float)bb[col];
            if (outF) outF[(size_t)row * 1024 + col] = y;
            if (outB) outB[(size_t)row * 1024 + col] = (bf16)y;
        }
}

// ---------------------------------------------------------------------------
// SRU segmented scan. c_s = f_s*c_{s-1} + (1-f_s)*xc_s is LINEAR in c, so each
// 128-step segment is an affine map c_out = A*c_in + B. 8 segments -> 65536
// threads (1024 waves, 4/CU) instead of 128 waves: MLP-bound -> BW-bound.
// Phase 1: per (ch,seg) compute A = prod(f), B = scan-from-0. Reads U2a only.
__global__ __launch_bounds__(64) void k_sru_ab(
    const bf16* __restrict__ U2a, const bf16* __restrict__ v2, const bf16* __restrict__ b2,
    float* __restrict__ AB) {
    int ch = blockIdx.x * 64 + threadIdx.x;  // 0..8191
    int g = blockIdx.y;                      // 0..7
    int hh = ch & 2047;
    float vf = (float)v2[hh], bfv = (float)b2[hh];
    const bf16x8* u = (const bf16x8*)(U2a + (size_t)ch * 2048 + g * 256);  // 32 chunks x 4 steps
    float A = 1.f, c = 0.f;
    bf16x8 q[4];
#pragma unroll
    for (int i = 0; i < 4; i++) q[i] = u[i];
    for (int it = 0; it < 8; it++) {
#pragma unroll
        for (int j = 0; j < 4; j++) {
            int cidx = it * 4 + j;
            bf16x8 v = q[j];
            if (cidx + 4 < 32) q[j] = u[cidx + 4];
#pragma unroll
            for (int t = 0; t < 4; t++) {
                float xc = (float)v[t * 2], fp = (float)v[t * 2 + 1];
                float f = 1.f / (1.f + __expf(-(fp + vf * c + bfv)));
                A *= f;
                c = f * c + (1.f - f) * xc;
            }
        }
    }
    AB[(size_t)(g * 8192 + ch) * 2] = A;
    AB[(size_t)(g * 8192 + ch) * 2 + 1] = c;
}

// Phase 2: fold upstream (A,B) for c_in (g is wave-uniform), re-scan segment
// computing h. Reads U2a+U2b, writes h rows m=s*4+b.
__global__ __launch_bounds__(64) void k_sru_h(
    const bf16* __restrict__ U2a, const bf16* __restrict__ U2b,
    const bf16* __restrict__ v2, const bf16* __restrict__ b2,
    const float* __restrict__ AB, bf16* __restrict__ Hb) {
    int ch = blockIdx.x * 64 + threadIdx.x;
    int g = blockIdx.y;
    int b = ch >> 11, hh = ch & 2047;
    float vf = (float)v2[hh], vr = (float)v2[2048 + hh];
    float bfv = (float)b2[hh], brv = (float)b2[2048 + hh];
    float c = 0.f;
    for (int s = 0; s < g; s++) {  // wave-uniform bound
        float As = AB[(size_t)(s * 8192 + ch) * 2];
        float Bs = AB[(size_t)(s * 8192 + ch) * 2 + 1];
        c = As * c + Bs;
    }
    const bf16x8* ua = (const bf16x8*)(U2a + (size_t)ch * 2048 + g * 256);
    const bf16x8* ub = (const bf16x8*)(U2b + (size_t)ch * 2048 + g * 256);
    bf16* ho = Hb + ((size_t)(g * 128) * 4 + b) * 2048 + hh;  // +8192 per local step
    bf16x8 qa[4], qb[4];
#pragma unroll
    for (int i = 0; i < 4; i++) { qa[i] = ua[i]; qb[i] = ub[i]; }
    for (int it = 0; it < 8; it++) {
#pragma unroll
        for (int j = 0; j < 4; j++) {
            int cidx = it * 4 + j;
            bf16x8 va = qa[j], vb = qb[j];
            if (cidx + 4 < 32) { qa[j] = ua[cidx + 4]; qb[j] = ub[cidx + 4]; }
#pragma unroll
            for (int t = 0; t < 4; t++) {
                float xc = (float)va[t * 2], fp = (float)va[t * 2 + 1];
                float rp = (float)vb[t * 2], xh = (float)vb[t * 2 + 1];
                float f = 1.f / (1.f + __expf(-(fp + vf * c + bfv)));
                float r = 1.f / (1.f + __expf(-(rp + vr * c + brv)));
                c = f * c + (1.f - f) * xc;
                float hv = r * c + (1.f - r) * xh;
                ho[(size_t)(cidx * 4 + t) * 8192] = (bf16)hv;
            }
        }
    }
}

// ---------------------------------------------------------------------------
extern "C" void kernel_launch(void* const* d_in, const int* in_sizes, int n_in,
                              void* d_out, int out_size, void* d_ws, size_t ws_size,
                              hipStream_t stream) {
    const size_t MB = 1u << 20;
    char* ws = (char*)d_ws;

    bf16* memB    = (bf16*)(ws + 0);
    bf16* sawinB  = (bf16*)(ws + 8 * MB);
    bf16* sawoutB = (bf16*)(ws + 14 * MB);
    bf16* cawinB  = (bf16*)(ws + 16 * MB);
    bf16* cawoutB = (bf16*)(ws + 22 * MB);
    bf16* lin2wB  = (bf16*)(ws + 24 * MB);
    char* S0 = ws + 28 * MB;
    bf16* sabinB  = (bf16*)(S0 + 0 * 8192);
    bf16* cabinB  = (bf16*)(S0 + 1 * 8192);
    bf16* saboutB = (bf16*)(S0 + 2 * 8192);
    bf16* caboutB = (bf16*)(S0 + 3 * 8192);
    bf16* lin2bB  = (bf16*)(S0 + 4 * 8192);
    bf16* sruvB   = (bf16*)(S0 + 5 * 8192);
    bf16* srubB   = (bf16*)(S0 + 6 * 8192);
    bf16* ln1gB   = (bf16*)(S0 + 7 * 8192);
    bf16* ln1bB   = (bf16*)(S0 + 8 * 8192);
    bf16* ln2gB   = (bf16*)(S0 + 9 * 8192);
    bf16* ln2bB   = (bf16*)(S0 + 10 * 8192);
    bf16* ln3gB   = (bf16*)(S0 + 11 * 8192);
    bf16* ln3bB   = (bf16*)(S0 + 12 * 8192);
    int*  flag    = (int*)(S0 + 13 * 8192);
    float* AB     = (float*)(S0 + 128 * 1024);  // 8 x 8192 x 2 f32 = 512 KB (region is 1 MB)

    char* P = ws + 29 * MB;
    float* t0   = (float*)(P + 0);
    bf16*  qkv  = (bf16*)(P + 16 * MB);
    bf16*  qca  = qkv;
    bf16*  kvca = (bf16*)(P + 24 * MB);
    bf16*  obuf = (bf16*)(P + 40 * MB);
    bf16*  Vt   = (bf16*)(P + 56 * MB);
    bf16*  t0b  = (bf16*)(P + 64 * MB);
    float* tmp  = (float*)(P + 64 * MB);
    bf16*  t1   = (bf16*)(P + 80 * MB);
    bf16*  t2   = (bf16*)(ws + 0);        // overlays dead memB
    bf16*  wT   = (bf16*)(P + 0);         // overlays dead t0
    bf16*  U2a  = (bf16*)(P + 16 * MB);   // 8192ch x 1024step x {xc,fp} = 32MB
    bf16*  U2b  = (bf16*)(P + 48 * MB);   // 8192ch x 1024step x {rp,xh} = 32MB
    bf16*  hb   = (bf16*)(P + 80 * MB);   // overlays dead t1
    float* tmp2 = (float*)(P + 16 * MB);  // U2a dead after scan

    k_detect<<<1, 256, 0, stream>>>(d_in[0], flag);
    BigSegs bg;
    {
        const void* bsrc[6] = {d_in[1], d_in[2], d_in[4], d_in[6], d_in[8], d_in[13]};
        bf16* bdst[6] = {memB, sawinB, sawoutB, cawinB, cawoutB, lin2wB};
        const int cum[7] = {0, 2048, 3584, 4096, 5632, 6144, 7168};
        for (int i = 0; i < 6; i++) { bg.src[i] = bsrc[i]; bg.dst[i] = bdst[i]; }
        for (int i = 0; i < 7; i++) bg.cum[i] = cum[i];
    }
    k_norm_big<<<7168, 256, 0, stream>>>(flag, bg);
    SmallSegs sg;
    const int srcIdx[13] = {3, 7, 5, 9, 14, 11, 12, 15, 16, 17, 18, 19, 20};
    bf16* dsts[13] = {sabinB, cabinB, saboutB, caboutB, lin2bB, sruvB, srubB,
                      ln1gB, ln1bB, ln2gB, ln2bB, ln3gB, ln3bB};
    const int n8s[13] = {384, 384, 128, 128, 128, 512, 512, 128, 128, 128, 128, 128, 128};
    for (int i = 0; i < 13; i++) { sg.src[i] = d_in[srcIdx[i]]; sg.dst[i] = dsts[i]; sg.n8[i] = n8s[i]; }
    k_norm_multi<<<13, 256, 0, stream>>>(flag, sg);

    k_cvt<<<2048, 256, 0, stream>>>(flag, d_in[0], t0, t0b);

    // ---- self attention ----
    k_gemm<128, false><<<dim3(24, 32), 256, 0, stream>>>(t0b, 1024, sawinB, 1024, sabinB,
                                                         nullptr, qkv, 3072, 1024, 1024, 0.125f);
    k_vtr<<<dim3(16, 16, 4), 256, 0, stream>>>(qkv + 2048, 3072, Vt);
    k_attn<<<dim3(64, 8), 256, 0, stream>>>(qkv, qkv + 1024, Vt, 3072, 3072, obuf);
    k_gemm<64, false><<<dim3(8, 64), 256, 0, stream>>>(obuf, 1024, sawoutB, 1024, saboutB,
                                                       tmp, nullptr, 1024, 1024, 0, 1.f);
    k_addln<float><<<1024, 256, 0, stream>>>(t0, tmp, ln1gB, ln1bB, nullptr, t1);

    // ---- cross attention ----
    k_gemm<64, false><<<dim3(8, 64), 256, 0, stream>>>(t1, 1024, cawinB, 1024, cabinB,
                                                       nullptr, qca, 1024, 1024, 1024, 0.125f);
    k_gemm<128, false><<<dim3(16, 32), 256, 0, stream>>>(memB, 1024, cawinB + (size_t)1024 * 1024, 1024,
                                                         cabinB + 1024, nullptr, kvca, 2048, 1024, 0, 1.f);
    k_vtr<<<dim3(16, 16, 4), 256, 0, stream>>>(kvca + 1024, 2048, Vt);
    k_attn<<<dim3(64, 8), 256, 0, stream>>>(qca, kvca, Vt, 1024, 2048, obuf);
    k_gemm<64, false><<<dim3(8, 64), 256, 0, stream>>>(obuf, 1024, cawoutB, 1024, caboutB,
                                                       tmp, nullptr, 1024, 1024, 0, 1.f);
    k_addln<bf16><<<1024, 256, 0, stream>>>(t1, tmp, ln2gB, ln2bB, nullptr, t2);

    // ---- SRU: GEMM scatters (U2a,U2b); segmented 2-phase scan ----
    k_transpose<<<dim3(128, 16), 256, 0, stream>>>(flag, d_in[10], wT, 1024, 8192);
    k_gemm<128, true><<<dim3(64, 32), 256, 0, stream>>>(t2, 1024, wT, 1024,
                                                        nullptr, (float*)U2b, U2a, 0, 1024, 0, 1.f);
    k_sru_ab<<<dim3(128, 8), 64, 0, stream>>>(U2a, sruvB, srubB, AB);
    k_sru_h<<<dim3(128, 8), 64, 0, stream>>>(U2a, U2b, sruvB, srubB, AB, hb);
    k_gemm<64, false><<<dim3(8, 64), 256, 0, stream>>>(hb, 2048, lin2wB, 2048, lin2bB,
                                                       tmp2, nullptr, 1024, 2048, 0, 1.f);
    k_addln<bf16><<<1024, 256, 0, stream>>>(t2, tmp2, ln3gB, ln3bB, (float*)d_out, nullptr);
}

// Round 13
// 470.943 us; speedup vs baseline: 2.1079x; 1.0769x over previous
//
#include <hip/hip_runtime.h>
#include <hip/hip_bf16.h>

typedef __bf16 bf16;
typedef bf16 bf16x8 __attribute__((ext_vector_type(8)));
typedef bf16 bf16x4 __attribute__((ext_vector_type(4)));
typedef float f32x4 __attribute__((ext_vector_type(4)));

#define MFMA16(a, b, c) __builtin_amdgcn_mfma_f32_16x16x32_bf16((a), (b), (c), 0, 0, 0)

__device__ __forceinline__ void gl_lds16(const void* g, void* l) {
    __builtin_amdgcn_global_load_lds((const __attribute__((address_space(1))) void*)g,
                                     (__attribute__((address_space(3))) void*)l, 16, 0, 0);
}

// ---------------------------------------------------------------------------
__global__ __launch_bounds__(256) void k_detect(const void* __restrict__ src, int* __restrict__ flag) {
    __shared__ int cnt;
    if (threadIdx.x == 0) cnt = 0;
    __syncthreads();
    const unsigned int* w = (const unsigned int*)src;
    int local = 0;
    for (int i = threadIdx.x; i < 4096; i += 256) {
        unsigned int e = (w[i] >> 7) & 0xFF;
        local += (e > 100 && e < 150) ? 1 : 0;
    }
    atomicAdd(&cnt, local);
    __syncthreads();
    if (threadIdx.x == 0) *flag = (cnt > 2048) ? 1 : 0;
}

struct BigSegs {
    const void* src[6];
    bf16* dst[6];
    int cum[7];
};
__global__ __launch_bounds__(256) void k_norm_big(const int* __restrict__ flag, BigSegs s) {
    int seg = 0;
#pragma unroll
    for (int t = 0; t < 5; t++) seg += (blockIdx.x >= s.cum[t + 1]) ? 1 : 0;
    int i = (blockIdx.x - s.cum[seg]) * 256 + threadIdx.x;
    const void* sp = s.src[seg];
    bf16* dp = s.dst[seg];
    if (*flag) {
        ((bf16x8*)dp)[i] = ((const bf16x8*)sp)[i];
    } else {
        const float* fs = (const float*)sp + (size_t)i * 8;
        bf16x8 o;
#pragma unroll
        for (int j = 0; j < 8; j++) o[j] = (bf16)fs[j];
        ((bf16x8*)dp)[i] = o;
    }
}

struct SmallSegs {
    const void* src[13];
    bf16* dst[13];
    int n8[13];
};
__global__ __launch_bounds__(256) void k_norm_multi(const int* __restrict__ flag, SmallSegs s) {
    int seg = blockIdx.x;
    const void* sp = s.src[seg];
    bf16* dp = s.dst[seg];
    int n = s.n8[seg];
    int f = *flag;
    for (int i = threadIdx.x; i < n; i += 256) {
        if (f) {
            ((bf16x8*)dp)[i] = ((const bf16x8*)sp)[i];
        } else {
            const float* fs = (const float*)sp + (size_t)i * 8;
            bf16x8 o;
#pragma unroll
            for (int j = 0; j < 8; j++) o[j] = (bf16)fs[j];
            ((bf16x8*)dp)[i] = o;
        }
    }
}

// tgt -> f32 residual t0 AND bf16 copy t0b
__global__ __launch_bounds__(256) void k_cvt(const int* __restrict__ flag, const void* __restrict__ in,
                                             float* __restrict__ out, bf16* __restrict__ outb) {
    size_t i = (size_t)blockIdx.x * 256 + threadIdx.x;
    f32x4 a, b;
    bf16x8 v;
    if (*flag) {
        v = ((const bf16x8*)in)[i];
#pragma unroll
        for (int j = 0; j < 4; j++) { a[j] = (float)v[j]; b[j] = (float)v[4 + j]; }
    } else {
        a = ((const f32x4*)in)[i * 2];
        b = ((const f32x4*)in)[i * 2 + 1];
#pragma unroll
        for (int j = 0; j < 4; j++) { v[j] = (bf16)a[j]; v[4 + j] = (bf16)b[j]; }
    }
    ((f32x4*)out)[i * 2] = a;
    ((f32x4*)out)[i * 2 + 1] = b;
    ((bf16x8*)outb)[i] = v;
}

// ---------------------------------------------------------------------------
// transpose+permute: sru_w (1024,8192) -> wT' (8192,1024) with row n'=h*4+j
__global__ __launch_bounds__(256) void k_transpose(const int* __restrict__ flag, const void* __restrict__ in,
                                                   bf16* __restrict__ out, int R, int C) {
    __shared__ __align__(16) bf16 t[64][72];
    int tid = threadIdx.x;
    int c0 = blockIdx.x * 64, r0 = blockIdx.y * 64;
#pragma unroll
    for (int i = 0; i < 2; i++) {
        int idx = tid + i * 256;
        int r = idx >> 3, ch = idx & 7;
        size_t base = (size_t)(r0 + r) * C + c0 + ch * 8;
        bf16x8 v;
        if (*flag) {
            v = *(const bf16x8*)((const bf16*)in + base);
        } else {
            const float* f = (const float*)in + base;
            f32x4 x = *(const f32x4*)f, y = *(const f32x4*)(f + 4);
#pragma unroll
            for (int j = 0; j < 4; j++) { v[j] = (bf16)x[j]; v[4 + j] = (bf16)y[j]; }
        }
        *(bf16x8*)&t[r][ch * 8] = v;
    }
    __syncthreads();
    int nbase = c0 & 2047, joff = c0 >> 11;
#pragma unroll
    for (int i = 0; i < 2; i++) {
        int idx = tid + i * 256;
        int cr = idx >> 3, ch = idx & 7;
        bf16x8 v;
#pragma unroll
        for (int j = 0; j < 8; j++) v[j] = t[ch * 8 + j][cr];
        int np = (nbase + cr) * 4 + joff;
        *(bf16x8*)(out + (size_t)np * R + r0 + ch * 8) = v;
    }
}

// ---------------------------------------------------------------------------
// V pre-transpose: in rows m=s*4+b, 64 cols -> Vt[b][n][s] ([4][1024][1024])
__global__ __launch_bounds__(256) void k_vtr(const bf16* __restrict__ in, int ldv, bf16* __restrict__ out) {
    int nt = blockIdx.x, st = blockIdx.y, b = blockIdx.z;
    __shared__ __align__(16) bf16 t[64][72];
    int tid = threadIdx.x;
#pragma unroll
    for (int i = 0; i < 2; i++) {
        int idx = tid + i * 256;
        int r = idx >> 3, ch = idx & 7;
        bf16x8 v = *(const bf16x8*)(in + (size_t)((st * 64 + r) * 4 + b) * ldv + nt * 64 + ch * 8);
        *(bf16x8*)&t[r][ch * 8] = v;
    }
    __syncthreads();
#pragma unroll
    for (int i = 0; i < 2; i++) {
        int idx = tid + i * 256;
        int dr = idx >> 3, ch = idx & 7;
        bf16x8 v;
#pragma unroll
        for (int j = 0; j < 8; j++) v[j] = t[ch * 8 + j][dr];
        *(bf16x8*)(out + (size_t)(b * 1024 + nt * 64 + dr) * 1024 + st * 64 + ch * 8) = v;
    }
}

// ---------------------------------------------------------------------------
// GEMM (bf16 A): C[M,N] = A @ W^T (+bias)(*scale). BMx128 tile, BK=64.
// USCAT epilogue: stage tile in (dead) Asm/Bsm LDS in U2a/U2b split layout,
// then 256 threads each write one 128B-contiguous run (no partial-line RMW).
__device__ __forceinline__ int swzB(int r, int byteInRow) {
    return r * 128 + (byteInRow ^ ((r & 7) << 4));
}

template <int BM, bool USCAT>
__global__ __launch_bounds__(256) void k_gemm(
    const bf16* __restrict__ A, int lda,
    const bf16* __restrict__ W, int ldw,
    const bf16* __restrict__ bias,
    float* __restrict__ Cf, bf16* __restrict__ Cb, int ldc,
    int K, int scale_end, float scale) {
    constexpr int MI = BM / 32;
    __shared__ __align__(16) char Asm[BM * 128];
    __shared__ __align__(16) char Bsm[128 * 128];
    int tid = threadIdx.x, w = tid >> 6, l = tid & 63, lg = l >> 4, lm = l & 15;
    int wm = w >> 1, wn = w & 1;
    int m0 = blockIdx.y * BM, n0 = blockIdx.x * 128;

    f32x4 acc[MI][4] = {};

    for (int k0 = 0; k0 < K; k0 += 64) {
#pragma unroll
        for (int i = 0; i < BM / 32; i++) {
            int r = i * 32 + w * 8 + (l >> 3);
            int gs = (l & 7) ^ (r & 7);
            gl_lds16(A + (size_t)(m0 + r) * lda + k0 + gs * 8,
                     Asm + (i * 32 + w * 8) * 128);
        }
#pragma unroll
        for (int i = 0; i < 4; i++) {
            int r = i * 32 + w * 8 + (l >> 3);
            int gs = (l & 7) ^ (r & 7);
            gl_lds16(W + (size_t)(n0 + r) * ldw + k0 + gs * 8,
                     Bsm + (i * 32 + w * 8) * 128);
        }
        __syncthreads();
#pragma unroll
        for (int kh = 0; kh < 2; kh++) {
            bf16x8 af[MI], bfr[4];
#pragma unroll
            for (int i = 0; i < MI; i++)
                af[i] = *(const bf16x8*)(Asm + swzB(wm * (BM / 2) + i * 16 + lm, kh * 64 + lg * 16));
#pragma unroll
            for (int j = 0; j < 4; j++)
                bfr[j] = *(const bf16x8*)(Bsm + swzB(wn * 64 + j * 16 + lm, kh * 64 + lg * 16));
#pragma unroll
            for (int i = 0; i < MI; i++)
#pragma unroll
                for (int j = 0; j < 4; j++)
                    acc[i][j] = MFMA16(af[i], bfr[j], acc[i][j]);
        }
        __syncthreads();
    }
    if constexpr (USCAT) {
        // k-loop ended with a barrier -> Asm/Bsm dead; reuse as epilogue staging.
        // Layout: ls{A,B}[b:4][chl:32] runs of 64 bf16 (32 steps x 2 gates),
        // run-internal byte offset XOR-swizzled by (chl&7)<<4.
        bf16* lsA = (bf16*)Asm;  // 16 KB (BM=128)
        bf16* lsB = (bf16*)Bsm;  // 16 KB
#pragma unroll
        for (int j = 0; j < 4; j++) {
            int cl = wn * 16 + j * 4 + (lm >> 2);  // channel-local 0..31
            int g = lm & 3;
            bf16* ls = (g < 2) ? lsA : lsB;
            int g01 = g & 1;
#pragma unroll
            for (int i = 0; i < MI; i++) {
                int slb = wm * 16 + i * 4 + lg;    // step-local 0..31
                int boff = (slb * 2 + g01) * 2;    // byte in run
                int swz = boff ^ ((cl & 7) << 4);
#pragma unroll
                for (int r = 0; r < 4; r++) {      // b = r
                    float v = acc[i][j][r];
                    *(bf16*)((char*)ls + (r * 32 + cl) * 128 + swz) = (bf16)v;
                }
            }
        }
        __syncthreads();
        // thread t: buffer t>>7, b (t>>5)&3, chl t&31 -> one 128B run.
        int buf = tid >> 7, bb = (tid >> 5) & 3, cl = tid & 31;
        const char* ls = (buf == 0) ? (const char*)lsA : (const char*)lsB;
        bf16* dstbase = (buf == 0) ? Cb : (bf16*)Cf;  // U2a / U2b
        int ch = bb * 2048 + (n0 >> 2) + cl;
        size_t gbase = (size_t)ch * 2048 + (size_t)(m0 >> 2) * 2;
        const char* src = ls + (bb * 32 + cl) * 128;
#pragma unroll
        for (int q = 0; q < 8; q++) {
            int pq = (q * 16) ^ ((cl & 7) << 4);  // de-swizzle
            *(bf16x8*)(dstbase + gbase + q * 8) = *(const bf16x8*)(src + pq);
        }
    } else {
#pragma unroll
        for (int j = 0; j < 4; j++) {
            int col = n0 + wn * 64 + j * 16 + lm;
            float bv = bias ? (float)bias[col] : 0.f;
            float sc = (col < scale_end) ? scale : 1.f;
#pragma unroll
            for (int i = 0; i < MI; i++) {
                int row = m0 + wm * (BM / 2) + i * 16 + lg * 4;
#pragma unroll
                for (int r = 0; r < 4; r++) {
                    float v = (acc[i][j][r] + bv) * sc;
                    size_t idx = (size_t)(row + r) * ldc + col;
                    if (Cf) Cf[idx] = v;
                    if (Cb) Cb[idx] = (bf16)v;
                }
            }
        }
    }
}

// ---------------------------------------------------------------------------
// Flash attention, QBLK=128, V pre-transposed, defer-max, lane-partial lrun.
__device__ __forceinline__ int swz2(int row, int byteInRow) {
    return row * 128 + (byteInRow ^ ((row & 7) << 4));
}
__device__ __forceinline__ int swzP(int row, int byteInRow) {
    return row * 128 + (byteInRow ^ ((row & 3) << 4) ^ (((row >> 2) & 1) << 6));
}

__global__ __launch_bounds__(256) void k_attn(
    const bf16* __restrict__ Qp, const bf16* __restrict__ Kp, const bf16* __restrict__ Vt,
    int ldq, int ldk, bf16* __restrict__ Op) {
    int h = blockIdx.x & 15, b = blockIdx.x >> 4, qblk = blockIdx.y;
    int tid = threadIdx.x, w = tid >> 6, l = tid & 63, lg = l >> 4, lm = l & 15;
    int r0 = tid >> 3, ch = tid & 7;

    __shared__ __align__(16) char Ksm[64 * 128];
    __shared__ __align__(16) char Vsm[64 * 128];
    __shared__ __align__(16) char Psm[4][32 * 128];

    bf16x8 qf[2][2];
#pragma unroll
    for (int u = 0; u < 2; u++) {
        int qrow = qblk * 128 + w * 32 + u * 16 + lm;
#pragma unroll
        for (int kk = 0; kk < 2; kk++)
            qf[u][kk] = *(const bf16x8*)(Qp + (size_t)(qrow * 4 + b) * ldq + h * 64 + kk * 32 + lg * 8);
    }

    const bf16* vbase = Vt + (size_t)(b * 1024 + h * 64) * 1024;

    bf16x8 kreg[2], vreg[2];
#pragma unroll
    for (int p = 0; p < 2; p++) {
        int r = r0 + p * 32;
        kreg[p] = *(const bf16x8*)(Kp + (size_t)(r * 4 + b) * ldk + h * 64 + ch * 8);
        vreg[p] = *(const bf16x8*)(vbase + (size_t)r * 1024 + ch * 8);
    }

    f32x4 oa[2][4] = {};
    float mrun[2][4], lrun[2][4];
#pragma unroll
    for (int u = 0; u < 2; u++)
#pragma unroll
        for (int r = 0; r < 4; r++) { mrun[u][r] = -1e30f; lrun[u][r] = 0.f; }

    for (int kt = 0; kt < 16; kt++) {
        __syncthreads();
#pragma unroll
        for (int p = 0; p < 2; p++) {
            int r = r0 + p * 32;
            *(bf16x8*)(Ksm + swz2(r, ch * 16)) = kreg[p];
            *(bf16x8*)(Vsm + swz2(r, ch * 16)) = vreg[p];
        }
        if (kt < 15) {
#pragma unroll
            for (int p = 0; p < 2; p++) {
                int r = (kt + 1) * 64 + r0 + p * 32;
                kreg[p] = *(const bf16x8*)(Kp + (size_t)(r * 4 + b) * ldk + h * 64 + ch * 8);
                vreg[p] = *(const bf16x8*)(vbase + (size_t)(r0 + p * 32) * 1024 + (kt + 1) * 64 + ch * 8);
            }
        }
        __syncthreads();

        f32x4 sc[2][4] = {};
#pragma unroll
        for (int kk = 0; kk < 2; kk++)
#pragma unroll
            for (int jt = 0; jt < 4; jt++) {
                bf16x8 bk = *(const bf16x8*)(Ksm + swz2(jt * 16 + lm, kk * 64 + lg * 16));
#pragma unroll
                for (int u = 0; u < 2; u++)
                    sc[u][jt] = MFMA16(qf[u][kk], bk, sc[u][jt]);
            }

        float m_[2][4];
#pragma unroll
        for (int u = 0; u < 2; u++)
#pragma unroll
            for (int r = 0; r < 4; r++) {
                float m = fmaxf(fmaxf(sc[u][0][r], sc[u][1][r]), fmaxf(sc[u][2][r], sc[u][3][r]));
#pragma unroll
                for (int d = 1; d < 16; d <<= 1) m = fmaxf(m, __shfl_xor(m, d));
                m_[u][r] = m;
            }
        bool grow = false;
#pragma unroll
        for (int u = 0; u < 2; u++)
#pragma unroll
            for (int r = 0; r < 4; r++) grow = grow || (m_[u][r] > mrun[u][r] + 8.f);
        if (__any(grow)) {
#pragma unroll
            for (int u = 0; u < 2; u++)
#pragma unroll
                for (int r = 0; r < 4; r++) {
                    float mn = fmaxf(mrun[u][r], m_[u][r]);
                    float al = __expf(mrun[u][r] - mn);
                    mrun[u][r] = mn;
                    lrun[u][r] *= al;
#pragma unroll
                    for (int ot = 0; ot < 4; ot++) oa[u][ot][r] *= al;
                }
        }
#pragma unroll
        for (int u = 0; u < 2; u++)
#pragma unroll
            for (int jt = 0; jt < 4; jt++)
#pragma unroll
                for (int r = 0; r < 4; r++) {
                    float p = __expf(sc[u][jt][r] - mrun[u][r]);
                    sc[u][jt][r] = p;
                    lrun[u][r] += p;
                }
#pragma unroll
        for (int u = 0; u < 2; u++)
#pragma unroll
            for (int jt = 0; jt < 4; jt++)
#pragma unroll
                for (int r = 0; r < 4; r++)
                    *(bf16*)(Psm[w] + swzP(u * 16 + lg * 4 + r, (jt * 16 + lm) * 2)) = (bf16)sc[u][jt][r];
        asm volatile("s_waitcnt lgkmcnt(0)" ::: "memory");
        __builtin_amdgcn_sched_barrier(0);
#pragma unroll
        for (int kk = 0; kk < 2; kk++) {
            bf16x8 pa[2];
#pragma unroll
            for (int u = 0; u < 2; u++)
                pa[u] = *(const bf16x8*)(Psm[w] + swzP(u * 16 + lm, kk * 64 + lg * 16));
#pragma unroll
            for (int ot = 0; ot < 4; ot++) {
                bf16x8 bv = *(const bf16x8*)(Vsm + swz2(ot * 16 + lm, kk * 64 + lg * 16));
#pragma unroll
                for (int u = 0; u < 2; u++)
                    oa[u][ot] = MFMA16(pa[u], bv, oa[u][ot]);
            }
        }
    }
#pragma unroll
    for (int u = 0; u < 2; u++)
#pragma unroll
        for (int r = 0; r < 4; r++) {
#pragma unroll
            for (int d = 1; d < 16; d <<= 1) lrun[u][r] += __shfl_xor(lrun[u][r], d);
            float inv = 1.f / lrun[u][r];
            int srow = qblk * 128 + w * 32 + u * 16 + lg * 4 + r;
#pragma unroll
            for (int ot = 0; ot < 4; ot++) {
                int col = h * 64 + ot * 16 + lm;
                Op[(size_t)(srow * 4 + b) * 1024 + col] = (bf16)(oa[u][ot][r] * inv);
            }
        }
}

// ---------------------------------------------------------------------------
// residual-add + LayerNorm over D=1024 (f32 math). X dtype templated.
template <typename XT>
__global__ __launch_bounds__(256) void k_addln(
    const XT* __restrict__ X, const float* __restrict__ Yd,
    const bf16* __restrict__ g, const bf16* __restrict__ bb,
    float* __restrict__ outF, bf16* __restrict__ outB) {
    int row = blockIdx.x * 4 + (threadIdx.x >> 6);
    int l = threadIdx.x & 63;
    const XT* xr = X + (size_t)row * 1024;
    const float* yr = Yd + (size_t)row * 1024;
    float v[16];
    float s = 0.f, s2 = 0.f;
#pragma unroll
    for (int q = 0; q < 4; q++) {
        float xa[4];
        if constexpr (sizeof(XT) == 4) {
            f32x4 a = *(const f32x4*)(xr + l * 4 + q * 256);
#pragma unroll
            for (int j = 0; j < 4; j++) xa[j] = a[j];
        } else {
            bf16x4 a = *(const bf16x4*)(xr + l * 4 + q * 256);
#pragma unroll
            for (int j = 0; j < 4; j++) xa[j] = (float)a[j];
        }
        f32x4 c = *(const f32x4*)(yr + l * 4 + q * 256);
#pragma unroll
        for (int j = 0; j < 4; j++) {
            float t = xa[j] + c[j];
            v[q * 4 + j] = t;
            s += t;
            s2 += t * t;
        }
    }
#pragma unroll
    for (int d = 1; d < 64; d <<= 1) { s += __shfl_xor(s, d); s2 += __shfl_xor(s2, d); }
    float mu = s * (1.f / 1024.f);
    float var = s2 * (1.f / 1024.f) - mu * mu;
    float rstd = rsqrtf(var + 1e-5f);
#pragma unroll
    for (int q = 0; q < 4; q++)
#pragma unroll
        for (int j = 0; j < 4; j++) {
            int col = l * 4 + q * 256 + j;
            float y = (v[q * 4 + j] - mu) * rstd * (float)g[col] + (float)bb[col];
            if (outF) outF[(size_t)row * 1024 + col] = y;
            if (outB) outB[(size_t)row * 1024 + col] = (bf16)y;
        }
}

// ---------------------------------------------------------------------------
// SRU segmented scan: 8 segments of 128 steps (affine maps), 2 phases.
__global__ __launch_bounds__(64) void k_sru_ab(
    const bf16* __restrict__ U2a, const bf16* __restrict__ v2, const bf16* __restrict__ b2,
    float* __restrict__ AB) {
    int ch = blockIdx.x * 64 + threadIdx.x;  // 0..8191
    int g = blockIdx.y;                      // 0..7
    int hh = ch & 2047;
    float vf = (float)v2[hh], bfv = (float)b2[hh];
    const bf16x8* u = (const bf16x8*)(U2a + (size_t)ch * 2048 + g * 256);  // 32 chunks x 4 steps
    float A = 1.f, c = 0.f;
    bf16x8 q[4];
#pragma unroll
    for (int i = 0; i < 4; i++) q[i] = u[i];
    for (int it = 0; it < 8; it++) {
#pragma unroll
        for (int j = 0; j < 4; j++) {
            int cidx = it * 4 + j;
            bf16x8 v = q[j];
            if (cidx + 4 < 32) q[j] = u[cidx + 4];
#pragma unroll
            for (int t = 0; t < 4; t++) {
                float xc = (float)v[t * 2], fp = (float)v[t * 2 + 1];
                float f = 1.f / (1.f + __expf(-(fp + vf * c + bfv)));
                A *= f;
                c = f * c + (1.f - f) * xc;
            }
        }
    }
    AB[(size_t)(g * 8192 + ch) * 2] = A;
    AB[(size_t)(g * 8192 + ch) * 2 + 1] = c;
}

__global__ __launch_bounds__(64) void k_sru_h(
    const bf16* __restrict__ U2a, const bf16* __restrict__ U2b,
    const bf16* __restrict__ v2, const bf16* __restrict__ b2,
    const float* __restrict__ AB, bf16* __restrict__ Hb) {
    int ch = blockIdx.x * 64 + threadIdx.x;
    int g = blockIdx.y;
    int b = ch >> 11, hh = ch & 2047;
    float vf = (float)v2[hh], vr = (float)v2[2048 + hh];
    float bfv = (float)b2[hh], brv = (float)b2[2048 + hh];
    float c = 0.f;
    for (int s = 0; s < g; s++) {  // wave-uniform bound
        float As = AB[(size_t)(s * 8192 + ch) * 2];
        float Bs = AB[(size_t)(s * 8192 + ch) * 2 + 1];
        c = As * c + Bs;
    }
    const bf16x8* ua = (const bf16x8*)(U2a + (size_t)ch * 2048 + g * 256);
    const bf16x8* ub = (const bf16x8*)(U2b + (size_t)ch * 2048 + g * 256);
    bf16* ho = Hb + ((size_t)(g * 128) * 4 + b) * 2048 + hh;  // +8192 per local step
    bf16x8 qa[4], qb[4];
#pragma unroll
    for (int i = 0; i < 4; i++) { qa[i] = ua[i]; qb[i] = ub[i]; }
    for (int it = 0; it < 8; it++) {
#pragma unroll
        for (int j = 0; j < 4; j++) {
            int cidx = it * 4 + j;
            bf16x8 va = qa[j], vb = qb[j];
            if (cidx + 4 < 32) { qa[j] = ua[cidx + 4]; qb[j] = ub[cidx + 4]; }
#pragma unroll
            for (int t = 0; t < 4; t++) {
                float xc = (float)va[t * 2], fp = (float)va[t * 2 + 1];
                float rp = (float)vb[t * 2], xh = (float)vb[t * 2 + 1];
                float f = 1.f / (1.f + __expf(-(fp + vf * c + bfv)));
                float r = 1.f / (1.f + __expf(-(rp + vr * c + brv)));
                c = f * c + (1.f - f) * xc;
                float hv = r * c + (1.f - r) * xh;
                ho[(size_t)(cidx * 4 + t) * 8192] = (bf16)hv;
            }
        }
    }
}

// ---------------------------------------------------------------------------
extern "C" void kernel_launch(void* const* d_in, const int* in_sizes, int n_in,
                              void* d_out, int out_size, void* d_ws, size_t ws_size,
                              hipStream_t stream) {
    const size_t MB = 1u << 20;
    char* ws = (char*)d_ws;

    bf16* memB    = (bf16*)(ws + 0);
    bf16* sawinB  = (bf16*)(ws + 8 * MB);
    bf16* sawoutB = (bf16*)(ws + 14 * MB);
    bf16* cawinB  = (bf16*)(ws + 16 * MB);
    bf16* cawoutB = (bf16*)(ws + 22 * MB);
    bf16* lin2wB  = (bf16*)(ws + 24 * MB);
    char* S0 = ws + 28 * MB;
    bf16* sabinB  = (bf16*)(S0 + 0 * 8192);
    bf16* cabinB  = (bf16*)(S0 + 1 * 8192);
    bf16* saboutB = (bf16*)(S0 + 2 * 8192);
    bf16* caboutB = (bf16*)(S0 + 3 * 8192);
    bf16* lin2bB  = (bf16*)(S0 + 4 * 8192);
    bf16* sruvB   = (bf16*)(S0 + 5 * 8192);
    bf16* srubB   = (bf16*)(S0 + 6 * 8192);
    bf16* ln1gB   = (bf16*)(S0 + 7 * 8192);
    bf16* ln1bB   = (bf16*)(S0 + 8 * 8192);
    bf16* ln2gB   = (bf16*)(S0 + 9 * 8192);
    bf16* ln2bB   = (bf16*)(S0 + 10 * 8192);
    bf16* ln3gB   = (bf16*)(S0 + 11 * 8192);
    bf16* ln3bB   = (bf16*)(S0 + 12 * 8192);
    int*  flag    = (int*)(S0 + 13 * 8192);
    float* AB     = (float*)(S0 + 128 * 1024);  // 512 KB within the 1 MB region

    char* P = ws + 29 * MB;
    float* t0   = (float*)(P + 0);
    bf16*  qkv  = (bf16*)(P + 16 * MB);
    bf16*  qca  = qkv;
    bf16*  kvca = (bf16*)(P + 24 * MB);
    bf16*  obuf = (bf16*)(P + 40 * MB);
    bf16*  Vt   = (bf16*)(P + 56 * MB);
    bf16*  t0b  = (bf16*)(P + 64 * MB);
    float* tmp  = (float*)(P + 64 * MB);
    bf16*  t1   = (bf16*)(P + 80 * MB);
    bf16*  t2   = (bf16*)(ws + 0);        // overlays dead memB
    bf16*  wT   = (bf16*)(P + 0);         // overlays dead t0
    bf16*  U2a  = (bf16*)(P + 16 * MB);   // 8192ch x 1024step x {xc,fp} = 32MB
    bf16*  U2b  = (bf16*)(P + 48 * MB);   // 8192ch x 1024step x {rp,xh} = 32MB
    bf16*  hb   = (bf16*)(P + 80 * MB);   // overlays dead t1
    float* tmp2 = (float*)(P + 16 * MB);  // U2a dead after scan

    k_detect<<<1, 256, 0, stream>>>(d_in[0], flag);
    BigSegs bg;
    {
        const void* bsrc[6] = {d_in[1], d_in[2], d_in[4], d_in[6], d_in[8], d_in[13]};
        bf16* bdst[6] = {memB, sawinB, sawoutB, cawinB, cawoutB, lin2wB};
        const int cum[7] = {0, 2048, 3584, 4096, 5632, 6144, 7168};
        for (int i = 0; i < 6; i++) { bg.src[i] = bsrc[i]; bg.dst[i] = bdst[i]; }
        for (int i = 0; i < 7; i++) bg.cum[i] = cum[i];
    }
    k_norm_big<<<7168, 256, 0, stream>>>(flag, bg);
    SmallSegs sg;
    const int srcIdx[13] = {3, 7, 5, 9, 14, 11, 12, 15, 16, 17, 18, 19, 20};
    bf16* dsts[13] = {sabinB, cabinB, saboutB, caboutB, lin2bB, sruvB, srubB,
                      ln1gB, ln1bB, ln2gB, ln2bB, ln3gB, ln3bB};
    const int n8s[13] = {384, 384, 128, 128, 128, 512, 512, 128, 128, 128, 128, 128, 128};
    for (int i = 0; i < 13; i++) { sg.src[i] = d_in[srcIdx[i]]; sg.dst[i] = dsts[i]; sg.n8[i] = n8s[i]; }
    k_norm_multi<<<13, 256, 0, stream>>>(flag, sg);

    k_cvt<<<2048, 256, 0, stream>>>(flag, d_in[0], t0, t0b);

    // ---- self attention ----
    k_gemm<128, false><<<dim3(24, 32), 256, 0, stream>>>(t0b, 1024, sawinB, 1024, sabinB,
                                                         nullptr, qkv, 3072, 1024, 1024, 0.125f);
    k_vtr<<<dim3(16, 16, 4), 256, 0, stream>>>(qkv + 2048, 3072, Vt);
    k_attn<<<dim3(64, 8), 256, 0, stream>>>(qkv, qkv + 1024, Vt, 3072, 3072, obuf);
    k_gemm<64, false><<<dim3(8, 64), 256, 0, stream>>>(obuf, 1024, sawoutB, 1024, saboutB,
                                                       tmp, nullptr, 1024, 1024, 0, 1.f);
    k_addln<float><<<1024, 256, 0, stream>>>(t0, tmp, ln1gB, ln1bB, nullptr, t1);

    // ---- cross attention ----
    k_gemm<64, false><<<dim3(8, 64), 256, 0, stream>>>(t1, 1024, cawinB, 1024, cabinB,
                                                       nullptr, qca, 1024, 1024, 1024, 0.125f);
    k_gemm<128, false><<<dim3(16, 32), 256, 0, stream>>>(memB, 1024, cawinB + (size_t)1024 * 1024, 1024,
                                                         cabinB + 1024, nullptr, kvca, 2048, 1024, 0, 1.f);
    k_vtr<<<dim3(16, 16, 4), 256, 0, stream>>>(kvca + 1024, 2048, Vt);
    k_attn<<<dim3(64, 8), 256, 0, stream>>>(qca, kvca, Vt, 1024, 2048, obuf);
    k_gemm<64, false><<<dim3(8, 64), 256, 0, stream>>>(obuf, 1024, cawoutB, 1024, caboutB,
                                                       tmp, nullptr, 1024, 1024, 0, 1.f);
    k_addln<bf16><<<1024, 256, 0, stream>>>(t1, tmp, ln2gB, ln2bB, nullptr, t2);

    // ---- SRU: GEMM scatters (U2a,U2b) via LDS-staged 128B runs; 2-phase scan ----
    k_transpose<<<dim3(128, 16), 256, 0, stream>>>(flag, d_in[10], wT, 1024, 8192);
    k_gemm<128, true><<<dim3(64, 32), 256, 0, stream>>>(t2, 1024, wT, 1024,
                                                        nullptr, (float*)U2b, U2a, 0, 1024, 0, 1.f);
    k_sru_ab<<<dim3(128, 8), 64, 0, stream>>>(U2a, sruvB, srubB, AB);
    k_sru_h<<<dim3(128, 8), 64, 0, stream>>>(U2a, U2b, sruvB, srubB, AB, hb);
    k_gemm<64, false><<<dim3(8, 64), 256, 0, stream>>>(hb, 2048, lin2wB, 2048, lin2bB,
                                                       tmp2, nullptr, 1024, 2048, 0, 1.f);
    k_addln<bf16><<<1024, 256, 0, stream>>>(t2, tmp2, ln3gB, ln3bB, (float*)d_out, nullptr);
}

// Round 14
// 454.807 us; speedup vs baseline: 2.1827x; 1.0355x over previous
//
#include <hip/hip_runtime.h>
#include <hip/hip_bf16.h>

typedef __bf16 bf16;
typedef bf16 bf16x8 __attribute__((ext_vector_type(8)));
typedef bf16 bf16x4 __attribute__((ext_vector_type(4)));
typedef float f32x4 __attribute__((ext_vector_type(4)));

#define MFMA16(a, b, c) __builtin_amdgcn_mfma_f32_16x16x32_bf16((a), (b), (c), 0, 0, 0)

__device__ __forceinline__ void gl_lds16(const void* g, void* l) {
    __builtin_amdgcn_global_load_lds((const __attribute__((address_space(1))) void*)g,
                                     (__attribute__((address_space(3))) void*)l, 16, 0, 0);
}

// ---------------------------------------------------------------------------
__global__ __launch_bounds__(256) void k_detect(const void* __restrict__ src, int* __restrict__ flag) {
    __shared__ int cnt;
    if (threadIdx.x == 0) cnt = 0;
    __syncthreads();
    const unsigned int* w = (const unsigned int*)src;
    int local = 0;
    for (int i = threadIdx.x; i < 4096; i += 256) {
        unsigned int e = (w[i] >> 7) & 0xFF;
        local += (e > 100 && e < 150) ? 1 : 0;
    }
    atomicAdd(&cnt, local);
    __syncthreads();
    if (threadIdx.x == 0) *flag = (cnt > 2048) ? 1 : 0;
}

struct BigSegs {
    const void* src[6];
    bf16* dst[6];
    int cum[7];
};
__global__ __launch_bounds__(256) void k_norm_big(const int* __restrict__ flag, BigSegs s) {
    int seg = 0;
#pragma unroll
    for (int t = 0; t < 5; t++) seg += (blockIdx.x >= s.cum[t + 1]) ? 1 : 0;
    int i = (blockIdx.x - s.cum[seg]) * 256 + threadIdx.x;
    const void* sp = s.src[seg];
    bf16* dp = s.dst[seg];
    if (*flag) {
        ((bf16x8*)dp)[i] = ((const bf16x8*)sp)[i];
    } else {
        const float* fs = (const float*)sp + (size_t)i * 8;
        bf16x8 o;
#pragma unroll
        for (int j = 0; j < 8; j++) o[j] = (bf16)fs[j];
        ((bf16x8*)dp)[i] = o;
    }
}

struct SmallSegs {
    const void* src[13];
    bf16* dst[13];
    int n8[13];
};
__global__ __launch_bounds__(256) void k_norm_multi(const int* __restrict__ flag, SmallSegs s) {
    int seg = blockIdx.x;
    const void* sp = s.src[seg];
    bf16* dp = s.dst[seg];
    int n = s.n8[seg];
    int f = *flag;
    for (int i = threadIdx.x; i < n; i += 256) {
        if (f) {
            ((bf16x8*)dp)[i] = ((const bf16x8*)sp)[i];
        } else {
            const float* fs = (const float*)sp + (size_t)i * 8;
            bf16x8 o;
#pragma unroll
            for (int j = 0; j < 8; j++) o[j] = (bf16)fs[j];
            ((bf16x8*)dp)[i] = o;
        }
    }
}

// tgt -> bf16 copy t0b (GEMM A operand + ln1 residual)
__global__ __launch_bounds__(256) void k_cvt(const int* __restrict__ flag, const void* __restrict__ in,
                                             bf16* __restrict__ outb) {
    size_t i = (size_t)blockIdx.x * 256 + threadIdx.x;
    bf16x8 v;
    if (*flag) {
        v = ((const bf16x8*)in)[i];
    } else {
        f32x4 a = ((const f32x4*)in)[i * 2];
        f32x4 b = ((const f32x4*)in)[i * 2 + 1];
#pragma unroll
        for (int j = 0; j < 4; j++) { v[j] = (bf16)a[j]; v[4 + j] = (bf16)b[j]; }
    }
    ((bf16x8*)outb)[i] = v;
}

// ---------------------------------------------------------------------------
// transpose+permute: sru_w (1024,8192) -> wT' (8192,1024) with row n'=h*4+j
__global__ __launch_bounds__(256) void k_transpose(const int* __restrict__ flag, const void* __restrict__ in,
                                                   bf16* __restrict__ out, int R, int C) {
    __shared__ __align__(16) bf16 t[64][72];
    int tid = threadIdx.x;
    int c0 = blockIdx.x * 64, r0 = blockIdx.y * 64;
#pragma unroll
    for (int i = 0; i < 2; i++) {
        int idx = tid + i * 256;
        int r = idx >> 3, ch = idx & 7;
        size_t base = (size_t)(r0 + r) * C + c0 + ch * 8;
        bf16x8 v;
        if (*flag) {
            v = *(const bf16x8*)((const bf16*)in + base);
        } else {
            const float* f = (const float*)in + base;
            f32x4 x = *(const f32x4*)f, y = *(const f32x4*)(f + 4);
#pragma unroll
            for (int j = 0; j < 4; j++) { v[j] = (bf16)x[j]; v[4 + j] = (bf16)y[j]; }
        }
        *(bf16x8*)&t[r][ch * 8] = v;
    }
    __syncthreads();
    int nbase = c0 & 2047, joff = c0 >> 11;
#pragma unroll
    for (int i = 0; i < 2; i++) {
        int idx = tid + i * 256;
        int cr = idx >> 3, ch = idx & 7;
        bf16x8 v;
#pragma unroll
        for (int j = 0; j < 8; j++) v[j] = t[ch * 8 + j][cr];
        int np = (nbase + cr) * 4 + joff;
        *(bf16x8*)(out + (size_t)np * R + r0 + ch * 8) = v;
    }
}

// ---------------------------------------------------------------------------
// V pre-transpose: in rows m=s*4+b, 64 cols -> Vt[b][n][s] ([4][1024][1024])
__global__ __launch_bounds__(256) void k_vtr(const bf16* __restrict__ in, int ldv, bf16* __restrict__ out) {
    int nt = blockIdx.x, st = blockIdx.y, b = blockIdx.z;
    __shared__ __align__(16) bf16 t[64][72];
    int tid = threadIdx.x;
#pragma unroll
    for (int i = 0; i < 2; i++) {
        int idx = tid + i * 256;
        int r = idx >> 3, ch = idx & 7;
        bf16x8 v = *(const bf16x8*)(in + (size_t)((st * 64 + r) * 4 + b) * ldv + nt * 64 + ch * 8);
        *(bf16x8*)&t[r][ch * 8] = v;
    }
    __syncthreads();
#pragma unroll
    for (int i = 0; i < 2; i++) {
        int idx = tid + i * 256;
        int dr = idx >> 3, ch = idx & 7;
        bf16x8 v;
#pragma unroll
        for (int j = 0; j < 8; j++) v[j] = t[ch * 8 + j][dr];
        *(bf16x8*)(out + (size_t)(b * 1024 + nt * 64 + dr) * 1024 + st * 64 + ch * 8) = v;
    }
}

// ---------------------------------------------------------------------------
// GEMM (bf16 A): C[M,N] = A @ W^T (+bias)(*scale). BMx128 tile, BK=64.
// USCAT epilogue: LDS-staged 128B-contiguous runs into U2a/U2b.
__device__ __forceinline__ int swzB(int r, int byteInRow) {
    return r * 128 + (byteInRow ^ ((r & 7) << 4));
}

template <int BM, bool USCAT>
__global__ __launch_bounds__(256) void k_gemm(
    const bf16* __restrict__ A, int lda,
    const bf16* __restrict__ W, int ldw,
    const bf16* __restrict__ bias,
    float* __restrict__ Cf, bf16* __restrict__ Cb, int ldc,
    int K, int scale_end, float scale) {
    constexpr int MI = BM / 32;
    __shared__ __align__(16) char Asm[BM * 128];
    __shared__ __align__(16) char Bsm[128 * 128];
    int tid = threadIdx.x, w = tid >> 6, l = tid & 63, lg = l >> 4, lm = l & 15;
    int wm = w >> 1, wn = w & 1;
    int m0 = blockIdx.y * BM, n0 = blockIdx.x * 128;

    f32x4 acc[MI][4] = {};

    for (int k0 = 0; k0 < K; k0 += 64) {
#pragma unroll
        for (int i = 0; i < BM / 32; i++) {
            int r = i * 32 + w * 8 + (l >> 3);
            int gs = (l & 7) ^ (r & 7);
            gl_lds16(A + (size_t)(m0 + r) * lda + k0 + gs * 8,
                     Asm + (i * 32 + w * 8) * 128);
        }
#pragma unroll
        for (int i = 0; i < 4; i++) {
            int r = i * 32 + w * 8 + (l >> 3);
            int gs = (l & 7) ^ (r & 7);
            gl_lds16(W + (size_t)(n0 + r) * ldw + k0 + gs * 8,
                     Bsm + (i * 32 + w * 8) * 128);
        }
        __syncthreads();
#pragma unroll
        for (int kh = 0; kh < 2; kh++) {
            bf16x8 af[MI], bfr[4];
#pragma unroll
            for (int i = 0; i < MI; i++)
                af[i] = *(const bf16x8*)(Asm + swzB(wm * (BM / 2) + i * 16 + lm, kh * 64 + lg * 16));
#pragma unroll
            for (int j = 0; j < 4; j++)
                bfr[j] = *(const bf16x8*)(Bsm + swzB(wn * 64 + j * 16 + lm, kh * 64 + lg * 16));
#pragma unroll
            for (int i = 0; i < MI; i++)
#pragma unroll
                for (int j = 0; j < 4; j++)
                    acc[i][j] = MFMA16(af[i], bfr[j], acc[i][j]);
        }
        __syncthreads();
    }
    if constexpr (USCAT) {
        bf16* lsA = (bf16*)Asm;  // 16 KB (BM=128)
        bf16* lsB = (bf16*)Bsm;  // 16 KB
#pragma unroll
        for (int j = 0; j < 4; j++) {
            int cl = wn * 16 + j * 4 + (lm >> 2);  // channel-local 0..31
            int g = lm & 3;
            bf16* ls = (g < 2) ? lsA : lsB;
            int g01 = g & 1;
#pragma unroll
            for (int i = 0; i < MI; i++) {
                int slb = wm * 16 + i * 4 + lg;    // step-local 0..31
                int boff = (slb * 2 + g01) * 2;
                int swz = boff ^ ((cl & 7) << 4);
#pragma unroll
                for (int r = 0; r < 4; r++) {
                    float v = acc[i][j][r];
                    *(bf16*)((char*)ls + (r * 32 + cl) * 128 + swz) = (bf16)v;
                }
            }
        }
        __syncthreads();
        int buf = tid >> 7, bb = (tid >> 5) & 3, cl = tid & 31;
        const char* ls = (buf == 0) ? (const char*)lsA : (const char*)lsB;
        bf16* dstbase = (buf == 0) ? Cb : (bf16*)Cf;  // U2a / U2b
        int ch = bb * 2048 + (n0 >> 2) + cl;
        size_t gbase = (size_t)ch * 2048 + (size_t)(m0 >> 2) * 2;
        const char* src = ls + (bb * 32 + cl) * 128;
#pragma unroll
        for (int q = 0; q < 8; q++) {
            int pq = (q * 16) ^ ((cl & 7) << 4);
            *(bf16x8*)(dstbase + gbase + q * 8) = *(const bf16x8*)(src + pq);
        }
    } else {
#pragma unroll
        for (int j = 0; j < 4; j++) {
            int col = n0 + wn * 64 + j * 16 + lm;
            float bv = bias ? (float)bias[col] : 0.f;
            float sc = (col < scale_end) ? scale : 1.f;
#pragma unroll
            for (int i = 0; i < MI; i++) {
                int row = m0 + wm * (BM / 2) + i * 16 + lg * 4;
#pragma unroll
                for (int r = 0; r < 4; r++) {
                    float v = (acc[i][j][r] + bv) * sc;
                    size_t idx = (size_t)(row + r) * ldc + col;
                    if (Cf) Cf[idx] = v;
                    if (Cb) Cb[idx] = (bf16)v;
                }
            }
        }
    }
}

// ---------------------------------------------------------------------------
// Flash attention, QBLK=128, V pre-transposed, defer-max (lazy cross-lane
// reduce: full shuffle-reduce + rescale only when some lane's tile max grows
// past mrun+8), lane-partial lrun.
__device__ __forceinline__ int swz2(int row, int byteInRow) {
    return row * 128 + (byteInRow ^ ((row & 7) << 4));
}
__device__ __forceinline__ int swzP(int row, int byteInRow) {
    return row * 128 + (byteInRow ^ ((row & 3) << 4) ^ (((row >> 2) & 1) << 6));
}

__global__ __launch_bounds__(256) void k_attn(
    const bf16* __restrict__ Qp, const bf16* __restrict__ Kp, const bf16* __restrict__ Vt,
    int ldq, int ldk, bf16* __restrict__ Op) {
    int h = blockIdx.x & 15, b = blockIdx.x >> 4, qblk = blockIdx.y;
    int tid = threadIdx.x, w = tid >> 6, l = tid & 63, lg = l >> 4, lm = l & 15;
    int r0 = tid >> 3, ch = tid & 7;

    __shared__ __align__(16) char Ksm[64 * 128];
    __shared__ __align__(16) char Vsm[64 * 128];
    __shared__ __align__(16) char Psm[4][32 * 128];

    bf16x8 qf[2][2];
#pragma unroll
    for (int u = 0; u < 2; u++) {
        int qrow = qblk * 128 + w * 32 + u * 16 + lm;
#pragma unroll
        for (int kk = 0; kk < 2; kk++)
            qf[u][kk] = *(const bf16x8*)(Qp + (size_t)(qrow * 4 + b) * ldq + h * 64 + kk * 32 + lg * 8);
    }

    const bf16* vbase = Vt + (size_t)(b * 1024 + h * 64) * 1024;

    bf16x8 kreg[2], vreg[2];
#pragma unroll
    for (int p = 0; p < 2; p++) {
        int r = r0 + p * 32;
        kreg[p] = *(const bf16x8*)(Kp + (size_t)(r * 4 + b) * ldk + h * 64 + ch * 8);
        vreg[p] = *(const bf16x8*)(vbase + (size_t)r * 1024 + ch * 8);
    }

    f32x4 oa[2][4] = {};
    float mrun[2][4], lrun[2][4];
#pragma unroll
    for (int u = 0; u < 2; u++)
#pragma unroll
        for (int r = 0; r < 4; r++) { mrun[u][r] = -1e30f; lrun[u][r] = 0.f; }

    for (int kt = 0; kt < 16; kt++) {
        __syncthreads();
#pragma unroll
        for (int p = 0; p < 2; p++) {
            int r = r0 + p * 32;
            *(bf16x8*)(Ksm + swz2(r, ch * 16)) = kreg[p];
            *(bf16x8*)(Vsm + swz2(r, ch * 16)) = vreg[p];
        }
        if (kt < 15) {
#pragma unroll
            for (int p = 0; p < 2; p++) {
                int r = (kt + 1) * 64 + r0 + p * 32;
                kreg[p] = *(const bf16x8*)(Kp + (size_t)(r * 4 + b) * ldk + h * 64 + ch * 8);
                vreg[p] = *(const bf16x8*)(vbase + (size_t)(r0 + p * 32) * 1024 + (kt + 1) * 64 + ch * 8);
            }
        }
        __syncthreads();

        f32x4 sc[2][4] = {};
#pragma unroll
        for (int kk = 0; kk < 2; kk++)
#pragma unroll
            for (int jt = 0; jt < 4; jt++) {
                bf16x8 bk = *(const bf16x8*)(Ksm + swz2(jt * 16 + lm, kk * 64 + lg * 16));
#pragma unroll
                for (int u = 0; u < 2; u++)
                    sc[u][jt] = MFMA16(qf[u][kk], bk, sc[u][jt]);
            }

        // per-lane tile max (no cross-lane traffic)
        float lmax[2][4];
        bool grow = false;
#pragma unroll
        for (int u = 0; u < 2; u++)
#pragma unroll
            for (int r = 0; r < 4; r++) {
                lmax[u][r] = fmaxf(fmaxf(sc[u][0][r], sc[u][1][r]), fmaxf(sc[u][2][r], sc[u][3][r]));
                grow = grow || (lmax[u][r] > mrun[u][r] + 8.f);
            }
        if (__any(grow)) {  // rare: full row reduce + rescale
#pragma unroll
            for (int u = 0; u < 2; u++)
#pragma unroll
                for (int r = 0; r < 4; r++) {
                    float m = lmax[u][r];
#pragma unroll
                    for (int d = 1; d < 16; d <<= 1) m = fmaxf(m, __shfl_xor(m, d));
                    float mn = fmaxf(mrun[u][r], m);
                    float al = __expf(mrun[u][r] - mn);
                    mrun[u][r] = mn;
                    lrun[u][r] *= al;
#pragma unroll
                    for (int ot = 0; ot < 4; ot++) oa[u][ot][r] *= al;
                }
        }
#pragma unroll
        for (int u = 0; u < 2; u++)
#pragma unroll
            for (int jt = 0; jt < 4; jt++)
#pragma unroll
                for (int r = 0; r < 4; r++) {
                    float p = __expf(sc[u][jt][r] - mrun[u][r]);
                    sc[u][jt][r] = p;
                    lrun[u][r] += p;
                }
#pragma unroll
        for (int u = 0; u < 2; u++)
#pragma unroll
            for (int jt = 0; jt < 4; jt++)
#pragma unroll
                for (int r = 0; r < 4; r++)
                    *(bf16*)(Psm[w] + swzP(u * 16 + lg * 4 + r, (jt * 16 + lm) * 2)) = (bf16)sc[u][jt][r];
        asm volatile("s_waitcnt lgkmcnt(0)" ::: "memory");
        __builtin_amdgcn_sched_barrier(0);
#pragma unroll
        for (int kk = 0; kk < 2; kk++) {
            bf16x8 pa[2];
#pragma unroll
            for (int u = 0; u < 2; u++)
                pa[u] = *(const bf16x8*)(Psm[w] + swzP(u * 16 + lm, kk * 64 + lg * 16));
#pragma unroll
            for (int ot = 0; ot < 4; ot++) {
                bf16x8 bv = *(const bf16x8*)(Vsm + swz2(ot * 16 + lm, kk * 64 + lg * 16));
#pragma unroll
                for (int u = 0; u < 2; u++)
                    oa[u][ot] = MFMA16(pa[u], bv, oa[u][ot]);
            }
        }
    }
#pragma unroll
    for (int u = 0; u < 2; u++)
#pragma unroll
        for (int r = 0; r < 4; r++) {
#pragma unroll
            for (int d = 1; d < 16; d <<= 1) lrun[u][r] += __shfl_xor(lrun[u][r], d);
            float inv = 1.f / lrun[u][r];
            int srow = qblk * 128 + w * 32 + u * 16 + lg * 4 + r;
#pragma unroll
            for (int ot = 0; ot < 4; ot++) {
                int col = h * 64 + ot * 16 + lm;
                Op[(size_t)(srow * 4 + b) * 1024 + col] = (bf16)(oa[u][ot][r] * inv);
            }
        }
}

// ---------------------------------------------------------------------------
// residual-add + LayerNorm over D=1024 (f32 math). X dtype templated.
template <typename XT>
__global__ __launch_bounds__(256) void k_addln(
    const XT* __restrict__ X, const float* __restrict__ Yd,
    const bf16* __restrict__ g, const bf16* __restrict__ bb,
    float* __restrict__ outF, bf16* __restrict__ outB) {
    int row = blockIdx.x * 4 + (threadIdx.x >> 6);
    int l = threadIdx.x & 63;
    const XT* xr = X + (size_t)row * 1024;
    const float* yr = Yd + (size_t)row * 1024;
    float v[16];
    float s = 0.f, s2 = 0.f;
#pragma unroll
    for (int q = 0; q < 4; q++) {
        float xa[4];
        if constexpr (sizeof(XT) == 4) {
            f32x4 a = *(const f32x4*)(xr + l * 4 + q * 256);
#pragma unroll
            for (int j = 0; j < 4; j++) xa[j] = a[j];
        } else {
            bf16x4 a = *(const bf16x4*)(xr + l * 4 + q * 256);
#pragma unroll
            for (int j = 0; j < 4; j++) xa[j] = (float)a[j];
        }
        f32x4 c = *(const f32x4*)(yr + l * 4 + q * 256);
#pragma unroll
        for (int j = 0; j < 4; j++) {
            float t = xa[j] + c[j];
            v[q * 4 + j] = t;
            s += t;
            s2 += t * t;
        }
    }
#pragma unroll
    for (int d = 1; d < 64; d <<= 1) { s += __shfl_xor(s, d); s2 += __shfl_xor(s2, d); }
    float mu = s * (1.f / 1024.f);
    float var = s2 * (1.f / 1024.f) - mu * mu;
    float rstd = rsqrtf(var + 1e-5f);
#pragma unroll
    for (int q = 0; q < 4; q++)
#pragma unroll
        for (int j = 0; j < 4; j++) {
            int col = l * 4 + q * 256 + j;
            float y = (v[q * 4 + j] - mu) * rstd * (float)g[col] + (float)bb[col];
            if (outF) outF[(size_t)row * 1024 + col] = y;
            if (outB) outB[(size_t)row * 1024 + col] = (bf16)y;
        }
}

// ---------------------------------------------------------------------------
// SRU segmented scan: 8 segments of 128 steps (affine maps), 2 phases.
__global__ __launch_bounds__(64) void k_sru_ab(
    const bf16* __restrict__ U2a, const bf16* __restrict__ v2, const bf16* __restrict__ b2,
    float* __restrict__ AB) {
    int ch = blockIdx.x * 64 + threadIdx.x;  // 0..8191
    int g = blockIdx.y;                      // 0..7
    int hh = ch & 2047;
    float vf = (float)v2[hh], bfv = (float)b2[hh];
    const bf16x8* u = (const bf16x8*)(U2a + (size_t)ch * 2048 + g * 256);
    float A = 1.f, c = 0.f;
    bf16x8 q[4];
#pragma unroll
    for (int i = 0; i < 4; i++) q[i] = u[i];
    for (int it = 0; it < 8; it++) {
#pragma unroll
        for (int j = 0; j < 4; j++) {
            int cidx = it * 4 + j;
            bf16x8 v = q[j];
            if (cidx + 4 < 32) q[j] = u[cidx + 4];
#pragma unroll
            for (int t = 0; t < 4; t++) {
                float xc = (float)v[t * 2], fp = (float)v[t * 2 + 1];
                float f = 1.f / (1.f + __expf(-(fp + vf * c + bfv)));
                A *= f;
                c = f * c + (1.f - f) * xc;
            }
        }
    }
    AB[(size_t)(g * 8192 + ch) * 2] = A;
    AB[(size_t)(g * 8192 + ch) * 2 + 1] = c;
}

__global__ __launch_bounds__(64) void k_sru_h(
    const bf16* __restrict__ U2a, const bf16* __restrict__ U2b,
    const bf16* __restrict__ v2, const bf16* __restrict__ b2,
    const float* __restrict__ AB, bf16* __restrict__ Hb) {
    int ch = blockIdx.x * 64 + threadIdx.x;
    int g = blockIdx.y;
    int b = ch >> 11, hh = ch & 2047;
    float vf = (float)v2[hh], vr = (float)v2[2048 + hh];
    float bfv = (float)b2[hh], brv = (float)b2[2048 + hh];
    float c = 0.f;
    for (int s = 0; s < g; s++) {  // wave-uniform bound
        float As = AB[(size_t)(s * 8192 + ch) * 2];
        float Bs = AB[(size_t)(s * 8192 + ch) * 2 + 1];
        c = As * c + Bs;
    }
    const bf16x8* ua = (const bf16x8*)(U2a + (size_t)ch * 2048 + g * 256);
    const bf16x8* ub = (const bf16x8*)(U2b + (size_t)ch * 2048 + g * 256);
    bf16* ho = Hb + ((size_t)(g * 128) * 4 + b) * 2048 + hh;
    bf16x8 qa[4], qb[4];
#pragma unroll
    for (int i = 0; i < 4; i++) { qa[i] = ua[i]; qb[i] = ub[i]; }
    for (int it = 0; it < 8; it++) {
#pragma unroll
        for (int j = 0; j < 4; j++) {
            int cidx = it * 4 + j;
            bf16x8 va = qa[j], vb = qb[j];
            if (cidx + 4 < 32) { qa[j] = ua[cidx + 4]; qb[j] = ub[cidx + 4]; }
#pragma unroll
            for (int t = 0; t < 4; t++) {
                float xc = (float)va[t * 2], fp = (float)va[t * 2 + 1];
                float rp = (float)vb[t * 2], xh = (float)vb[t * 2 + 1];
                float f = 1.f / (1.f + __expf(-(fp + vf * c + bfv)));
                float r = 1.f / (1.f + __expf(-(rp + vr * c + brv)));
                c = f * c + (1.f - f) * xc;
                float hv = r * c + (1.f - r) * xh;
                ho[(size_t)(cidx * 4 + t) * 8192] = (bf16)hv;
            }
        }
    }
}

// ---------------------------------------------------------------------------
extern "C" void kernel_launch(void* const* d_in, const int* in_sizes, int n_in,
                              void* d_out, int out_size, void* d_ws, size_t ws_size,
                              hipStream_t stream) {
    const size_t MB = 1u << 20;
    char* ws = (char*)d_ws;

    bf16* memB    = (bf16*)(ws + 0);
    bf16* sawinB  = (bf16*)(ws + 8 * MB);
    bf16* sawoutB = (bf16*)(ws + 14 * MB);
    bf16* cawinB  = (bf16*)(ws + 16 * MB);
    bf16* cawoutB = (bf16*)(ws + 22 * MB);
    bf16* lin2wB  = (bf16*)(ws + 24 * MB);
    char* S0 = ws + 28 * MB;
    bf16* sabinB  = (bf16*)(S0 + 0 * 8192);
    bf16* cabinB  = (bf16*)(S0 + 1 * 8192);
    bf16* saboutB = (bf16*)(S0 + 2 * 8192);
    bf16* caboutB = (bf16*)(S0 + 3 * 8192);
    bf16* lin2bB  = (bf16*)(S0 + 4 * 8192);
    bf16* sruvB   = (bf16*)(S0 + 5 * 8192);
    bf16* srubB   = (bf16*)(S0 + 6 * 8192);
    bf16* ln1gB   = (bf16*)(S0 + 7 * 8192);
    bf16* ln1bB   = (bf16*)(S0 + 8 * 8192);
    bf16* ln2gB   = (bf16*)(S0 + 9 * 8192);
    bf16* ln2bB   = (bf16*)(S0 + 10 * 8192);
    bf16* ln3gB   = (bf16*)(S0 + 11 * 8192);
    bf16* ln3bB   = (bf16*)(S0 + 12 * 8192);
    int*  flag    = (int*)(S0 + 13 * 8192);
    float* AB     = (float*)(S0 + 128 * 1024);  // 512 KB within the 1 MB region

    char* P = ws + 29 * MB;
    bf16*  t0b  = (bf16*)(P + 0);         // 4096x1024 (QKV A + ln1 residual)
    bf16*  qkv  = (bf16*)(P + 16 * MB);
    bf16*  qca  = qkv;
    bf16*  kvca = (bf16*)(P + 24 * MB);
    bf16*  obuf = (bf16*)(P + 40 * MB);
    bf16*  Vt   = (bf16*)(P + 56 * MB);
    float* tmp  = (float*)(P + 64 * MB);
    bf16*  t1   = (bf16*)(P + 80 * MB);
    bf16*  t2   = (bf16*)(ws + 0);        // overlays dead memB
    bf16*  wT   = (bf16*)(P + 0);         // overlays dead t0b (after ln1)
    bf16*  U2a  = (bf16*)(P + 16 * MB);   // 32MB
    bf16*  U2b  = (bf16*)(P + 48 * MB);   // 32MB
    bf16*  hb   = (bf16*)(P + 80 * MB);   // overlays dead t1
    float* tmp2 = (float*)(P + 16 * MB);  // U2a dead after scan

    k_detect<<<1, 256, 0, stream>>>(d_in[0], flag);
    BigSegs bg;
    {
        const void* bsrc[6] = {d_in[1], d_in[2], d_in[4], d_in[6], d_in[8], d_in[13]};
        bf16* bdst[6] = {memB, sawinB, sawoutB, cawinB, cawoutB, lin2wB};
        const int cum[7] = {0, 2048, 3584, 4096, 5632, 6144, 7168};
        for (int i = 0; i < 6; i++) { bg.src[i] = bsrc[i]; bg.dst[i] = bdst[i]; }
        for (int i = 0; i < 7; i++) bg.cum[i] = cum[i];
    }
    k_norm_big<<<7168, 256, 0, stream>>>(flag, bg);
    SmallSegs sg;
    const int srcIdx[13] = {3, 7, 5, 9, 14, 11, 12, 15, 16, 17, 18, 19, 20};
    bf16* dsts[13] = {sabinB, cabinB, saboutB, caboutB, lin2bB, sruvB, srubB,
                      ln1gB, ln1bB, ln2gB, ln2bB, ln3gB, ln3bB};
    const int n8s[13] = {384, 384, 128, 128, 128, 512, 512, 128, 128, 128, 128, 128, 128};
    for (int i = 0; i < 13; i++) { sg.src[i] = d_in[srcIdx[i]]; sg.dst[i] = dsts[i]; sg.n8[i] = n8s[i]; }
    k_norm_multi<<<13, 256, 0, stream>>>(flag, sg);

    k_cvt<<<2048, 256, 0, stream>>>(flag, d_in[0], t0b);

    // ---- self attention ----
    k_gemm<128, false><<<dim3(24, 32), 256, 0, stream>>>(t0b, 1024, sawinB, 1024, sabinB,
                                                         nullptr, qkv, 3072, 1024, 1024, 0.125f);
    k_vtr<<<dim3(16, 16, 4), 256, 0, stream>>>(qkv + 2048, 3072, Vt);
    k_attn<<<dim3(64, 8), 256, 0, stream>>>(qkv, qkv + 1024, Vt, 3072, 3072, obuf);
    k_gemm<64, false><<<dim3(8, 64), 256, 0, stream>>>(obuf, 1024, sawoutB, 1024, saboutB,
                                                       tmp, nullptr, 1024, 1024, 0, 1.f);
    k_addln<bf16><<<1024, 256, 0, stream>>>(t0b, tmp, ln1gB, ln1bB, nullptr, t1);

    // ---- cross attention ----
    k_gemm<64, false><<<dim3(8, 64), 256, 0, stream>>>(t1, 1024, cawinB, 1024, cabinB,
                                                       nullptr, qca, 1024, 1024, 1024, 0.125f);
    k_gemm<128, false><<<dim3(16, 32), 256, 0, stream>>>(memB, 1024, cawinB + (size_t)1024 * 1024, 1024,
                                                         cabinB + 1024, nullptr, kvca, 2048, 1024, 0, 1.f);
    k_vtr<<<dim3(16, 16, 4), 256, 0, stream>>>(kvca + 1024, 2048, Vt);
    k_attn<<<dim3(64, 8), 256, 0, stream>>>(qca, kvca, Vt, 1024, 2048, obuf);
    k_gemm<64, false><<<dim3(8, 64), 256, 0, stream>>>(obuf, 1024, cawoutB, 1024, caboutB,
                                                       tmp, nullptr, 1024, 1024, 0, 1.f);
    k_addln<bf16><<<1024, 256, 0, stream>>>(t1, tmp, ln2gB, ln2bB, nullptr, t2);

    // ---- SRU ----
    k_transpose<<<dim3(128, 16), 256, 0, stream>>>(flag, d_in[10], wT, 1024, 8192);
    k_gemm<128, true><<<dim3(64, 32), 256, 0, stream>>>(t2, 1024, wT, 1024,
                                                        nullptr, (float*)U2b, U2a, 0, 1024, 0, 1.f);
    k_sru_ab<<<dim3(128, 8), 64, 0, stream>>>(U2a, sruvB, srubB, AB);
    k_sru_h<<<dim3(128, 8), 64, 0, stream>>>(U2a, U2b, sruvB, srubB, AB, hb);
    k_gemm<64, false><<<dim3(8, 64), 256, 0, stream>>>(hb, 2048, lin2wB, 2048, lin2bB,
                                                       tmp2, nullptr, 1024, 2048, 0, 1.f);
    k_addln<bf16><<<1024, 256, 0, stream>>>(t2, tmp2, ln3gB, ln3bB, (float*)d_out, nullptr);
}